// Round 7
// baseline (137.418 us; speedup 1.0000x reference)
//
#include <hip/hip_runtime.h>
#include <hip/hip_bf16.h>
#include <math.h>

#define DDIM 768
#define NCLS 256
#define NFEAT 768
#define NTOK 1024
#define NBATCH 4
#define KSEL 128

typedef float f32x4 __attribute__((ext_vector_type(4)));
typedef short s16x8 __attribute__((ext_vector_type(8)));

// ---------------- helpers ----------------
__device__ __forceinline__ float wsum(float v) {
#pragma unroll
  for (int o = 32; o; o >>= 1) v += __shfl_down(v, o, 64);
  return v;
}
__device__ __forceinline__ float wmaxr(float v) {
#pragma unroll
  for (int o = 32; o; o >>= 1) v = fmaxf(v, __shfl_down(v, o, 64));
  return v;
}
__device__ __forceinline__ short f2bf(float f) {
  union { __hip_bfloat16 h; short s; } u;
  u.h = __float2bfloat16(f);
  return u.s;
}
__device__ __forceinline__ float bf2f(short s) {
  union { unsigned u; float f; } c;
  c.u = ((unsigned)(unsigned short)s) << 16;
  return c.f;
}
__device__ __forceinline__ void cvt8(float4 x, float4 y, s16x8& h, s16x8& l) {
  float v[8] = {x.x, x.y, x.z, x.w, y.x, y.y, y.z, y.w};
#pragma unroll
  for (int i = 0; i < 8; ++i) {
    short hh = f2bf(v[i]);
    h[i] = hh;
    l[i] = f2bf(v[i] - bf2f(hh));
  }
}

// -------- X prep: concat(cls,feats) per batch -> packed hi/lo bf16 -------
// X row r (0..4095): b=r>>10, rr=r&1023; rr<256 -> cls[b][rr], else feats.
__global__ __launch_bounds__(256) void xprep(const float* __restrict__ cls,
                                             const float* __restrict__ feats,
                                             short* __restrict__ Xh,
                                             short* __restrict__ Xl) {
  const size_t base = ((size_t)blockIdx.x * 256 + threadIdx.x) * 8;
  const int row = (int)(base / DDIM);
  const int col = (int)(base % DDIM);
  const int b = row >> 10, rr = row & 1023;
  const float* src = (rr < NCLS)
                         ? cls + ((size_t)b * NCLS + rr) * DDIM + col
                         : feats + ((size_t)b * NFEAT + (rr - NCLS)) * DDIM + col;
  float4 a0 = *(const float4*)(src);
  float4 a1 = *(const float4*)(src + 4);
  s16x8 h, l;
  cvt8(a0, a1, h, l);
  *(s16x8*)(Xh + base) = h;
  *(s16x8*)(Xl + base) = l;
}

// -------- transpose + bf16-convert weights (z: 0=Wh split,1=Wt split,
//          2=L1 plain,3=L2 plain) --------
__global__ __launch_bounds__(256) void prep_weights(
    const float* __restrict__ w0, const float* __restrict__ w1,
    const float* __restrict__ w2, const float* __restrict__ w3,
    short* __restrict__ h0, short* __restrict__ h1, short* __restrict__ h2,
    short* __restrict__ h3, short* __restrict__ l0, short* __restrict__ l1) {
  __shared__ float tile[32][33];
  const int z = blockIdx.z;
  const float* s = z == 0 ? w0 : z == 1 ? w1 : z == 2 ? w2 : w3;
  short* dh = z == 0 ? h0 : z == 1 ? h1 : z == 2 ? h2 : h3;
  short* dl = z == 0 ? l0 : z == 1 ? l1 : nullptr;
  const int tx = threadIdx.x & 31, ty0 = threadIdx.x >> 5;
  const int r0 = blockIdx.y * 32, c0 = blockIdx.x * 32;
#pragma unroll
  for (int i = 0; i < 4; ++i) {
    int ty = ty0 + i * 8;
    tile[ty][tx] = s[(size_t)(r0 + ty) * DDIM + c0 + tx];
  }
  __syncthreads();
#pragma unroll
  for (int i = 0; i < 4; ++i) {
    int ty = ty0 + i * 8;
    float v = tile[tx][ty];
    short hh = f2bf(v);
    dh[(size_t)(c0 + ty) * DDIM + r0 + tx] = hh;
    if (dl) dl[(size_t)(c0 + ty) * DDIM + r0 + tx] = f2bf(v - bf2f(hh));
  }
}

// -------- front GEMM (fused e_h | e_t), 64x64 tiles, split-bf16,
//          pure-bf16 staging + double-buffered LDS (1 barrier/k-step),
//          XCD-chunked 1D grid (960 = 8 XCD x 120) --------
__global__ __launch_bounds__(256) void gemm_front(
    const short* __restrict__ Xh, const short* __restrict__ Xl,
    const short* __restrict__ WhT_h, const short* __restrict__ WhT_l,
    const float* __restrict__ Whb, const short* __restrict__ WtT_h,
    const short* __restrict__ WtT_l, const float* __restrict__ Wtb,
    float* __restrict__ e_h, short* __restrict__ eh_hi,
    short* __restrict__ eh_lo, float* __restrict__ e_t,
    short* __restrict__ et_hi, short* __restrict__ et_lo) {
  __shared__ short Ah[2][64 * 40], Al[2][64 * 40];
  __shared__ short Bh[2][64 * 40], Bl[2][64 * 40];
  const int bid = blockIdx.x;
  const int xcd = bid & 7, idx = bid >> 3;  // idx 0..119
  const int ytile = xcd * 10 + idx / 12;
  const int xtile = idx % 12;
  const int t = threadIdx.x;
  const int row0 = ytile * 64, col0 = xtile * 64;
  const bool head = row0 < 1024;
  const int sr = t >> 2, sk = (t & 3) * 8;

  size_t xrow = head ? (size_t)(((row0 >> 8) << 10) + (row0 & 255) + sr)
                     : (size_t)(row0 - 1024 + sr);
  const short* aph = Xh + xrow * DDIM + sk;
  const short* apl = Xl + xrow * DDIM + sk;
  const short* bph = (head ? WhT_h : WtT_h) + (size_t)(col0 + sr) * DDIM + sk;
  const short* bpl = (head ? WhT_l : WtT_l) + (size_t)(col0 + sr) * DDIM + sk;
  const float* biasu = head ? Whb : Wtb;

  const int lane = t & 63, wave = t >> 6;
  const int wr = wave >> 1, wc = wave & 1;
  const int fr = lane & 15, fq = lane >> 4;
  const int so = sr * 40 + sk;

  f32x4 acc[2][2] = {};
  s16x8 ra = *(const s16x8*)(aph);
  s16x8 rla = *(const s16x8*)(apl);
  s16x8 rb = *(const s16x8*)(bph);
  s16x8 rlb = *(const s16x8*)(bpl);

  for (int kt = 0; kt < 24; ++kt) {
    const int cur = kt & 1;
    *(s16x8*)&Ah[cur][so] = ra;
    *(s16x8*)&Al[cur][so] = rla;
    *(s16x8*)&Bh[cur][so] = rb;
    *(s16x8*)&Bl[cur][so] = rlb;
    __syncthreads();
    const int kn = (kt < 23 ? kt + 1 : 23) * 32;
    ra = *(const s16x8*)(aph + kn);
    rla = *(const s16x8*)(apl + kn);
    rb = *(const s16x8*)(bph + kn);
    rlb = *(const s16x8*)(bpl + kn);
#pragma unroll
    for (int n = 0; n < 2; ++n) {
      int bo = (wc * 32 + n * 16 + fr) * 40 + fq * 8;
      s16x8 bfh = *(const s16x8*)&Bh[cur][bo];
      s16x8 bfl = *(const s16x8*)&Bl[cur][bo];
#pragma unroll
      for (int m = 0; m < 2; ++m) {
        int ao = (wr * 32 + m * 16 + fr) * 40 + fq * 8;
        s16x8 afh = *(const s16x8*)&Ah[cur][ao];
        s16x8 afl = *(const s16x8*)&Al[cur][ao];
        acc[m][n] =
            __builtin_amdgcn_mfma_f32_16x16x32_bf16(afh, bfh, acc[m][n], 0, 0, 0);
        acc[m][n] =
            __builtin_amdgcn_mfma_f32_16x16x32_bf16(afh, bfl, acc[m][n], 0, 0, 0);
        acc[m][n] =
            __builtin_amdgcn_mfma_f32_16x16x32_bf16(afl, bfh, acc[m][n], 0, 0, 0);
      }
    }
  }

  float* Cf = head ? e_h : e_t;
  short* Ch = head ? eh_hi : et_hi;
  short* Cl = head ? eh_lo : et_lo;
  const int rbase = head ? row0 : row0 - 1024;
#pragma unroll
  for (int m = 0; m < 2; ++m) {
#pragma unroll
    for (int n = 0; n < 2; ++n) {
#pragma unroll
      for (int r = 0; r < 4; ++r) {
        int rg = rbase + wr * 32 + m * 16 + fq * 4 + r;
        int cg = col0 + wc * 32 + n * 16 + fr;
        float v = acc[m][n][r] + biasu[cg];
        size_t o = (size_t)rg * DDIM + cg;
        Cf[o] = v;
        short hh = f2bf(v);
        Ch[o] = hh;
        Cl[o] = f2bf(v - bf2f(hh));
      }
    }
  }
}

// -------- logits GEMM: 32x64 tiles, dbuf, 512 blocks, batch->XCD ---------
__global__ __launch_bounds__(256) void gemm_logits(
    const short* __restrict__ eh_hi, const short* __restrict__ eh_lo,
    const short* __restrict__ et_hi, const short* __restrict__ et_lo,
    float* __restrict__ logits, float scale) {
  __shared__ short Ah[2][32 * 40], Al[2][32 * 40];
  __shared__ short Bh[2][64 * 40], Bl[2][64 * 40];
  const int bid = blockIdx.x;
  const int xcd = bid & 7, idx = bid >> 3;
  const int batch = xcd >> 1;
  const int sub = ((xcd & 1) << 6) | idx;
  const int xtile = sub & 15, ytile = sub >> 4;
  const int row0 = ytile * 32, col0 = xtile * 64;
  const int t = threadIdx.x;

  const int ahalf = t >> 7, ac = t & 127;
  const int asr = ac >> 2, ask = (ac & 3) * 8;
  const short* aptr = (ahalf ? eh_lo : eh_hi) +
                      ((size_t)batch * NCLS + row0 + asr) * DDIM + ask;
  const int aso = asr * 40 + ask;
  const int bsr = t >> 2, bsk = (t & 3) * 8;
  const short* bph = et_hi + ((size_t)batch * NTOK + col0 + bsr) * DDIM + bsk;
  const short* bpl = et_lo + ((size_t)batch * NTOK + col0 + bsr) * DDIM + bsk;
  const int bso = bsr * 40 + bsk;

  const int lane = t & 63, wave = t >> 6;
  const int wr = wave >> 1, wc = wave & 1;
  const int fr = lane & 15, fq = lane >> 4;

  f32x4 acc[2] = {};
  s16x8 rA = *(const s16x8*)(aptr);
  s16x8 rbh = *(const s16x8*)(bph);
  s16x8 rbl = *(const s16x8*)(bpl);

  for (int kt = 0; kt < 24; ++kt) {
    const int cur = kt & 1;
    *(s16x8*)&(ahalf ? Al : Ah)[cur][aso] = rA;
    *(s16x8*)&Bh[cur][bso] = rbh;
    *(s16x8*)&Bl[cur][bso] = rbl;
    __syncthreads();
    const int kn = (kt < 23 ? kt + 1 : 23) * 32;
    rA = *(const s16x8*)(aptr + kn);
    rbh = *(const s16x8*)(bph + kn);
    rbl = *(const s16x8*)(bpl + kn);
    int ao = (wr * 16 + fr) * 40 + fq * 8;
    s16x8 afh = *(const s16x8*)&Ah[cur][ao];
    s16x8 afl = *(const s16x8*)&Al[cur][ao];
#pragma unroll
    for (int n = 0; n < 2; ++n) {
      int bo = (wc * 32 + n * 16 + fr) * 40 + fq * 8;
      s16x8 bfh = *(const s16x8*)&Bh[cur][bo];
      s16x8 bfl = *(const s16x8*)&Bl[cur][bo];
      acc[n] = __builtin_amdgcn_mfma_f32_16x16x32_bf16(afh, bfh, acc[n], 0, 0, 0);
      acc[n] = __builtin_amdgcn_mfma_f32_16x16x32_bf16(afh, bfl, acc[n], 0, 0, 0);
      acc[n] = __builtin_amdgcn_mfma_f32_16x16x32_bf16(afl, bfh, acc[n], 0, 0, 0);
    }
  }

  float* Cb = logits + (size_t)batch * NCLS * NTOK;
#pragma unroll
  for (int n = 0; n < 2; ++n)
#pragma unroll
    for (int r = 0; r < 4; ++r) {
      int rg = row0 + wr * 16 + fq * 4 + r;
      int cg = col0 + wc * 32 + n * 16 + fr;
      Cb[(size_t)rg * NTOK + cg] = scale * acc[n][r];
    }
}

// -------- lin GEMM (fused lin1/lin2), 64x64, dbuf, plain bf16, leaky,
//          XCD-chunked (384 = 8 x 48) ----------
__global__ __launch_bounds__(256) void gemm_lin(
    const short* __restrict__ inbf, const short* __restrict__ L1T,
    const short* __restrict__ L2T, const float* __restrict__ b1,
    const float* __restrict__ b2, float* __restrict__ C) {
  __shared__ short Ah[2][64 * 40], Bh[2][64 * 40];
  const int bid = blockIdx.x;
  const int xcd = bid & 7, idx = bid >> 3;
  const int ytile = xcd * 4 + idx / 12, xtile = idx % 12;
  const int t = threadIdx.x;
  const int row0 = ytile * 64, col0 = xtile * 64;
  const bool second = row0 >= 1024;
  const int sr = t >> 2, sk = (t & 3) * 8;
  const short* aptr = inbf + (size_t)(row0 + sr) * DDIM + sk;
  const short* bptr = (second ? L2T : L1T) + (size_t)(col0 + sr) * DDIM + sk;
  const float* biasu = second ? b2 : b1;
  const int lane = t & 63, wave = t >> 6;
  const int wr = wave >> 1, wc = wave & 1;
  const int fr = lane & 15, fq = lane >> 4;
  const int so = sr * 40 + sk;

  f32x4 acc[2][2] = {};
  s16x8 rA = *(const s16x8*)(aptr);
  s16x8 rB = *(const s16x8*)(bptr);
  for (int kt = 0; kt < 24; ++kt) {
    const int cur = kt & 1;
    *(s16x8*)&Ah[cur][so] = rA;
    *(s16x8*)&Bh[cur][so] = rB;
    __syncthreads();
    const int kn = (kt < 23 ? kt + 1 : 23) * 32;
    rA = *(const s16x8*)(aptr + kn);
    rB = *(const s16x8*)(bptr + kn);
#pragma unroll
    for (int n = 0; n < 2; ++n) {
      int bo = (wc * 32 + n * 16 + fr) * 40 + fq * 8;
      s16x8 bfh = *(const s16x8*)&Bh[cur][bo];
#pragma unroll
      for (int m = 0; m < 2; ++m) {
        int ao = (wr * 32 + m * 16 + fr) * 40 + fq * 8;
        s16x8 afh = *(const s16x8*)&Ah[cur][ao];
        acc[m][n] =
            __builtin_amdgcn_mfma_f32_16x16x32_bf16(afh, bfh, acc[m][n], 0, 0, 0);
      }
    }
  }
#pragma unroll
  for (int m = 0; m < 2; ++m)
#pragma unroll
    for (int n = 0; n < 2; ++n)
#pragma unroll
      for (int r = 0; r < 4; ++r) {
        int rg = row0 + wr * 32 + m * 16 + fq * 4 + r;
        int cg = col0 + wc * 32 + n * 16 + fr;
        float v = acc[m][n][r] + biasu[cg];
        v = v > 0.f ? v : 0.01f * v;
        C[(size_t)rg * DDIM + cg] = v;
      }
}

// -------- top-k via 4-round byte radix select (set semantics) ------------
__global__ __launch_bounds__(256) void topk_select(
    const float* __restrict__ logits, float* __restrict__ tw,
    int* __restrict__ ti) {
  const int row = blockIdx.x;
  const int t = threadIdx.x;
  const int lane = t & 63, wave = t >> 6;
  __shared__ int hist[256];
  __shared__ int sh_bin, sh_rem;
  __shared__ int cnt;
  __shared__ int wsumT[4];

  float4 v4 = *(const float4*)(logits + (size_t)row * NTOK + 4 * t);
  float val[4] = {v4.x, v4.y, v4.z, v4.w};
  unsigned key[4];
#pragma unroll
  for (int i = 0; i < 4; ++i) {
    unsigned u = __float_as_uint(val[i]);
    key[i] = (u & 0x80000000u) ? ~u : (u | 0x80000000u);
  }

  unsigned pref = 0, mask = 0;
  int rem = KSEL;
#pragma unroll
  for (int shift = 24; shift >= 0; shift -= 8) {
    hist[t] = 0;
    __syncthreads();
#pragma unroll
    for (int i = 0; i < 4; ++i)
      if ((key[i] & mask) == pref)
        atomicAdd(&hist[(key[i] >> shift) & 255], 1);
    __syncthreads();
    if (wave == 0) {
      int h0 = hist[4 * lane], h1 = hist[4 * lane + 1];
      int h2 = hist[4 * lane + 2], h3 = hist[4 * lane + 3];
      int s = h0 + h1 + h2 + h3;
#pragma unroll
      for (int o = 1; o < 64; o <<= 1) {
        int v = __shfl_down(s, o, 64);
        if (lane + o < 64) s += v;
      }
      int abv = __shfl_down(s, 1, 64);
      if (lane == 63) abv = 0;
      int c3 = abv + h3, c2 = c3 + h2, c1 = c2 + h1, c0 = c1 + h0;
      int bin = -1, nab = 0;
      if (c3 >= rem && abv < rem) { bin = 4 * lane + 3; nab = abv; }
      else if (c2 >= rem && c3 < rem) { bin = 4 * lane + 2; nab = c3; }
      else if (c1 >= rem && c2 < rem) { bin = 4 * lane + 1; nab = c2; }
      else if (c0 >= rem && c1 < rem) { bin = 4 * lane + 0; nab = c1; }
      if (bin >= 0) { sh_bin = bin; sh_rem = rem - nab; }
    }
    __syncthreads();
    pref |= ((unsigned)sh_bin) << shift;
    mask |= 0xFFu << shift;
    rem = sh_rem;
  }

  const unsigned T = pref;
  const int above = KSEL - rem;

  if (t == 0) cnt = 0;
  int tc = 0;
#pragma unroll
  for (int i = 0; i < 4; ++i) tc += (key[i] == T);
  int inc = tc;
#pragma unroll
  for (int o = 1; o < 64; o <<= 1) {
    int v = __shfl_up(inc, o, 64);
    if (lane >= o) inc += v;
  }
  if (lane == 63) wsumT[wave] = inc;
  __syncthreads();
  int wbase = 0;
#pragma unroll
  for (int w = 0; w < 4; ++w)
    if (w < wave) wbase += wsumT[w];
  int excl = wbase + inc - tc;

  float* twr = tw + (size_t)row * KSEL;
  int* tir = ti + (size_t)row * KSEL;
#pragma unroll
  for (int i = 0; i < 4; ++i) {
    if (key[i] > T) {
      int slot = atomicAdd(&cnt, 1);
      twr[slot] = val[i];
      tir[slot] = 4 * t + i;
    } else if (key[i] == T) {
      int r = excl++;
      if (r < rem) {
        twr[above + r] = val[i];
        tir[above + r] = 4 * t + i;
      }
    }
  }
}

// -------- agg1: gated ka weights (2 blocks/row, XCD-batch affinity) ------
__global__ __launch_bounds__(256) void agg1(const float* __restrict__ e_h,
                                            const float* __restrict__ e_t,
                                            const float* __restrict__ tw,
                                            const int* __restrict__ ti,
                                            float* __restrict__ kaw_raw) {
  const int bid = blockIdx.x;
  const int xcd = bid & 7, slot = bid >> 3;
  const int batch = xcd >> 1;
  const int u = ((xcd & 1) << 8) | slot;
  const int row = batch * 256 + (u >> 1);
  const int half = u & 1;
  const int t = threadIdx.x, lane = t & 63, wave = t >> 6;
  __shared__ float p[KSEL];
  __shared__ int idxs[KSEL];
  __shared__ float red[2];

  if (t < KSEL) {
    p[t] = tw[(size_t)row * KSEL + t];
    idxs[t] = ti[(size_t)row * KSEL + t];
  }
  __syncthreads();
  if (wave == 0) {
    float m = wmaxr(fmaxf(p[lane], p[lane + 64]));
    if (!lane) red[0] = m;
  }
  __syncthreads();
  if (t < KSEL) p[t] = __expf(p[t] - red[0]);
  __syncthreads();
  if (wave == 0) {
    float s = wsum(p[lane] + p[lane + 64]);
    if (!lane) red[1] = s;
  }
  __syncthreads();
  if (t < KSEL) p[t] *= (1.f / red[1]);
  __syncthreads();

  float ehr[12];
  {
    const float* ehrow = e_h + (size_t)row * DDIM;
#pragma unroll
    for (int c = 0; c < 3; ++c) {
      float4 v = *(const float4*)(ehrow + 4 * lane + 256 * c);
      ehr[4 * c + 0] = v.x;
      ehr[4 * c + 1] = v.y;
      ehr[4 * c + 2] = v.z;
      ehr[4 * c + 3] = v.w;
    }
  }
  const float* etb = e_t + (size_t)batch * NTOK * DDIM;

  for (int i = 0; i < 16; ++i) {
    int j = half * 64 + wave * 16 + i;
    float pj = p[j];
    float a = 4.f - 2.f * pj, b2 = 2.f * pj;
    const float* nb = etb + (size_t)idxs[j] * DDIM;
    float partial = 0.f;
#pragma unroll
    for (int c = 0; c < 3; ++c) {
      float4 nv = *(const float4*)(nb + 4 * lane + 256 * c);
      float nq[4] = {nv.x, nv.y, nv.z, nv.w};
#pragma unroll
      for (int q = 0; q < 4; ++q) {
        float y2 = fmaf(a, ehr[4 * c + q], b2 * nq[q]);
        float ex = __expf(y2);
        float g = fmaf(-2.f, __builtin_amdgcn_rcpf(1.f + ex), 1.f);
        partial = fmaf(nq[q], g, partial);
      }
    }
    partial = wsum(partial);
    if (!lane) kaw_raw[(size_t)row * KSEL + j] = partial;
  }
}

// -------- agg2: ka softmax + weighted sum -> bf16 lin inputs -------------
__global__ __launch_bounds__(192) void agg2(
    const float* __restrict__ e_h, const float* __restrict__ e_t,
    const float* __restrict__ cls, const float* __restrict__ kaw_raw,
    const int* __restrict__ ti, short* __restrict__ inbf) {
  const int bid = blockIdx.x;
  const int xcd = bid & 7, slot = bid >> 3;
  const int batch = xcd >> 1;
  const int row = batch * 256 + (xcd & 1) * 128 + slot;
  const int t = threadIdx.x, lane = t & 63, wave = t >> 6;
  __shared__ float kp[KSEL];
  __shared__ int idxs[KSEL];
  __shared__ float red[2];

  if (t < KSEL) {
    kp[t] = kaw_raw[(size_t)row * KSEL + t];
    idxs[t] = ti[(size_t)row * KSEL + t];
  }
  __syncthreads();
  if (wave == 0) {
    float m = wmaxr(fmaxf(kp[lane], kp[lane + 64]));
    if (!lane) red[0] = m;
  }
  __syncthreads();
  if (t < KSEL) kp[t] = __expf(kp[t] - red[0]);
  __syncthreads();
  if (wave == 0) {
    float s = wsum(kp[lane] + kp[lane + 64]);
    if (!lane) red[1] = s;
  }
  __syncthreads();
  if (t < KSEL) kp[t] *= (1.f / red[1]);
  __syncthreads();

  const size_t o = (size_t)row * DDIM + 4 * t;
  float4 eh4 = *(const float4*)(e_h + o);
  float4 cl4 = *(const float4*)(cls + o);
  const float* etb = e_t + (size_t)batch * NTOK * DDIM;

  float ax = 0.f, ay = 0.f, az = 0.f, aw = 0.f;
#pragma unroll 8
  for (int j = 0; j < KSEL; ++j) {
    float pr = kp[j];
    float4 nb = *(const float4*)(etb + (size_t)idxs[j] * DDIM + 4 * t);
    ax = fmaf(pr, nb.x, ax);
    ay = fmaf(pr, nb.y, ay);
    az = fmaf(pr, nb.z, az);
    aw = fmaf(pr, nb.w, aw);
  }

  short4 sv, bv;
  sv.x = f2bf((eh4.x + ax) * 0.1f + cl4.x);
  sv.y = f2bf((eh4.y + ay) * 0.1f + cl4.y);
  sv.z = f2bf((eh4.z + az) * 0.1f + cl4.z);
  sv.w = f2bf((eh4.w + aw) * 0.1f + cl4.w);
  bv.x = f2bf((eh4.x * ax) * 0.1f + cl4.x);
  bv.y = f2bf((eh4.y * ay) * 0.1f + cl4.y);
  bv.z = f2bf((eh4.z * az) * 0.1f + cl4.z);
  bv.w = f2bf((eh4.w * aw) * 0.1f + cl4.w);
  *(short4*)&inbf[o] = sv;
  *(short4*)&inbf[(size_t)(NBATCH * NCLS) * DDIM + o] = bv;
}

// -------- layernorm over D=768 on (embA[row] + embB[row]) --------
__global__ __launch_bounds__(256) void ln_kernel(const float* __restrict__ embA,
                                                 const float* __restrict__ embB,
                                                 const float* __restrict__ lw,
                                                 const float* __restrict__ lb,
                                                 float* __restrict__ out) {
  const int row = blockIdx.x;
  const int t = threadIdx.x;
  const int lane = t & 63, wave = t >> 6;
  __shared__ float red[4];
  __shared__ float bs[2];
  float e[3];
#pragma unroll
  for (int c = 0; c < 3; ++c) {
    size_t o = (size_t)row * DDIM + t + 256 * c;
    e[c] = embA[o] + embB[o];
  }
  float s = e[0] + e[1] + e[2];
  s = wsum(s);
  if (lane == 0) red[wave] = s;
  __syncthreads();
  if (t == 0) bs[0] = (red[0] + red[1] + red[2] + red[3]) * (1.f / DDIM);
  __syncthreads();
  float mu = bs[0];
  float q = 0.f;
#pragma unroll
  for (int c = 0; c < 3; ++c) {
    float d = e[c] - mu;
    q = fmaf(d, d, q);
  }
  q = wsum(q);
  if (lane == 0) red[wave] = q;
  __syncthreads();
  if (t == 0) bs[1] = (red[0] + red[1] + red[2] + red[3]) * (1.f / DDIM);
  __syncthreads();
  float rstd = rsqrtf(bs[1] + 1e-5f);
#pragma unroll
  for (int c = 0; c < 3; ++c) {
    int d = t + 256 * c;
    out[(size_t)row * DDIM + d] = (e[c] - mu) * rstd * lw[d] + lb[d];
  }
}

// ---------------- launch ----------------
extern "C" void kernel_launch(void* const* d_in, const int* in_sizes, int n_in,
                              void* d_out, int out_size, void* d_ws,
                              size_t ws_size, hipStream_t stream) {
  const float* cls = (const float*)d_in[0];
  const float* feats = (const float*)d_in[1];
  const float* Whw = (const float*)d_in[2];
  const float* Whb = (const float*)d_in[3];
  const float* Wtw = (const float*)d_in[4];
  const float* Wtb = (const float*)d_in[5];
  const float* l1w = (const float*)d_in[6];
  const float* l1b = (const float*)d_in[7];
  const float* l2w = (const float*)d_in[8];
  const float* l2b = (const float*)d_in[9];
  const float* lnw = (const float*)d_in[10];
  const float* lnb = (const float*)d_in[11];
  float* out = (float*)d_out;

  float* ws = (float*)d_ws;
  // layout (float units)
  float* e_h = ws;                          // 786432
  float* e_t = ws + 786432;                 // 3145728
  short* eh_hi = (short*)(ws + 3932160);    // 786432 shorts
  short* eh_lo = eh_hi + 786432;            // (ends 4718592f)
  short* et_hi = (short*)(ws + 4718592);    // 3145728 shorts
  short* et_lo = et_hi + 3145728;           // (ends 7864320f)
  short* WhT_h = (short*)(ws + 7864320);    // 589824 shorts each
  short* WhT_l = WhT_h + 589824;
  short* WtT_h = WhT_h + 2 * 589824;
  short* WtT_l = WhT_h + 3 * 589824;        // (ends 9043968f)
  short* L1T = (short*)(ws + 9043968);      // 589824 shorts
  short* L2T = L1T + 589824;                // (ends 9633792f)
  float* logits = ws + 7864320;             // overlays WhT/WtT (dead by then)
  // X (bf16 hi/lo of concat inputs) lives only until gemm_front completes,
  // then its region is reused for tw/ti/kaw/inbf (all written after front).
  short* Xh = (short*)(ws + 9633792);       // 3145728 shorts (1572864 f)
  short* Xl = Xh + 3145728;                 // (ends 12779520f)
  float* tw = ws + 9633792;                 // 131072 (overlays Xh - X dead)
  int* ti = (int*)(ws + 9764864);           // 131072
  float* kaw = ws + 9895936;                // 131072
  short* inbf = (short*)(ws + 10027008);    // 2048*768 shorts (786432 f)
  float* linC = e_t;                        // overlays e_t (dead after agg2)
  (void)ws_size;
  (void)in_sizes;
  (void)n_in;
  (void)out_size;

  const float scale = 0.036084391824351615f;  // 1/sqrt(768)
  dim3 blk(256);

  // X -> packed bf16 hi/lo (4096 rows x 768)
  xprep<<<dim3(1536), blk, 0, stream>>>(cls, feats, Xh, Xl);
  // weights -> transposed bf16 (hi/lo for Wh/Wt, plain for L1/L2)
  prep_weights<<<dim3(24, 24, 4), blk, 0, stream>>>(
      Whw, Wtw, l1w, l2w, WhT_h, WtT_h, L1T, L2T, WhT_l, WtT_l);
  // fused e_h | e_t (960 blocks, XCD-chunked, dbuf)
  gemm_front<<<dim3(960), blk, 0, stream>>>(
      Xh, Xl, WhT_h, WhT_l, Whb, WtT_h, WtT_l, Wtb, e_h, eh_hi, eh_lo, e_t,
      et_hi, et_lo);
  // logits[b] = scale * e_h[b] @ e_t[b]^T (512 blocks, batch->XCD, dbuf)
  gemm_logits<<<dim3(512), blk, 0, stream>>>(eh_hi, eh_lo, et_hi, et_lo,
                                             logits, scale);
  // top-128 per row (radix select)
  topk_select<<<dim3(NBATCH * NCLS), blk, 0, stream>>>(logits, tw, ti);
  // agg1: gated ka weights (2048 blocks)
  agg1<<<dim3(2048), blk, 0, stream>>>(e_h, e_t, tw, ti, kaw);
  // agg2: softmax + weighted sum -> bf16 lin inputs
  agg2<<<dim3(1024), dim3(192), 0, stream>>>(e_h, e_t, cls, kaw, ti, inbf);
  // fused lin1/lin2 (384 blocks, XCD-chunked, dbuf)
  gemm_lin<<<dim3(384), blk, 0, stream>>>(inbf, L1T, L2T, l1b, l2b, linC);
  // layernorm(sum_emb + bi_emb) -> out
  ln_kernel<<<dim3(NBATCH * NCLS), blk, 0, stream>>>(
      linC, linC + (size_t)(NBATCH * NCLS) * DDIM, lnw, lnb, out);
}

// Round 8
// 133.774 us; speedup vs baseline: 1.0272x; 1.0272x over previous
//
#include <hip/hip_runtime.h>
#include <hip/hip_bf16.h>
#include <math.h>

#define DDIM 768
#define NCLS 256
#define NFEAT 768
#define NTOK 1024
#define NBATCH 4
#define KSEL 128

typedef float f32x4 __attribute__((ext_vector_type(4)));
typedef short s16x8 __attribute__((ext_vector_type(8)));

// ---------------- helpers ----------------
__device__ __forceinline__ float wsum(float v) {
#pragma unroll
  for (int o = 32; o; o >>= 1) v += __shfl_down(v, o, 64);
  return v;
}
__device__ __forceinline__ float wmaxr(float v) {
#pragma unroll
  for (int o = 32; o; o >>= 1) v = fmaxf(v, __shfl_down(v, o, 64));
  return v;
}
__device__ __forceinline__ short f2bf(float f) {
  union { __hip_bfloat16 h; short s; } u;
  u.h = __float2bfloat16(f);
  return u.s;
}
__device__ __forceinline__ float bf2f(short s) {
  union { unsigned u; float f; } c;
  c.u = ((unsigned)(unsigned short)s) << 16;
  return c.f;
}
__device__ __forceinline__ void cvt8(float4 x, float4 y, s16x8& h, s16x8& l) {
  float v[8] = {x.x, x.y, x.z, x.w, y.x, y.y, y.z, y.w};
#pragma unroll
  for (int i = 0; i < 8; ++i) {
    short hh = f2bf(v[i]);
    h[i] = hh;
    l[i] = f2bf(v[i] - bf2f(hh));
  }
}

// -------- X prep: concat(cls,feats) per batch -> packed hi/lo bf16 -------
__global__ __launch_bounds__(256) void xprep(const float* __restrict__ cls,
                                             const float* __restrict__ feats,
                                             short* __restrict__ Xh,
                                             short* __restrict__ Xl) {
  const size_t base = ((size_t)blockIdx.x * 256 + threadIdx.x) * 8;
  const int row = (int)(base / DDIM);
  const int col = (int)(base % DDIM);
  const int b = row >> 10, rr = row & 1023;
  const float* src = (rr < NCLS)
                         ? cls + ((size_t)b * NCLS + rr) * DDIM + col
                         : feats + ((size_t)b * NFEAT + (rr - NCLS)) * DDIM + col;
  float4 a0 = *(const float4*)(src);
  float4 a1 = *(const float4*)(src + 4);
  s16x8 h, l;
  cvt8(a0, a1, h, l);
  *(s16x8*)(Xh + base) = h;
  *(s16x8*)(Xl + base) = l;
}

// -------- transpose + bf16-convert weights (z: 0=Wh split,1=Wt split,
//          2=L1 plain,3=L2 plain) --------
__global__ __launch_bounds__(256) void prep_weights(
    const float* __restrict__ w0, const float* __restrict__ w1,
    const float* __restrict__ w2, const float* __restrict__ w3,
    short* __restrict__ h0, short* __restrict__ h1, short* __restrict__ h2,
    short* __restrict__ h3, short* __restrict__ l0, short* __restrict__ l1) {
  __shared__ float tile[32][33];
  const int z = blockIdx.z;
  const float* s = z == 0 ? w0 : z == 1 ? w1 : z == 2 ? w2 : w3;
  short* dh = z == 0 ? h0 : z == 1 ? h1 : z == 2 ? h2 : h3;
  short* dl = z == 0 ? l0 : z == 1 ? l1 : nullptr;
  const int tx = threadIdx.x & 31, ty0 = threadIdx.x >> 5;
  const int r0 = blockIdx.y * 32, c0 = blockIdx.x * 32;
#pragma unroll
  for (int i = 0; i < 4; ++i) {
    int ty = ty0 + i * 8;
    tile[ty][tx] = s[(size_t)(r0 + ty) * DDIM + c0 + tx];
  }
  __syncthreads();
#pragma unroll
  for (int i = 0; i < 4; ++i) {
    int ty = ty0 + i * 8;
    float v = tile[tx][ty];
    short hh = f2bf(v);
    dh[(size_t)(c0 + ty) * DDIM + r0 + tx] = hh;
    if (dl) dl[(size_t)(c0 + ty) * DDIM + r0 + tx] = f2bf(v - bf2f(hh));
  }
}

// -------- front GEMM (fused e_h | e_t), 128x64 tiles, split-bf16,
//          single-buffer LDS with load-after-store overlap,
//          XCD-chunked 1D grid (480 = 8 XCD x 60) --------
__global__ __launch_bounds__(256) void gemm_front(
    const short* __restrict__ Xh, const short* __restrict__ Xl,
    const short* __restrict__ WhT_h, const short* __restrict__ WhT_l,
    const float* __restrict__ Whb, const short* __restrict__ WtT_h,
    const short* __restrict__ WtT_l, const float* __restrict__ Wtb,
    float* __restrict__ e_h, short* __restrict__ eh_hi,
    short* __restrict__ eh_lo, float* __restrict__ e_t,
    short* __restrict__ et_hi, short* __restrict__ et_lo) {
  __shared__ short Ah[128 * 40], Al[128 * 40];
  __shared__ short Bh[64 * 40], Bl[64 * 40];
  const int bid = blockIdx.x;
  const int xcd = bid & 7, idx = bid >> 3;  // idx 0..59
  const int ytile = xcd * 5 + idx / 12;     // 0..39
  const int xtile = idx % 12;
  const int t = threadIdx.x;
  const int row0 = ytile * 128, col0 = xtile * 64;
  const bool head = row0 < 1024;

  // A staging: row = t>>1 (0..127), k-half = (t&1)*16
  const int ar = t >> 1, ak = (t & 1) * 16;
  size_t xrow;
  {
    int gr = row0 + ar;
    xrow = head ? (size_t)(((gr >> 8) << 10) + (gr & 255)) : (size_t)(gr - 1024);
  }
  const short* aph = Xh + xrow * DDIM + ak;
  const short* apl = Xl + xrow * DDIM + ak;
  // B staging: row = t>>2 (0..63), k-off = (t&3)*8
  const int br = t >> 2, bk = (t & 3) * 8;
  const short* bph = (head ? WhT_h : WtT_h) + (size_t)(col0 + br) * DDIM + bk;
  const short* bpl = (head ? WhT_l : WtT_l) + (size_t)(col0 + br) * DDIM + bk;
  const float* biasu = head ? Whb : Wtb;

  const int lane = t & 63, wave = t >> 6;
  const int wr = wave >> 1, wc = wave & 1;  // wave tile: 64 rows x 32 cols
  const int fr = lane & 15, fq = lane >> 4;

  f32x4 acc[4][2] = {};
  s16x8 rah0 = *(const s16x8*)(aph);
  s16x8 rah1 = *(const s16x8*)(aph + 8);
  s16x8 ral0 = *(const s16x8*)(apl);
  s16x8 ral1 = *(const s16x8*)(apl + 8);
  s16x8 rbh = *(const s16x8*)(bph);
  s16x8 rbl = *(const s16x8*)(bpl);

  for (int kt = 0; kt < 24; ++kt) {
    __syncthreads();  // previous iteration's LDS reads complete
    *(s16x8*)&Ah[ar * 40 + ak] = rah0;
    *(s16x8*)&Ah[ar * 40 + ak + 8] = rah1;
    *(s16x8*)&Al[ar * 40 + ak] = ral0;
    *(s16x8*)&Al[ar * 40 + ak + 8] = ral1;
    *(s16x8*)&Bh[br * 40 + bk] = rbh;
    *(s16x8*)&Bl[br * 40 + bk] = rbl;
    __syncthreads();
    const int kn = (kt < 23 ? kt + 1 : 23) * 32;  // prefetch next k-step
    rah0 = *(const s16x8*)(aph + kn);
    rah1 = *(const s16x8*)(aph + kn + 8);
    ral0 = *(const s16x8*)(apl + kn);
    ral1 = *(const s16x8*)(apl + kn + 8);
    rbh = *(const s16x8*)(bph + kn);
    rbl = *(const s16x8*)(bpl + kn);

    s16x8 afh[4], afl[4];
#pragma unroll
    for (int m = 0; m < 4; ++m) {
      int ao = (wr * 64 + m * 16 + fr) * 40 + fq * 8;
      afh[m] = *(const s16x8*)&Ah[ao];
      afl[m] = *(const s16x8*)&Al[ao];
    }
#pragma unroll
    for (int n = 0; n < 2; ++n) {
      int bo = (wc * 32 + n * 16 + fr) * 40 + fq * 8;
      s16x8 bfh = *(const s16x8*)&Bh[bo];
      s16x8 bfl = *(const s16x8*)&Bl[bo];
#pragma unroll
      for (int m = 0; m < 4; ++m) {
        acc[m][n] =
            __builtin_amdgcn_mfma_f32_16x16x32_bf16(afh[m], bfh, acc[m][n], 0, 0, 0);
        acc[m][n] =
            __builtin_amdgcn_mfma_f32_16x16x32_bf16(afh[m], bfl, acc[m][n], 0, 0, 0);
        acc[m][n] =
            __builtin_amdgcn_mfma_f32_16x16x32_bf16(afl[m], bfh, acc[m][n], 0, 0, 0);
      }
    }
  }

  float* Cf = head ? e_h : e_t;
  short* Ch = head ? eh_hi : et_hi;
  short* Cl = head ? eh_lo : et_lo;
  const int rbase = head ? row0 : row0 - 1024;
#pragma unroll
  for (int m = 0; m < 4; ++m) {
#pragma unroll
    for (int n = 0; n < 2; ++n) {
#pragma unroll
      for (int r = 0; r < 4; ++r) {
        int rg = rbase + wr * 64 + m * 16 + fq * 4 + r;
        int cg = col0 + wc * 32 + n * 16 + fr;
        float v = acc[m][n][r] + biasu[cg];
        size_t o = (size_t)rg * DDIM + cg;
        Cf[o] = v;
        short hh = f2bf(v);
        Ch[o] = hh;
        Cl[o] = f2bf(v - bf2f(hh));
      }
    }
  }
}

// -------- logits GEMM: 32x64 tiles, 512 blocks, batch->XCD affinity,
//          single-buffer + overlap --------
__global__ __launch_bounds__(256) void gemm_logits(
    const short* __restrict__ eh_hi, const short* __restrict__ eh_lo,
    const short* __restrict__ et_hi, const short* __restrict__ et_lo,
    float* __restrict__ logits, float scale) {
  __shared__ short Ah[32 * 40], Al[32 * 40];
  __shared__ short Bh[64 * 40], Bl[64 * 40];
  const int bid = blockIdx.x;
  const int xcd = bid & 7, idx = bid >> 3;
  const int batch = xcd >> 1;
  const int sub = ((xcd & 1) << 6) | idx;
  const int xtile = sub & 15, ytile = sub >> 4;
  const int row0 = ytile * 32, col0 = xtile * 64;
  const int t = threadIdx.x;

  const int ahalf = t >> 7, ac = t & 127;
  const int asr = ac >> 2, ask = (ac & 3) * 8;
  const short* aptr = (ahalf ? eh_lo : eh_hi) +
                      ((size_t)batch * NCLS + row0 + asr) * DDIM + ask;
  const int aso = asr * 40 + ask;
  const int bsr = t >> 2, bsk = (t & 3) * 8;
  const short* bph = et_hi + ((size_t)batch * NTOK + col0 + bsr) * DDIM + bsk;
  const short* bpl = et_lo + ((size_t)batch * NTOK + col0 + bsr) * DDIM + bsk;
  const int bso = bsr * 40 + bsk;

  const int lane = t & 63, wave = t >> 6;
  const int wr = wave >> 1, wc = wave & 1;
  const int fr = lane & 15, fq = lane >> 4;

  f32x4 acc[2] = {};
  s16x8 rA = *(const s16x8*)(aptr);
  s16x8 rbh = *(const s16x8*)(bph);
  s16x8 rbl = *(const s16x8*)(bpl);

  for (int kt = 0; kt < 24; ++kt) {
    __syncthreads();
    *(s16x8*)&(ahalf ? Al : Ah)[aso] = rA;
    *(s16x8*)&Bh[bso] = rbh;
    *(s16x8*)&Bl[bso] = rbl;
    __syncthreads();
    const int kn = (kt < 23 ? kt + 1 : 23) * 32;
    rA = *(const s16x8*)(aptr + kn);
    rbh = *(const s16x8*)(bph + kn);
    rbl = *(const s16x8*)(bpl + kn);
    int ao = (wr * 16 + fr) * 40 + fq * 8;
    s16x8 afh = *(const s16x8*)&Ah[ao];
    s16x8 afl = *(const s16x8*)&Al[ao];
#pragma unroll
    for (int n = 0; n < 2; ++n) {
      int bo = (wc * 32 + n * 16 + fr) * 40 + fq * 8;
      s16x8 bfh = *(const s16x8*)&Bh[bo];
      s16x8 bfl = *(const s16x8*)&Bl[bo];
      acc[n] = __builtin_amdgcn_mfma_f32_16x16x32_bf16(afh, bfh, acc[n], 0, 0, 0);
      acc[n] = __builtin_amdgcn_mfma_f32_16x16x32_bf16(afh, bfl, acc[n], 0, 0, 0);
      acc[n] = __builtin_amdgcn_mfma_f32_16x16x32_bf16(afl, bfh, acc[n], 0, 0, 0);
    }
  }

  float* Cb = logits + (size_t)batch * NCLS * NTOK;
#pragma unroll
  for (int n = 0; n < 2; ++n)
#pragma unroll
    for (int r = 0; r < 4; ++r) {
      int rg = row0 + wr * 16 + fq * 4 + r;
      int cg = col0 + wc * 32 + n * 16 + fr;
      Cb[(size_t)rg * NTOK + cg] = scale * acc[n][r];
    }
}

// -------- lin GEMM (fused lin1/lin2), 64x64, plain bf16, leaky,
//          single-buffer + overlap, XCD-chunked (384 = 8 x 48) -----------
__global__ __launch_bounds__(256) void gemm_lin(
    const short* __restrict__ inbf, const short* __restrict__ L1T,
    const short* __restrict__ L2T, const float* __restrict__ b1,
    const float* __restrict__ b2, float* __restrict__ C) {
  __shared__ short Ah[64 * 40], Bh[64 * 40];
  const int bid = blockIdx.x;
  const int xcd = bid & 7, idx = bid >> 3;
  const int ytile = xcd * 4 + idx / 12, xtile = idx % 12;
  const int t = threadIdx.x;
  const int row0 = ytile * 64, col0 = xtile * 64;
  const bool second = row0 >= 1024;
  const int sr = t >> 2, sk = (t & 3) * 8;
  const short* aptr = inbf + (size_t)(row0 + sr) * DDIM + sk;
  const short* bptr = (second ? L2T : L1T) + (size_t)(col0 + sr) * DDIM + sk;
  const float* biasu = second ? b2 : b1;
  const int lane = t & 63, wave = t >> 6;
  const int wr = wave >> 1, wc = wave & 1;
  const int fr = lane & 15, fq = lane >> 4;
  const int so = sr * 40 + sk;

  f32x4 acc[2][2] = {};
  s16x8 rA = *(const s16x8*)(aptr);
  s16x8 rB = *(const s16x8*)(bptr);
  for (int kt = 0; kt < 24; ++kt) {
    __syncthreads();
    *(s16x8*)&Ah[so] = rA;
    *(s16x8*)&Bh[so] = rB;
    __syncthreads();
    const int kn = (kt < 23 ? kt + 1 : 23) * 32;
    rA = *(const s16x8*)(aptr + kn);
    rB = *(const s16x8*)(bptr + kn);
#pragma unroll
    for (int n = 0; n < 2; ++n) {
      int bo = (wc * 32 + n * 16 + fr) * 40 + fq * 8;
      s16x8 bfh = *(const s16x8*)&Bh[bo];
#pragma unroll
      for (int m = 0; m < 2; ++m) {
        int ao = (wr * 32 + m * 16 + fr) * 40 + fq * 8;
        s16x8 afh = *(const s16x8*)&Ah[ao];
        acc[m][n] =
            __builtin_amdgcn_mfma_f32_16x16x32_bf16(afh, bfh, acc[m][n], 0, 0, 0);
      }
    }
  }
#pragma unroll
  for (int m = 0; m < 2; ++m)
#pragma unroll
    for (int n = 0; n < 2; ++n)
#pragma unroll
      for (int r = 0; r < 4; ++r) {
        int rg = row0 + wr * 32 + m * 16 + fq * 4 + r;
        int cg = col0 + wc * 32 + n * 16 + fr;
        float v = acc[m][n][r] + biasu[cg];
        v = v > 0.f ? v : 0.01f * v;
        C[(size_t)rg * DDIM + cg] = v;
      }
}

// -------- top-k via 4-round byte radix select (set semantics) ------------
__global__ __launch_bounds__(256) void topk_select(
    const float* __restrict__ logits, float* __restrict__ tw,
    int* __restrict__ ti) {
  const int row = blockIdx.x;
  const int t = threadIdx.x;
  const int lane = t & 63, wave = t >> 6;
  __shared__ int hist[256];
  __shared__ int sh_bin, sh_rem;
  __shared__ int cnt;
  __shared__ int wsumT[4];

  float4 v4 = *(const float4*)(logits + (size_t)row * NTOK + 4 * t);
  float val[4] = {v4.x, v4.y, v4.z, v4.w};
  unsigned key[4];
#pragma unroll
  for (int i = 0; i < 4; ++i) {
    unsigned u = __float_as_uint(val[i]);
    key[i] = (u & 0x80000000u) ? ~u : (u | 0x80000000u);
  }

  unsigned pref = 0, mask = 0;
  int rem = KSEL;
#pragma unroll
  for (int shift = 24; shift >= 0; shift -= 8) {
    hist[t] = 0;
    __syncthreads();
#pragma unroll
    for (int i = 0; i < 4; ++i)
      if ((key[i] & mask) == pref)
        atomicAdd(&hist[(key[i] >> shift) & 255], 1);
    __syncthreads();
    if (wave == 0) {
      int h0 = hist[4 * lane], h1 = hist[4 * lane + 1];
      int h2 = hist[4 * lane + 2], h3 = hist[4 * lane + 3];
      int s = h0 + h1 + h2 + h3;
#pragma unroll
      for (int o = 1; o < 64; o <<= 1) {
        int v = __shfl_down(s, o, 64);
        if (lane + o < 64) s += v;
      }
      int abv = __shfl_down(s, 1, 64);
      if (lane == 63) abv = 0;
      int c3 = abv + h3, c2 = c3 + h2, c1 = c2 + h1, c0 = c1 + h0;
      int bin = -1, nab = 0;
      if (c3 >= rem && abv < rem) { bin = 4 * lane + 3; nab = abv; }
      else if (c2 >= rem && c3 < rem) { bin = 4 * lane + 2; nab = c3; }
      else if (c1 >= rem && c2 < rem) { bin = 4 * lane + 1; nab = c2; }
      else if (c0 >= rem && c1 < rem) { bin = 4 * lane + 0; nab = c1; }
      if (bin >= 0) { sh_bin = bin; sh_rem = rem - nab; }
    }
    __syncthreads();
    pref |= ((unsigned)sh_bin) << shift;
    mask |= 0xFFu << shift;
    rem = sh_rem;
  }

  const unsigned T = pref;
  const int above = KSEL - rem;

  if (t == 0) cnt = 0;
  int tc = 0;
#pragma unroll
  for (int i = 0; i < 4; ++i) tc += (key[i] == T);
  int inc = tc;
#pragma unroll
  for (int o = 1; o < 64; o <<= 1) {
    int v = __shfl_up(inc, o, 64);
    if (lane >= o) inc += v;
  }
  if (lane == 63) wsumT[wave] = inc;
  __syncthreads();
  int wbase = 0;
#pragma unroll
  for (int w = 0; w < 4; ++w)
    if (w < wave) wbase += wsumT[w];
  int excl = wbase + inc - tc;

  float* twr = tw + (size_t)row * KSEL;
  int* tir = ti + (size_t)row * KSEL;
#pragma unroll
  for (int i = 0; i < 4; ++i) {
    if (key[i] > T) {
      int slot = atomicAdd(&cnt, 1);
      twr[slot] = val[i];
      tir[slot] = 4 * t + i;
    } else if (key[i] == T) {
      int r = excl++;
      if (r < rem) {
        twr[above + r] = val[i];
        tir[above + r] = 4 * t + i;
      }
    }
  }
}

// -------- agg1: gated ka weights (2 blocks/row, XCD-batch affinity) ------
__global__ __launch_bounds__(256) void agg1(const float* __restrict__ e_h,
                                            const float* __restrict__ e_t,
                                            const float* __restrict__ tw,
                                            const int* __restrict__ ti,
                                            float* __restrict__ kaw_raw) {
  const int bid = blockIdx.x;
  const int xcd = bid & 7, slot = bid >> 3;
  const int batch = xcd >> 1;
  const int u = ((xcd & 1) << 8) | slot;
  const int row = batch * 256 + (u >> 1);
  const int half = u & 1;
  const int t = threadIdx.x, lane = t & 63, wave = t >> 6;
  __shared__ float p[KSEL];
  __shared__ int idxs[KSEL];
  __shared__ float red[2];

  if (t < KSEL) {
    p[t] = tw[(size_t)row * KSEL + t];
    idxs[t] = ti[(size_t)row * KSEL + t];
  }
  __syncthreads();
  if (wave == 0) {
    float m = wmaxr(fmaxf(p[lane], p[lane + 64]));
    if (!lane) red[0] = m;
  }
  __syncthreads();
  if (t < KSEL) p[t] = __expf(p[t] - red[0]);
  __syncthreads();
  if (wave == 0) {
    float s = wsum(p[lane] + p[lane + 64]);
    if (!lane) red[1] = s;
  }
  __syncthreads();
  if (t < KSEL) p[t] *= (1.f / red[1]);
  __syncthreads();

  float ehr[12];
  {
    const float* ehrow = e_h + (size_t)row * DDIM;
#pragma unroll
    for (int c = 0; c < 3; ++c) {
      float4 v = *(const float4*)(ehrow + 4 * lane + 256 * c);
      ehr[4 * c + 0] = v.x;
      ehr[4 * c + 1] = v.y;
      ehr[4 * c + 2] = v.z;
      ehr[4 * c + 3] = v.w;
    }
  }
  const float* etb = e_t + (size_t)batch * NTOK * DDIM;

  for (int i = 0; i < 16; ++i) {
    int j = half * 64 + wave * 16 + i;
    float pj = p[j];
    float a = 4.f - 2.f * pj, b2 = 2.f * pj;
    const float* nb = etb + (size_t)idxs[j] * DDIM;
    float partial = 0.f;
#pragma unroll
    for (int c = 0; c < 3; ++c) {
      float4 nv = *(const float4*)(nb + 4 * lane + 256 * c);
      float nq[4] = {nv.x, nv.y, nv.z, nv.w};
#pragma unroll
      for (int q = 0; q < 4; ++q) {
        float y2 = fmaf(a, ehr[4 * c + q], b2 * nq[q]);
        float ex = __expf(y2);
        float g = fmaf(-2.f, __builtin_amdgcn_rcpf(1.f + ex), 1.f);
        partial = fmaf(nq[q], g, partial);
      }
    }
    partial = wsum(partial);
    if (!lane) kaw_raw[(size_t)row * KSEL + j] = partial;
  }
}

// -------- agg2: ka softmax + weighted sum -> bf16 lin inputs -------------
__global__ __launch_bounds__(192) void agg2(
    const float* __restrict__ e_h, const float* __restrict__ e_t,
    const float* __restrict__ cls, const float* __restrict__ kaw_raw,
    const int* __restrict__ ti, short* __restrict__ inbf) {
  const int bid = blockIdx.x;
  const int xcd = bid & 7, slot = bid >> 3;
  const int batch = xcd >> 1;
  const int row = batch * 256 + (xcd & 1) * 128 + slot;
  const int t = threadIdx.x, lane = t & 63, wave = t >> 6;
  __shared__ float kp[KSEL];
  __shared__ int idxs[KSEL];
  __shared__ float red[2];

  if (t < KSEL) {
    kp[t] = kaw_raw[(size_t)row * KSEL + t];
    idxs[t] = ti[(size_t)row * KSEL + t];
  }
  __syncthreads();
  if (wave == 0) {
    float m = wmaxr(fmaxf(kp[lane], kp[lane + 64]));
    if (!lane) red[0] = m;
  }
  __syncthreads();
  if (t < KSEL) kp[t] = __expf(kp[t] - red[0]);
  __syncthreads();
  if (wave == 0) {
    float s = wsum(kp[lane] + kp[lane + 64]);
    if (!lane) red[1] = s;
  }
  __syncthreads();
  if (t < KSEL) kp[t] *= (1.f / red[1]);
  __syncthreads();

  const size_t o = (size_t)row * DDIM + 4 * t;
  float4 eh4 = *(const float4*)(e_h + o);
  float4 cl4 = *(const float4*)(cls + o);
  const float* etb = e_t + (size_t)batch * NTOK * DDIM;

  float ax = 0.f, ay = 0.f, az = 0.f, aw = 0.f;
#pragma unroll 8
  for (int j = 0; j < KSEL; ++j) {
    float pr = kp[j];
    float4 nb = *(const float4*)(etb + (size_t)idxs[j] * DDIM + 4 * t);
    ax = fmaf(pr, nb.x, ax);
    ay = fmaf(pr, nb.y, ay);
    az = fmaf(pr, nb.z, az);
    aw = fmaf(pr, nb.w, aw);
  }

  short4 sv, bv;
  sv.x = f2bf((eh4.x + ax) * 0.1f + cl4.x);
  sv.y = f2bf((eh4.y + ay) * 0.1f + cl4.y);
  sv.z = f2bf((eh4.z + az) * 0.1f + cl4.z);
  sv.w = f2bf((eh4.w + aw) * 0.1f + cl4.w);
  bv.x = f2bf((eh4.x * ax) * 0.1f + cl4.x);
  bv.y = f2bf((eh4.y * ay) * 0.1f + cl4.y);
  bv.z = f2bf((eh4.z * az) * 0.1f + cl4.z);
  bv.w = f2bf((eh4.w * aw) * 0.1f + cl4.w);
  *(short4*)&inbf[o] = sv;
  *(short4*)&inbf[(size_t)(NBATCH * NCLS) * DDIM + o] = bv;
}

// -------- layernorm over D=768 on (embA[row] + embB[row]) --------
__global__ __launch_bounds__(256) void ln_kernel(const float* __restrict__ embA,
                                                 const float* __restrict__ embB,
                                                 const float* __restrict__ lw,
                                                 const float* __restrict__ lb,
                                                 float* __restrict__ out) {
  const int row = blockIdx.x;
  const int t = threadIdx.x;
  const int lane = t & 63, wave = t >> 6;
  __shared__ float red[4];
  __shared__ float bs[2];
  float e[3];
#pragma unroll
  for (int c = 0; c < 3; ++c) {
    size_t o = (size_t)row * DDIM + t + 256 * c;
    e[c] = embA[o] + embB[o];
  }
  float s = e[0] + e[1] + e[2];
  s = wsum(s);
  if (lane == 0) red[wave] = s;
  __syncthreads();
  if (t == 0) bs[0] = (red[0] + red[1] + red[2] + red[3]) * (1.f / DDIM);
  __syncthreads();
  float mu = bs[0];
  float q = 0.f;
#pragma unroll
  for (int c = 0; c < 3; ++c) {
    float d = e[c] - mu;
    q = fmaf(d, d, q);
  }
  q = wsum(q);
  if (lane == 0) red[wave] = q;
  __syncthreads();
  if (t == 0) bs[1] = (red[0] + red[1] + red[2] + red[3]) * (1.f / DDIM);
  __syncthreads();
  float rstd = rsqrtf(bs[1] + 1e-5f);
#pragma unroll
  for (int c = 0; c < 3; ++c) {
    int d = t + 256 * c;
    out[(size_t)row * DDIM + d] = (e[c] - mu) * rstd * lw[d] + lb[d];
  }
}

// ---------------- launch ----------------
extern "C" void kernel_launch(void* const* d_in, const int* in_sizes, int n_in,
                              void* d_out, int out_size, void* d_ws,
                              size_t ws_size, hipStream_t stream) {
  const float* cls = (const float*)d_in[0];
  const float* feats = (const float*)d_in[1];
  const float* Whw = (const float*)d_in[2];
  const float* Whb = (const float*)d_in[3];
  const float* Wtw = (const float*)d_in[4];
  const float* Wtb = (const float*)d_in[5];
  const float* l1w = (const float*)d_in[6];
  const float* l1b = (const float*)d_in[7];
  const float* l2w = (const float*)d_in[8];
  const float* l2b = (const float*)d_in[9];
  const float* lnw = (const float*)d_in[10];
  const float* lnb = (const float*)d_in[11];
  float* out = (float*)d_out;

  float* ws = (float*)d_ws;
  // layout (float units)
  float* e_h = ws;                          // 786432
  float* e_t = ws + 786432;                 // 3145728
  short* eh_hi = (short*)(ws + 3932160);    // 786432 shorts
  short* eh_lo = eh_hi + 786432;            // (ends 4718592f)
  short* et_hi = (short*)(ws + 4718592);    // 3145728 shorts
  short* et_lo = et_hi + 3145728;           // (ends 7864320f)
  short* WhT_h = (short*)(ws + 7864320);    // 589824 shorts each
  short* WhT_l = WhT_h + 589824;
  short* WtT_h = WhT_h + 2 * 589824;
  short* WtT_l = WhT_h + 3 * 589824;        // (ends 9043968f)
  short* L1T = (short*)(ws + 9043968);      // 589824 shorts
  short* L2T = L1T + 589824;                // (ends 9633792f)
  float* logits = ws + 7864320;             // overlays WhT/WtT (dead by then)
  short* Xh = (short*)(ws + 9633792);       // X bf16 hi/lo; dead after front
  short* Xl = Xh + 3145728;                 // (ends 12779520f)
  float* tw = ws + 9633792;                 // 131072 (overlays Xh - X dead)
  int* ti = (int*)(ws + 9764864);           // 131072
  float* kaw = ws + 9895936;                // 131072
  short* inbf = (short*)(ws + 10027008);    // 2048*768 shorts (786432 f)
  float* linC = e_t;                        // overlays e_t (dead after agg2)
  (void)ws_size;
  (void)in_sizes;
  (void)n_in;
  (void)out_size;

  const float scale = 0.036084391824351615f;  // 1/sqrt(768)
  dim3 blk(256);

  // X -> packed bf16 hi/lo (4096 rows x 768)
  xprep<<<dim3(1536), blk, 0, stream>>>(cls, feats, Xh, Xl);
  // weights -> transposed bf16 (hi/lo for Wh/Wt, plain for L1/L2)
  prep_weights<<<dim3(24, 24, 4), blk, 0, stream>>>(
      Whw, Wtw, l1w, l2w, WhT_h, WtT_h, L1T, L2T, WhT_l, WtT_l);
  // fused e_h | e_t (480 blocks, 128x64, XCD-chunked)
  gemm_front<<<dim3(480), blk, 0, stream>>>(
      Xh, Xl, WhT_h, WhT_l, Whb, WtT_h, WtT_l, Wtb, e_h, eh_hi, eh_lo, e_t,
      et_hi, et_lo);
  // logits[b] = scale * e_h[b] @ e_t[b]^T (512 blocks, batch->XCD)
  gemm_logits<<<dim3(512), blk, 0, stream>>>(eh_hi, eh_lo, et_hi, et_lo,
                                             logits, scale);
  // top-128 per row (radix select)
  topk_select<<<dim3(NBATCH * NCLS), blk, 0, stream>>>(logits, tw, ti);
  // agg1: gated ka weights (2048 blocks)
  agg1<<<dim3(2048), blk, 0, stream>>>(e_h, e_t, tw, ti, kaw);
  // agg2: softmax + weighted sum -> bf16 lin inputs
  agg2<<<dim3(1024), dim3(192), 0, stream>>>(e_h, e_t, cls, kaw, ti, inbf);
  // fused lin1/lin2 (384 blocks, XCD-chunked)
  gemm_lin<<<dim3(384), blk, 0, stream>>>(inbf, L1T, L2T, l1b, l2b, linC);
  // layernorm(sum_emb + bi_emb) -> out
  ln_kernel<<<dim3(NBATCH * NCLS), blk, 0, stream>>>(
      linC, linC + (size_t)(NBATCH * NCLS) * DDIM, lnw, lnb, out);
}

// Round 9
// 131.904 us; speedup vs baseline: 1.0418x; 1.0142x over previous
//
#include <hip/hip_runtime.h>
#include <hip/hip_bf16.h>
#include <math.h>

#define DDIM 768
#define NCLS 256
#define NFEAT 768
#define NTOK 1024
#define NBATCH 4
#define KSEL 128

typedef float f32x4 __attribute__((ext_vector_type(4)));
typedef short s16x8 __attribute__((ext_vector_type(8)));

// ---------------- helpers ----------------
__device__ __forceinline__ float wsum(float v) {
#pragma unroll
  for (int o = 32; o; o >>= 1) v += __shfl_down(v, o, 64);
  return v;
}
__device__ __forceinline__ float wmaxr(float v) {
#pragma unroll
  for (int o = 32; o; o >>= 1) v = fmaxf(v, __shfl_down(v, o, 64));
  return v;
}
__device__ __forceinline__ short f2bf(float f) {
  union { __hip_bfloat16 h; short s; } u;
  u.h = __float2bfloat16(f);
  return u.s;
}
__device__ __forceinline__ float bf2f(short s) {
  union { unsigned u; float f; } c;
  c.u = ((unsigned)(unsigned short)s) << 16;
  return c.f;
}
__device__ __forceinline__ void cvt8(float4 x, float4 y, s16x8& h, s16x8& l) {
  float v[8] = {x.x, x.y, x.z, x.w, y.x, y.y, y.z, y.w};
#pragma unroll
  for (int i = 0; i < 8; ++i) {
    short hh = f2bf(v[i]);
    h[i] = hh;
    l[i] = f2bf(v[i] - bf2f(hh));
  }
}
// LDS address swizzle: 32-short (64B) rows, 8-short (16B) chunks.
// chunk ^= (row>>1)&3 spreads every 16-lane phase group across 8 distinct
// 16B slots -> <=2-way bank aliasing (free) for both staging writes and
// fragment ds_read_b128.
__device__ __forceinline__ int swz(int row, int chunk) {
  return (row << 5) + (((chunk ^ (row >> 1)) & 3) << 3);
}

// -------- X prep: concat(cls,feats) per batch -> packed hi/lo bf16 -------
__global__ __launch_bounds__(256) void xprep(const float* __restrict__ cls,
                                             const float* __restrict__ feats,
                                             short* __restrict__ Xh,
                                             short* __restrict__ Xl) {
  const size_t base = ((size_t)blockIdx.x * 256 + threadIdx.x) * 8;
  const int row = (int)(base / DDIM);
  const int col = (int)(base % DDIM);
  const int b = row >> 10, rr = row & 1023;
  const float* src = (rr < NCLS)
                         ? cls + ((size_t)b * NCLS + rr) * DDIM + col
                         : feats + ((size_t)b * NFEAT + (rr - NCLS)) * DDIM + col;
  float4 a0 = *(const float4*)(src);
  float4 a1 = *(const float4*)(src + 4);
  s16x8 h, l;
  cvt8(a0, a1, h, l);
  *(s16x8*)(Xh + base) = h;
  *(s16x8*)(Xl + base) = l;
}

// -------- transpose + bf16-convert weights (z: 0=Wh split,1=Wt split,
//          2=L1 plain,3=L2 plain) --------
__global__ __launch_bounds__(256) void prep_weights(
    const float* __restrict__ w0, const float* __restrict__ w1,
    const float* __restrict__ w2, const float* __restrict__ w3,
    short* __restrict__ h0, short* __restrict__ h1, short* __restrict__ h2,
    short* __restrict__ h3, short* __restrict__ l0, short* __restrict__ l1) {
  __shared__ float tile[32][33];
  const int z = blockIdx.z;
  const float* s = z == 0 ? w0 : z == 1 ? w1 : z == 2 ? w2 : w3;
  short* dh = z == 0 ? h0 : z == 1 ? h1 : z == 2 ? h2 : h3;
  short* dl = z == 0 ? l0 : z == 1 ? l1 : nullptr;
  const int tx = threadIdx.x & 31, ty0 = threadIdx.x >> 5;
  const int r0 = blockIdx.y * 32, c0 = blockIdx.x * 32;
#pragma unroll
  for (int i = 0; i < 4; ++i) {
    int ty = ty0 + i * 8;
    tile[ty][tx] = s[(size_t)(r0 + ty) * DDIM + c0 + tx];
  }
  __syncthreads();
#pragma unroll
  for (int i = 0; i < 4; ++i) {
    int ty = ty0 + i * 8;
    float v = tile[tx][ty];
    short hh = f2bf(v);
    dh[(size_t)(c0 + ty) * DDIM + r0 + tx] = hh;
    if (dl) dl[(size_t)(c0 + ty) * DDIM + r0 + tx] = f2bf(v - bf2f(hh));
  }
}

// -------- front GEMM (fused e_h | e_t), 128x64 tiles, split-bf16,
//          swizzled LDS (no padding), single-buffer + overlap,
//          XCD-chunked 1D grid (480 = 8 XCD x 60) --------
__global__ __launch_bounds__(256) void gemm_front(
    const short* __restrict__ Xh, const short* __restrict__ Xl,
    const short* __restrict__ WhT_h, const short* __restrict__ WhT_l,
    const float* __restrict__ Whb, const short* __restrict__ WtT_h,
    const short* __restrict__ WtT_l, const float* __restrict__ Wtb,
    float* __restrict__ e_h, short* __restrict__ eh_hi,
    short* __restrict__ eh_lo, float* __restrict__ e_t,
    short* __restrict__ et_hi, short* __restrict__ et_lo) {
  __shared__ short Ah[128 * 32], Al[128 * 32];
  __shared__ short Bh[64 * 32], Bl[64 * 32];
  const int bid = blockIdx.x;
  const int xcd = bid & 7, idx = bid >> 3;  // idx 0..59
  const int ytile = xcd * 5 + idx / 12;     // 0..39
  const int xtile = idx % 12;
  const int t = threadIdx.x;
  const int row0 = ytile * 128, col0 = xtile * 64;
  const bool head = row0 < 1024;

  // A staging: row = t>>1 (0..127), chunk pair (t&1)*2
  const int ar = t >> 1, ac = (t & 1) * 2;
  const int aw0 = swz(ar, ac), aw1 = swz(ar, ac + 1);
  size_t xrow;
  {
    int gr = row0 + ar;
    xrow = head ? (size_t)(((gr >> 8) << 10) + (gr & 255)) : (size_t)(gr - 1024);
  }
  const short* aph = Xh + xrow * DDIM + ac * 8;
  const short* apl = Xl + xrow * DDIM + ac * 8;
  // B staging: row = t>>2 (0..63), chunk t&3
  const int br = t >> 2, bc = t & 3;
  const int bw0 = swz(br, bc);
  const short* bph = (head ? WhT_h : WtT_h) + (size_t)(col0 + br) * DDIM + bc * 8;
  const short* bpl = (head ? WhT_l : WtT_l) + (size_t)(col0 + br) * DDIM + bc * 8;
  const float* biasu = head ? Whb : Wtb;

  const int lane = t & 63, wave = t >> 6;
  const int wr = wave >> 1, wc = wave & 1;  // wave tile: 64 rows x 32 cols
  const int fr = lane & 15, fq = lane >> 4;

  f32x4 acc[4][2] = {};
  s16x8 rah0 = *(const s16x8*)(aph);
  s16x8 rah1 = *(const s16x8*)(aph + 8);
  s16x8 ral0 = *(const s16x8*)(apl);
  s16x8 ral1 = *(const s16x8*)(apl + 8);
  s16x8 rbh = *(const s16x8*)(bph);
  s16x8 rbl = *(const s16x8*)(bpl);

  for (int kt = 0; kt < 24; ++kt) {
    __syncthreads();  // previous iteration's LDS reads complete
    *(s16x8*)&Ah[aw0] = rah0;
    *(s16x8*)&Ah[aw1] = rah1;
    *(s16x8*)&Al[aw0] = ral0;
    *(s16x8*)&Al[aw1] = ral1;
    *(s16x8*)&Bh[bw0] = rbh;
    *(s16x8*)&Bl[bw0] = rbl;
    __syncthreads();
    const int kn = (kt < 23 ? kt + 1 : 23) * 32;  // prefetch next k-step
    rah0 = *(const s16x8*)(aph + kn);
    rah1 = *(const s16x8*)(aph + kn + 8);
    ral0 = *(const s16x8*)(apl + kn);
    ral1 = *(const s16x8*)(apl + kn + 8);
    rbh = *(const s16x8*)(bph + kn);
    rbl = *(const s16x8*)(bpl + kn);

    s16x8 afh[4], afl[4];
#pragma unroll
    for (int m = 0; m < 4; ++m) {
      int ao = swz(wr * 64 + m * 16 + fr, fq);
      afh[m] = *(const s16x8*)&Ah[ao];
      afl[m] = *(const s16x8*)&Al[ao];
    }
#pragma unroll
    for (int n = 0; n < 2; ++n) {
      int bo = swz(wc * 32 + n * 16 + fr, fq);
      s16x8 bfh = *(const s16x8*)&Bh[bo];
      s16x8 bfl = *(const s16x8*)&Bl[bo];
#pragma unroll
      for (int m = 0; m < 4; ++m) {
        acc[m][n] =
            __builtin_amdgcn_mfma_f32_16x16x32_bf16(afh[m], bfh, acc[m][n], 0, 0, 0);
        acc[m][n] =
            __builtin_amdgcn_mfma_f32_16x16x32_bf16(afh[m], bfl, acc[m][n], 0, 0, 0);
        acc[m][n] =
            __builtin_amdgcn_mfma_f32_16x16x32_bf16(afl[m], bfh, acc[m][n], 0, 0, 0);
      }
    }
  }

  float* Cf = head ? e_h : e_t;
  short* Ch = head ? eh_hi : et_hi;
  short* Cl = head ? eh_lo : et_lo;
  const int rbase = head ? row0 : row0 - 1024;
#pragma unroll
  for (int m = 0; m < 4; ++m) {
#pragma unroll
    for (int n = 0; n < 2; ++n) {
#pragma unroll
      for (int r = 0; r < 4; ++r) {
        int rg = rbase + wr * 64 + m * 16 + fq * 4 + r;
        int cg = col0 + wc * 32 + n * 16 + fr;
        float v = acc[m][n][r] + biasu[cg];
        size_t o = (size_t)rg * DDIM + cg;
        Cf[o] = v;
        short hh = f2bf(v);
        Ch[o] = hh;
        Cl[o] = f2bf(v - bf2f(hh));
      }
    }
  }
}

// -------- logits GEMM: 32x64 tiles, swizzled LDS, 512 blocks,
//          batch->XCD affinity, single-buffer + overlap --------
__global__ __launch_bounds__(256) void gemm_logits(
    const short* __restrict__ eh_hi, const short* __restrict__ eh_lo,
    const short* __restrict__ et_hi, const short* __restrict__ et_lo,
    float* __restrict__ logits, float scale) {
  __shared__ short Ah[32 * 32], Al[32 * 32];
  __shared__ short Bh[64 * 32], Bl[64 * 32];
  const int bid = blockIdx.x;
  const int xcd = bid & 7, idx = bid >> 3;
  const int batch = xcd >> 1;
  const int sub = ((xcd & 1) << 6) | idx;
  const int xtile = sub & 15, ytile = sub >> 4;
  const int row0 = ytile * 32, col0 = xtile * 64;
  const int t = threadIdx.x;

  const int ahalf = t >> 7, ac2 = t & 127;
  const int asr = ac2 >> 2, acc_ = ac2 & 3;
  const short* aptr = (ahalf ? eh_lo : eh_hi) +
                      ((size_t)batch * NCLS + row0 + asr) * DDIM + acc_ * 8;
  const int aso = swz(asr, acc_);
  const int bsr = t >> 2, bcc = t & 3;
  const short* bph = et_hi + ((size_t)batch * NTOK + col0 + bsr) * DDIM + bcc * 8;
  const short* bpl = et_lo + ((size_t)batch * NTOK + col0 + bsr) * DDIM + bcc * 8;
  const int bso = swz(bsr, bcc);

  const int lane = t & 63, wave = t >> 6;
  const int wr = wave >> 1, wc = wave & 1;
  const int fr = lane & 15, fq = lane >> 4;

  f32x4 acc[2] = {};
  s16x8 rA = *(const s16x8*)(aptr);
  s16x8 rbh = *(const s16x8*)(bph);
  s16x8 rbl = *(const s16x8*)(bpl);

  for (int kt = 0; kt < 24; ++kt) {
    __syncthreads();
    *(s16x8*)&(ahalf ? Al : Ah)[aso] = rA;
    *(s16x8*)&Bh[bso] = rbh;
    *(s16x8*)&Bl[bso] = rbl;
    __syncthreads();
    const int kn = (kt < 23 ? kt + 1 : 23) * 32;
    rA = *(const s16x8*)(aptr + kn);
    rbh = *(const s16x8*)(bph + kn);
    rbl = *(const s16x8*)(bpl + kn);
    int ao = swz(wr * 16 + fr, fq);
    s16x8 afh = *(const s16x8*)&Ah[ao];
    s16x8 afl = *(const s16x8*)&Al[ao];
#pragma unroll
    for (int n = 0; n < 2; ++n) {
      int bo = swz(wc * 32 + n * 16 + fr, fq);
      s16x8 bfh = *(const s16x8*)&Bh[bo];
      s16x8 bfl = *(const s16x8*)&Bl[bo];
      acc[n] = __builtin_amdgcn_mfma_f32_16x16x32_bf16(afh, bfh, acc[n], 0, 0, 0);
      acc[n] = __builtin_amdgcn_mfma_f32_16x16x32_bf16(afh, bfl, acc[n], 0, 0, 0);
      acc[n] = __builtin_amdgcn_mfma_f32_16x16x32_bf16(afl, bfh, acc[n], 0, 0, 0);
    }
  }

  float* Cb = logits + (size_t)batch * NCLS * NTOK;
#pragma unroll
  for (int n = 0; n < 2; ++n)
#pragma unroll
    for (int r = 0; r < 4; ++r) {
      int rg = row0 + wr * 16 + fq * 4 + r;
      int cg = col0 + wc * 32 + n * 16 + fr;
      Cb[(size_t)rg * NTOK + cg] = scale * acc[n][r];
    }
}

// -------- lin GEMM (fused lin1/lin2), 64x64, swizzled LDS, plain bf16,
//          leaky, single-buffer + overlap, XCD-chunked (384 = 8 x 48) ----
__global__ __launch_bounds__(256) void gemm_lin(
    const short* __restrict__ inbf, const short* __restrict__ L1T,
    const short* __restrict__ L2T, const float* __restrict__ b1,
    const float* __restrict__ b2, float* __restrict__ C) {
  __shared__ short Ah[64 * 32], Bh[64 * 32];
  const int bid = blockIdx.x;
  const int xcd = bid & 7, idx = bid >> 3;
  const int ytile = xcd * 4 + idx / 12, xtile = idx % 12;
  const int t = threadIdx.x;
  const int row0 = ytile * 64, col0 = xtile * 64;
  const bool second = row0 >= 1024;
  const int sr = t >> 2, sc = t & 3;
  const short* aptr = inbf + (size_t)(row0 + sr) * DDIM + sc * 8;
  const short* bptr = (second ? L2T : L1T) + (size_t)(col0 + sr) * DDIM + sc * 8;
  const float* biasu = second ? b2 : b1;
  const int lane = t & 63, wave = t >> 6;
  const int wr = wave >> 1, wc = wave & 1;
  const int fr = lane & 15, fq = lane >> 4;
  const int so = swz(sr, sc);

  f32x4 acc[2][2] = {};
  s16x8 rA = *(const s16x8*)(aptr);
  s16x8 rB = *(const s16x8*)(bptr);
  for (int kt = 0; kt < 24; ++kt) {
    __syncthreads();
    *(s16x8*)&Ah[so] = rA;
    *(s16x8*)&Bh[so] = rB;
    __syncthreads();
    const int kn = (kt < 23 ? kt + 1 : 23) * 32;
    rA = *(const s16x8*)(aptr + kn);
    rB = *(const s16x8*)(bptr + kn);
#pragma unroll
    for (int n = 0; n < 2; ++n) {
      int bo = swz(wc * 32 + n * 16 + fr, fq);
      s16x8 bfh = *(const s16x8*)&Bh[bo];
#pragma unroll
      for (int m = 0; m < 2; ++m) {
        int ao = swz(wr * 32 + m * 16 + fr, fq);
        s16x8 afh = *(const s16x8*)&Ah[ao];
        acc[m][n] =
            __builtin_amdgcn_mfma_f32_16x16x32_bf16(afh, bfh, acc[m][n], 0, 0, 0);
      }
    }
  }
#pragma unroll
  for (int m = 0; m < 2; ++m)
#pragma unroll
    for (int n = 0; n < 2; ++n)
#pragma unroll
      for (int r = 0; r < 4; ++r) {
        int rg = row0 + wr * 32 + m * 16 + fq * 4 + r;
        int cg = col0 + wc * 32 + n * 16 + fr;
        float v = acc[m][n][r] + biasu[cg];
        v = v > 0.f ? v : 0.01f * v;
        C[(size_t)rg * DDIM + cg] = v;
      }
}

// -------- top-k via 4-round byte radix select (set semantics) ------------
__global__ __launch_bounds__(256) void topk_select(
    const float* __restrict__ logits, float* __restrict__ tw,
    int* __restrict__ ti) {
  const int row = blockIdx.x;
  const int t = threadIdx.x;
  const int lane = t & 63, wave = t >> 6;
  __shared__ int hist[256];
  __shared__ int sh_bin, sh_rem;
  __shared__ int cnt;
  __shared__ int wsumT[4];

  float4 v4 = *(const float4*)(logits + (size_t)row * NTOK + 4 * t);
  float val[4] = {v4.x, v4.y, v4.z, v4.w};
  unsigned key[4];
#pragma unroll
  for (int i = 0; i < 4; ++i) {
    unsigned u = __float_as_uint(val[i]);
    key[i] = (u & 0x80000000u) ? ~u : (u | 0x80000000u);
  }

  unsigned pref = 0, mask = 0;
  int rem = KSEL;
#pragma unroll
  for (int shift = 24; shift >= 0; shift -= 8) {
    hist[t] = 0;
    __syncthreads();
#pragma unroll
    for (int i = 0; i < 4; ++i)
      if ((key[i] & mask) == pref)
        atomicAdd(&hist[(key[i] >> shift) & 255], 1);
    __syncthreads();
    if (wave == 0) {
      int h0 = hist[4 * lane], h1 = hist[4 * lane + 1];
      int h2 = hist[4 * lane + 2], h3 = hist[4 * lane + 3];
      int s = h0 + h1 + h2 + h3;
#pragma unroll
      for (int o = 1; o < 64; o <<= 1) {
        int v = __shfl_down(s, o, 64);
        if (lane + o < 64) s += v;
      }
      int abv = __shfl_down(s, 1, 64);
      if (lane == 63) abv = 0;
      int c3 = abv + h3, c2 = c3 + h2, c1 = c2 + h1, c0 = c1 + h0;
      int bin = -1, nab = 0;
      if (c3 >= rem && abv < rem) { bin = 4 * lane + 3; nab = abv; }
      else if (c2 >= rem && c3 < rem) { bin = 4 * lane + 2; nab = c3; }
      else if (c1 >= rem && c2 < rem) { bin = 4 * lane + 1; nab = c2; }
      else if (c0 >= rem && c1 < rem) { bin = 4 * lane + 0; nab = c1; }
      if (bin >= 0) { sh_bin = bin; sh_rem = rem - nab; }
    }
    __syncthreads();
    pref |= ((unsigned)sh_bin) << shift;
    mask |= 0xFFu << shift;
    rem = sh_rem;
  }

  const unsigned T = pref;
  const int above = KSEL - rem;

  if (t == 0) cnt = 0;
  int tc = 0;
#pragma unroll
  for (int i = 0; i < 4; ++i) tc += (key[i] == T);
  int inc = tc;
#pragma unroll
  for (int o = 1; o < 64; o <<= 1) {
    int v = __shfl_up(inc, o, 64);
    if (lane >= o) inc += v;
  }
  if (lane == 63) wsumT[wave] = inc;
  __syncthreads();
  int wbase = 0;
#pragma unroll
  for (int w = 0; w < 4; ++w)
    if (w < wave) wbase += wsumT[w];
  int excl = wbase + inc - tc;

  float* twr = tw + (size_t)row * KSEL;
  int* tir = ti + (size_t)row * KSEL;
#pragma unroll
  for (int i = 0; i < 4; ++i) {
    if (key[i] > T) {
      int slot = atomicAdd(&cnt, 1);
      twr[slot] = val[i];
      tir[slot] = 4 * t + i;
    } else if (key[i] == T) {
      int r = excl++;
      if (r < rem) {
        twr[above + r] = val[i];
        tir[above + r] = 4 * t + i;
      }
    }
  }
}

// -------- agg1: gated ka weights (2 blocks/row, XCD-batch affinity) ------
__global__ __launch_bounds__(256) void agg1(const float* __restrict__ e_h,
                                            const float* __restrict__ e_t,
                                            const float* __restrict__ tw,
                                            const int* __restrict__ ti,
                                            float* __restrict__ kaw_raw) {
  const int bid = blockIdx.x;
  const int xcd = bid & 7, slot = bid >> 3;
  const int batch = xcd >> 1;
  const int u = ((xcd & 1) << 8) | slot;
  const int row = batch * 256 + (u >> 1);
  const int half = u & 1;
  const int t = threadIdx.x, lane = t & 63, wave = t >> 6;
  __shared__ float p[KSEL];
  __shared__ int idxs[KSEL];
  __shared__ float red[2];

  if (t < KSEL) {
    p[t] = tw[(size_t)row * KSEL + t];
    idxs[t] = ti[(size_t)row * KSEL + t];
  }
  __syncthreads();
  if (wave == 0) {
    float m = wmaxr(fmaxf(p[lane], p[lane + 64]));
    if (!lane) red[0] = m;
  }
  __syncthreads();
  if (t < KSEL) p[t] = __expf(p[t] - red[0]);
  __syncthreads();
  if (wave == 0) {
    float s = wsum(p[lane] + p[lane + 64]);
    if (!lane) red[1] = s;
  }
  __syncthreads();
  if (t < KSEL) p[t] *= (1.f / red[1]);
  __syncthreads();

  float ehr[12];
  {
    const float* ehrow = e_h + (size_t)row * DDIM;
#pragma unroll
    for (int c = 0; c < 3; ++c) {
      float4 v = *(const float4*)(ehrow + 4 * lane + 256 * c);
      ehr[4 * c + 0] = v.x;
      ehr[4 * c + 1] = v.y;
      ehr[4 * c + 2] = v.z;
      ehr[4 * c + 3] = v.w;
    }
  }
  const float* etb = e_t + (size_t)batch * NTOK * DDIM;

  for (int i = 0; i < 16; ++i) {
    int j = half * 64 + wave * 16 + i;
    float pj = p[j];
    float a = 4.f - 2.f * pj, b2 = 2.f * pj;
    const float* nb = etb + (size_t)idxs[j] * DDIM;
    float partial = 0.f;
#pragma unroll
    for (int c = 0; c < 3; ++c) {
      float4 nv = *(const float4*)(nb + 4 * lane + 256 * c);
      float nq[4] = {nv.x, nv.y, nv.z, nv.w};
#pragma unroll
      for (int q = 0; q < 4; ++q) {
        float y2 = fmaf(a, ehr[4 * c + q], b2 * nq[q]);
        float ex = __expf(y2);
        float g = fmaf(-2.f, __builtin_amdgcn_rcpf(1.f + ex), 1.f);
        partial = fmaf(nq[q], g, partial);
      }
    }
    partial = wsum(partial);
    if (!lane) kaw_raw[(size_t)row * KSEL + j] = partial;
  }
}

// -------- agg2: ka softmax + weighted sum -> bf16 lin inputs -------------
__global__ __launch_bounds__(192) void agg2(
    const float* __restrict__ e_h, const float* __restrict__ e_t,
    const float* __restrict__ cls, const float* __restrict__ kaw_raw,
    const int* __restrict__ ti, short* __restrict__ inbf) {
  const int bid = blockIdx.x;
  const int xcd = bid & 7, slot = bid >> 3;
  const int batch = xcd >> 1;
  const int row = batch * 256 + (xcd & 1) * 128 + slot;
  const int t = threadIdx.x, lane = t & 63, wave = t >> 6;
  __shared__ float kp[KSEL];
  __shared__ int idxs[KSEL];
  __shared__ float red[2];

  if (t < KSEL) {
    kp[t] = kaw_raw[(size_t)row * KSEL + t];
    idxs[t] = ti[(size_t)row * KSEL + t];
  }
  __syncthreads();
  if (wave == 0) {
    float m = wmaxr(fmaxf(kp[lane], kp[lane + 64]));
    if (!lane) red[0] = m;
  }
  __syncthreads();
  if (t < KSEL) kp[t] = __expf(kp[t] - red[0]);
  __syncthreads();
  if (wave == 0) {
    float s = wsum(kp[lane] + kp[lane + 64]);
    if (!lane) red[1] = s;
  }
  __syncthreads();
  if (t < KSEL) kp[t] *= (1.f / red[1]);
  __syncthreads();

  const size_t o = (size_t)row * DDIM + 4 * t;
  float4 eh4 = *(const float4*)(e_h + o);
  float4 cl4 = *(const float4*)(cls + o);
  const float* etb = e_t + (size_t)batch * NTOK * DDIM;

  float ax = 0.f, ay = 0.f, az = 0.f, aw = 0.f;
#pragma unroll 8
  for (int j = 0; j < KSEL; ++j) {
    float pr = kp[j];
    float4 nb = *(const float4*)(etb + (size_t)idxs[j] * DDIM + 4 * t);
    ax = fmaf(pr, nb.x, ax);
    ay = fmaf(pr, nb.y, ay);
    az = fmaf(pr, nb.z, az);
    aw = fmaf(pr, nb.w, aw);
  }

  short4 sv, bv;
  sv.x = f2bf((eh4.x + ax) * 0.1f + cl4.x);
  sv.y = f2bf((eh4.y + ay) * 0.1f + cl4.y);
  sv.z = f2bf((eh4.z + az) * 0.1f + cl4.z);
  sv.w = f2bf((eh4.w + aw) * 0.1f + cl4.w);
  bv.x = f2bf((eh4.x * ax) * 0.1f + cl4.x);
  bv.y = f2bf((eh4.y * ay) * 0.1f + cl4.y);
  bv.z = f2bf((eh4.z * az) * 0.1f + cl4.z);
  bv.w = f2bf((eh4.w * aw) * 0.1f + cl4.w);
  *(short4*)&inbf[o] = sv;
  *(short4*)&inbf[(size_t)(NBATCH * NCLS) * DDIM + o] = bv;
}

// -------- layernorm over D=768 on (embA[row] + embB[row]) --------
__global__ __launch_bounds__(256) void ln_kernel(const float* __restrict__ embA,
                                                 const float* __restrict__ embB,
                                                 const float* __restrict__ lw,
                                                 const float* __restrict__ lb,
                                                 float* __restrict__ out) {
  const int row = blockIdx.x;
  const int t = threadIdx.x;
  const int lane = t & 63, wave = t >> 6;
  __shared__ float red[4];
  __shared__ float bs[2];
  float e[3];
#pragma unroll
  for (int c = 0; c < 3; ++c) {
    size_t o = (size_t)row * DDIM + t + 256 * c;
    e[c] = embA[o] + embB[o];
  }
  float s = e[0] + e[1] + e[2];
  s = wsum(s);
  if (lane == 0) red[wave] = s;
  __syncthreads();
  if (t == 0) bs[0] = (red[0] + red[1] + red[2] + red[3]) * (1.f / DDIM);
  __syncthreads();
  float mu = bs[0];
  float q = 0.f;
#pragma unroll
  for (int c = 0; c < 3; ++c) {
    float d = e[c] - mu;
    q = fmaf(d, d, q);
  }
  q = wsum(q);
  if (lane == 0) red[wave] = q;
  __syncthreads();
  if (t == 0) bs[1] = (red[0] + red[1] + red[2] + red[3]) * (1.f / DDIM);
  __syncthreads();
  float rstd = rsqrtf(bs[1] + 1e-5f);
#pragma unroll
  for (int c = 0; c < 3; ++c) {
    int d = t + 256 * c;
    out[(size_t)row * DDIM + d] = (e[c] - mu) * rstd * lw[d] + lb[d];
  }
}

// ---------------- launch ----------------
extern "C" void kernel_launch(void* const* d_in, const int* in_sizes, int n_in,
                              void* d_out, int out_size, void* d_ws,
                              size_t ws_size, hipStream_t stream) {
  const float* cls = (const float*)d_in[0];
  const float* feats = (const float*)d_in[1];
  const float* Whw = (const float*)d_in[2];
  const float* Whb = (const float*)d_in[3];
  const float* Wtw = (const float*)d_in[4];
  const float* Wtb = (const float*)d_in[5];
  const float* l1w = (const float*)d_in[6];
  const float* l1b = (const float*)d_in[7];
  const float* l2w = (const float*)d_in[8];
  const float* l2b = (const float*)d_in[9];
  const float* lnw = (const float*)d_in[10];
  const float* lnb = (const float*)d_in[11];
  float* out = (float*)d_out;

  float* ws = (float*)d_ws;
  // layout (float units)
  float* e_h = ws;                          // 786432
  float* e_t = ws + 786432;                 // 3145728
  short* eh_hi = (short*)(ws + 3932160);    // 786432 shorts
  short* eh_lo = eh_hi + 786432;            // (ends 4718592f)
  short* et_hi = (short*)(ws + 4718592);    // 3145728 shorts
  short* et_lo = et_hi + 3145728;           // (ends 7864320f)
  short* WhT_h = (short*)(ws + 7864320);    // 589824 shorts each
  short* WhT_l = WhT_h + 589824;
  short* WtT_h = WhT_h + 2 * 589824;
  short* WtT_l = WhT_h + 3 * 589824;        // (ends 9043968f)
  short* L1T = (short*)(ws + 9043968);      // 589824 shorts
  short* L2T = L1T + 589824;                // (ends 9633792f)
  float* logits = ws + 7864320;             // overlays WhT/WtT (dead by then)
  short* Xh = (short*)(ws + 9633792);       // X bf16 hi/lo; dead after front
  short* Xl = Xh + 3145728;                 // (ends 12779520f)
  float* tw = ws + 9633792;                 // 131072 (overlays Xh - X dead)
  int* ti = (int*)(ws + 9764864);           // 131072
  float* kaw = ws + 9895936;                // 131072
  short* inbf = (short*)(ws + 10027008);    // 2048*768 shorts (786432 f)
  float* linC = e_t;                        // overlays e_t (dead after agg2)
  (void)ws_size;
  (void)in_sizes;
  (void)n_in;
  (void)out_size;

  const float scale = 0.036084391824351615f;  // 1/sqrt(768)
  dim3 blk(256);

  // X -> packed bf16 hi/lo (4096 rows x 768)
  xprep<<<dim3(1536), blk, 0, stream>>>(cls, feats, Xh, Xl);
  // weights -> transposed bf16 (hi/lo for Wh/Wt, plain for L1/L2)
  prep_weights<<<dim3(24, 24, 4), blk, 0, stream>>>(
      Whw, Wtw, l1w, l2w, WhT_h, WtT_h, L1T, L2T, WhT_l, WtT_l);
  // fused e_h | e_t (480 blocks, 128x64, XCD-chunked, swizzled LDS)
  gemm_front<<<dim3(480), blk, 0, stream>>>(
      Xh, Xl, WhT_h, WhT_l, Whb, WtT_h, WtT_l, Wtb, e_h, eh_hi, eh_lo, e_t,
      et_hi, et_lo);
  // logits[b] = scale * e_h[b] @ e_t[b]^T (512 blocks, batch->XCD)
  gemm_logits<<<dim3(512), blk, 0, stream>>>(eh_hi, eh_lo, et_hi, et_lo,
                                             logits, scale);
  // top-128 per row (radix select)
  topk_select<<<dim3(NBATCH * NCLS), blk, 0, stream>>>(logits, tw, ti);
  // agg1: gated ka weights (2048 blocks)
  agg1<<<dim3(2048), blk, 0, stream>>>(e_h, e_t, tw, ti, kaw);
  // agg2: softmax + weighted sum -> bf16 lin inputs
  agg2<<<dim3(1024), dim3(192), 0, stream>>>(e_h, e_t, cls, kaw, ti, inbf);
  // fused lin1/lin2 (384 blocks, XCD-chunked, swizzled LDS)
  gemm_lin<<<dim3(384), blk, 0, stream>>>(inbf, L1T, L2T, l1b, l2b, linC);
  // layernorm(sum_emb + bi_emb) -> out
  ln_kernel<<<dim3(NBATCH * NCLS), blk, 0, stream>>>(
      linC, linC + (size_t)(NBATCH * NCLS) * DDIM, lnw, lnb, out);
}

// Round 10
// 125.687 us; speedup vs baseline: 1.0933x; 1.0495x over previous
//
#include <hip/hip_runtime.h>
#include <hip/hip_bf16.h>
#include <math.h>

#define DDIM 768
#define NCLS 256
#define NFEAT 768
#define NTOK 1024
#define NBATCH 4
#define KSEL 128

typedef float f32x4 __attribute__((ext_vector_type(4)));
typedef short s16x8 __attribute__((ext_vector_type(8)));

// ---------------- helpers ----------------
__device__ __forceinline__ float wsum(float v) {
#pragma unroll
  for (int o = 32; o; o >>= 1) v += __shfl_down(v, o, 64);
  return v;
}
__device__ __forceinline__ float wmaxr(float v) {
#pragma unroll
  for (int o = 32; o; o >>= 1) v = fmaxf(v, __shfl_down(v, o, 64));
  return v;
}
__device__ __forceinline__ short f2bf(float f) {
  union { __hip_bfloat16 h; short s; } u;
  u.h = __float2bfloat16(f);
  return u.s;
}
__device__ __forceinline__ float bf2f(short s) {
  union { unsigned u; float f; } c;
  c.u = ((unsigned)(unsigned short)s) << 16;
  return c.f;
}
__device__ __forceinline__ void cvt8(float4 x, float4 y, s16x8& h, s16x8& l) {
  float v[8] = {x.x, x.y, x.z, x.w, y.x, y.y, y.z, y.w};
#pragma unroll
  for (int i = 0; i < 8; ++i) {
    short hh = f2bf(v[i]);
    h[i] = hh;
    l[i] = f2bf(v[i] - bf2f(hh));
  }
}
// LDS address swizzle: 32-short (64B) rows, 8-short (16B) chunks.
__device__ __forceinline__ int swz(int row, int chunk) {
  return (row << 5) + (((chunk ^ (row >> 1)) & 3) << 3);
}

// -------- X prep: concat(cls,feats) per batch -> packed hi/lo bf16 -------
__global__ __launch_bounds__(256) void xprep(const float* __restrict__ cls,
                                             const float* __restrict__ feats,
                                             short* __restrict__ Xh,
                                             short* __restrict__ Xl) {
  const size_t base = ((size_t)blockIdx.x * 256 + threadIdx.x) * 8;
  const int row = (int)(base / DDIM);
  const int col = (int)(base % DDIM);
  const int b = row >> 10, rr = row & 1023;
  const float* src = (rr < NCLS)
                         ? cls + ((size_t)b * NCLS + rr) * DDIM + col
                         : feats + ((size_t)b * NFEAT + (rr - NCLS)) * DDIM + col;
  float4 a0 = *(const float4*)(src);
  float4 a1 = *(const float4*)(src + 4);
  s16x8 h, l;
  cvt8(a0, a1, h, l);
  *(s16x8*)(Xh + base) = h;
  *(s16x8*)(Xl + base) = l;
}

// -------- transpose + bf16-convert weights (z: 0=Wh split,1=Wt split,
//          2=L1 plain,3=L2 plain) --------
__global__ __launch_bounds__(256) void prep_weights(
    const float* __restrict__ w0, const float* __restrict__ w1,
    const float* __restrict__ w2, const float* __restrict__ w3,
    short* __restrict__ h0, short* __restrict__ h1, short* __restrict__ h2,
    short* __restrict__ h3, short* __restrict__ l0, short* __restrict__ l1) {
  __shared__ float tile[32][33];
  const int z = blockIdx.z;
  const float* s = z == 0 ? w0 : z == 1 ? w1 : z == 2 ? w2 : w3;
  short* dh = z == 0 ? h0 : z == 1 ? h1 : z == 2 ? h2 : h3;
  short* dl = z == 0 ? l0 : z == 1 ? l1 : nullptr;
  const int tx = threadIdx.x & 31, ty0 = threadIdx.x >> 5;
  const int r0 = blockIdx.y * 32, c0 = blockIdx.x * 32;
#pragma unroll
  for (int i = 0; i < 4; ++i) {
    int ty = ty0 + i * 8;
    tile[ty][tx] = s[(size_t)(r0 + ty) * DDIM + c0 + tx];
  }
  __syncthreads();
#pragma unroll
  for (int i = 0; i < 4; ++i) {
    int ty = ty0 + i * 8;
    float v = tile[tx][ty];
    short hh = f2bf(v);
    dh[(size_t)(c0 + ty) * DDIM + r0 + tx] = hh;
    if (dl) dl[(size_t)(c0 + ty) * DDIM + r0 + tx] = f2bf(v - bf2f(hh));
  }
}

// -------- front GEMM (fused e_h | e_t), 128x64 tiles, split-bf16,
//          bf16 hi/lo outputs only (fp32 path removed),
//          swizzled LDS, single-buffer + overlap, XCD-chunked (480) -----
__global__ __launch_bounds__(256) void gemm_front(
    const short* __restrict__ Xh, const short* __restrict__ Xl,
    const short* __restrict__ WhT_h, const short* __restrict__ WhT_l,
    const float* __restrict__ Whb, const short* __restrict__ WtT_h,
    const short* __restrict__ WtT_l, const float* __restrict__ Wtb,
    short* __restrict__ eh_hi, short* __restrict__ eh_lo,
    short* __restrict__ et_hi, short* __restrict__ et_lo) {
  __shared__ short Ah[128 * 32], Al[128 * 32];
  __shared__ short Bh[64 * 32], Bl[64 * 32];
  const int bid = blockIdx.x;
  const int xcd = bid & 7, idx = bid >> 3;  // idx 0..59
  const int ytile = xcd * 5 + idx / 12;     // 0..39
  const int xtile = idx % 12;
  const int t = threadIdx.x;
  const int row0 = ytile * 128, col0 = xtile * 64;
  const bool head = row0 < 1024;

  const int ar = t >> 1, ac = (t & 1) * 2;
  const int aw0 = swz(ar, ac), aw1 = swz(ar, ac + 1);
  size_t xrow;
  {
    int gr = row0 + ar;
    xrow = head ? (size_t)(((gr >> 8) << 10) + (gr & 255)) : (size_t)(gr - 1024);
  }
  const short* aph = Xh + xrow * DDIM + ac * 8;
  const short* apl = Xl + xrow * DDIM + ac * 8;
  const int br = t >> 2, bc = t & 3;
  const int bw0 = swz(br, bc);
  const short* bph = (head ? WhT_h : WtT_h) + (size_t)(col0 + br) * DDIM + bc * 8;
  const short* bpl = (head ? WhT_l : WtT_l) + (size_t)(col0 + br) * DDIM + bc * 8;
  const float* biasu = head ? Whb : Wtb;

  const int lane = t & 63, wave = t >> 6;
  const int wr = wave >> 1, wc = wave & 1;
  const int fr = lane & 15, fq = lane >> 4;

  f32x4 acc[4][2] = {};
  s16x8 rah0 = *(const s16x8*)(aph);
  s16x8 rah1 = *(const s16x8*)(aph + 8);
  s16x8 ral0 = *(const s16x8*)(apl);
  s16x8 ral1 = *(const s16x8*)(apl + 8);
  s16x8 rbh = *(const s16x8*)(bph);
  s16x8 rbl = *(const s16x8*)(bpl);

  for (int kt = 0; kt < 24; ++kt) {
    __syncthreads();
    *(s16x8*)&Ah[aw0] = rah0;
    *(s16x8*)&Ah[aw1] = rah1;
    *(s16x8*)&Al[aw0] = ral0;
    *(s16x8*)&Al[aw1] = ral1;
    *(s16x8*)&Bh[bw0] = rbh;
    *(s16x8*)&Bl[bw0] = rbl;
    __syncthreads();
    const int kn = (kt < 23 ? kt + 1 : 23) * 32;
    rah0 = *(const s16x8*)(aph + kn);
    rah1 = *(const s16x8*)(aph + kn + 8);
    ral0 = *(const s16x8*)(apl + kn);
    ral1 = *(const s16x8*)(apl + kn + 8);
    rbh = *(const s16x8*)(bph + kn);
    rbl = *(const s16x8*)(bpl + kn);

    s16x8 afh[4], afl[4];
#pragma unroll
    for (int m = 0; m < 4; ++m) {
      int ao = swz(wr * 64 + m * 16 + fr, fq);
      afh[m] = *(const s16x8*)&Ah[ao];
      afl[m] = *(const s16x8*)&Al[ao];
    }
#pragma unroll
    for (int n = 0; n < 2; ++n) {
      int bo = swz(wc * 32 + n * 16 + fr, fq);
      s16x8 bfh = *(const s16x8*)&Bh[bo];
      s16x8 bfl = *(const s16x8*)&Bl[bo];
#pragma unroll
      for (int m = 0; m < 4; ++m) {
        acc[m][n] =
            __builtin_amdgcn_mfma_f32_16x16x32_bf16(afh[m], bfh, acc[m][n], 0, 0, 0);
        acc[m][n] =
            __builtin_amdgcn_mfma_f32_16x16x32_bf16(afh[m], bfl, acc[m][n], 0, 0, 0);
        acc[m][n] =
            __builtin_amdgcn_mfma_f32_16x16x32_bf16(afl[m], bfh, acc[m][n], 0, 0, 0);
      }
    }
  }

  short* Ch = head ? eh_hi : et_hi;
  short* Cl = head ? eh_lo : et_lo;
  const int rbase = head ? row0 : row0 - 1024;
#pragma unroll
  for (int m = 0; m < 4; ++m) {
#pragma unroll
    for (int n = 0; n < 2; ++n) {
#pragma unroll
      for (int r = 0; r < 4; ++r) {
        int rg = rbase + wr * 64 + m * 16 + fq * 4 + r;
        int cg = col0 + wc * 32 + n * 16 + fr;
        float v = acc[m][n][r] + biasu[cg];
        size_t o = (size_t)rg * DDIM + cg;
        short hh = f2bf(v);
        Ch[o] = hh;
        Cl[o] = f2bf(v - bf2f(hh));
      }
    }
  }
}

// -------- logits GEMM: 32x64 tiles, swizzled LDS, 512 blocks,
//          batch->XCD affinity, single-buffer + overlap --------
__global__ __launch_bounds__(256) void gemm_logits(
    const short* __restrict__ eh_hi, const short* __restrict__ eh_lo,
    const short* __restrict__ et_hi, const short* __restrict__ et_lo,
    float* __restrict__ logits, float scale) {
  __shared__ short Ah[32 * 32], Al[32 * 32];
  __shared__ short Bh[64 * 32], Bl[64 * 32];
  const int bid = blockIdx.x;
  const int xcd = bid & 7, idx = bid >> 3;
  const int batch = xcd >> 1;
  const int sub = ((xcd & 1) << 6) | idx;
  const int xtile = sub & 15, ytile = sub >> 4;
  const int row0 = ytile * 32, col0 = xtile * 64;
  const int t = threadIdx.x;

  const int ahalf = t >> 7, ac2 = t & 127;
  const int asr = ac2 >> 2, acc_ = ac2 & 3;
  const short* aptr = (ahalf ? eh_lo : eh_hi) +
                      ((size_t)batch * NCLS + row0 + asr) * DDIM + acc_ * 8;
  const int aso = swz(asr, acc_);
  const int bsr = t >> 2, bcc = t & 3;
  const short* bph = et_hi + ((size_t)batch * NTOK + col0 + bsr) * DDIM + bcc * 8;
  const short* bpl = et_lo + ((size_t)batch * NTOK + col0 + bsr) * DDIM + bcc * 8;
  const int bso = swz(bsr, bcc);

  const int lane = t & 63, wave = t >> 6;
  const int wr = wave >> 1, wc = wave & 1;
  const int fr = lane & 15, fq = lane >> 4;

  f32x4 acc[2] = {};
  s16x8 rA = *(const s16x8*)(aptr);
  s16x8 rbh = *(const s16x8*)(bph);
  s16x8 rbl = *(const s16x8*)(bpl);

  for (int kt = 0; kt < 24; ++kt) {
    __syncthreads();
    *(s16x8*)&(ahalf ? Al : Ah)[aso] = rA;
    *(s16x8*)&Bh[bso] = rbh;
    *(s16x8*)&Bl[bso] = rbl;
    __syncthreads();
    const int kn = (kt < 23 ? kt + 1 : 23) * 32;
    rA = *(const s16x8*)(aptr + kn);
    rbh = *(const s16x8*)(bph + kn);
    rbl = *(const s16x8*)(bpl + kn);
    int ao = swz(wr * 16 + fr, fq);
    s16x8 afh = *(const s16x8*)&Ah[ao];
    s16x8 afl = *(const s16x8*)&Al[ao];
#pragma unroll
    for (int n = 0; n < 2; ++n) {
      int bo = swz(wc * 32 + n * 16 + fr, fq);
      s16x8 bfh = *(const s16x8*)&Bh[bo];
      s16x8 bfl = *(const s16x8*)&Bl[bo];
      acc[n] = __builtin_amdgcn_mfma_f32_16x16x32_bf16(afh, bfh, acc[n], 0, 0, 0);
      acc[n] = __builtin_amdgcn_mfma_f32_16x16x32_bf16(afh, bfl, acc[n], 0, 0, 0);
      acc[n] = __builtin_amdgcn_mfma_f32_16x16x32_bf16(afl, bfh, acc[n], 0, 0, 0);
    }
  }

  float* Cb = logits + (size_t)batch * NCLS * NTOK;
#pragma unroll
  for (int n = 0; n < 2; ++n)
#pragma unroll
    for (int r = 0; r < 4; ++r) {
      int rg = row0 + wr * 16 + fq * 4 + r;
      int cg = col0 + wc * 32 + n * 16 + fr;
      Cb[(size_t)rg * NTOK + cg] = scale * acc[n][r];
    }
}

// -------- lin GEMM (fused lin1/lin2), 64x64, swizzled LDS, plain bf16,
//          leaky, single-buffer + overlap, XCD-chunked (384) ----
__global__ __launch_bounds__(256) void gemm_lin(
    const short* __restrict__ inbf, const short* __restrict__ L1T,
    const short* __restrict__ L2T, const float* __restrict__ b1,
    const float* __restrict__ b2, float* __restrict__ C) {
  __shared__ short Ah[64 * 32], Bh[64 * 32];
  const int bid = blockIdx.x;
  const int xcd = bid & 7, idx = bid >> 3;
  const int ytile = xcd * 4 + idx / 12, xtile = idx % 12;
  const int t = threadIdx.x;
  const int row0 = ytile * 64, col0 = xtile * 64;
  const bool second = row0 >= 1024;
  const int sr = t >> 2, sc = t & 3;
  const short* aptr = inbf + (size_t)(row0 + sr) * DDIM + sc * 8;
  const short* bptr = (second ? L2T : L1T) + (size_t)(col0 + sr) * DDIM + sc * 8;
  const float* biasu = second ? b2 : b1;
  const int lane = t & 63, wave = t >> 6;
  const int wr = wave >> 1, wc = wave & 1;
  const int fr = lane & 15, fq = lane >> 4;
  const int so = swz(sr, sc);

  f32x4 acc[2][2] = {};
  s16x8 rA = *(const s16x8*)(aptr);
  s16x8 rB = *(const s16x8*)(bptr);
  for (int kt = 0; kt < 24; ++kt) {
    __syncthreads();
    *(s16x8*)&Ah[so] = rA;
    *(s16x8*)&Bh[so] = rB;
    __syncthreads();
    const int kn = (kt < 23 ? kt + 1 : 23) * 32;
    rA = *(const s16x8*)(aptr + kn);
    rB = *(const s16x8*)(bptr + kn);
#pragma unroll
    for (int n = 0; n < 2; ++n) {
      int bo = swz(wc * 32 + n * 16 + fr, fq);
      s16x8 bfh = *(const s16x8*)&Bh[bo];
#pragma unroll
      for (int m = 0; m < 2; ++m) {
        int ao = swz(wr * 32 + m * 16 + fr, fq);
        s16x8 afh = *(const s16x8*)&Ah[ao];
        acc[m][n] =
            __builtin_amdgcn_mfma_f32_16x16x32_bf16(afh, bfh, acc[m][n], 0, 0, 0);
      }
    }
  }
#pragma unroll
  for (int m = 0; m < 2; ++m)
#pragma unroll
    for (int n = 0; n < 2; ++n)
#pragma unroll
      for (int r = 0; r < 4; ++r) {
        int rg = row0 + wr * 32 + m * 16 + fq * 4 + r;
        int cg = col0 + wc * 32 + n * 16 + fr;
        float v = acc[m][n][r] + biasu[cg];
        v = v > 0.f ? v : 0.01f * v;
        C[(size_t)rg * DDIM + cg] = v;
      }
}

// -------- top-k via 4-round byte radix select (set semantics) ------------
__global__ __launch_bounds__(256) void topk_select(
    const float* __restrict__ logits, float* __restrict__ tw,
    int* __restrict__ ti) {
  const int row = blockIdx.x;
  const int t = threadIdx.x;
  const int lane = t & 63, wave = t >> 6;
  __shared__ int hist[256];
  __shared__ int sh_bin, sh_rem;
  __shared__ int cnt;
  __shared__ int wsumT[4];

  float4 v4 = *(const float4*)(logits + (size_t)row * NTOK + 4 * t);
  float val[4] = {v4.x, v4.y, v4.z, v4.w};
  unsigned key[4];
#pragma unroll
  for (int i = 0; i < 4; ++i) {
    unsigned u = __float_as_uint(val[i]);
    key[i] = (u & 0x80000000u) ? ~u : (u | 0x80000000u);
  }

  unsigned pref = 0, mask = 0;
  int rem = KSEL;
#pragma unroll
  for (int shift = 24; shift >= 0; shift -= 8) {
    hist[t] = 0;
    __syncthreads();
#pragma unroll
    for (int i = 0; i < 4; ++i)
      if ((key[i] & mask) == pref)
        atomicAdd(&hist[(key[i] >> shift) & 255], 1);
    __syncthreads();
    if (wave == 0) {
      int h0 = hist[4 * lane], h1 = hist[4 * lane + 1];
      int h2 = hist[4 * lane + 2], h3 = hist[4 * lane + 3];
      int s = h0 + h1 + h2 + h3;
#pragma unroll
      for (int o = 1; o < 64; o <<= 1) {
        int v = __shfl_down(s, o, 64);
        if (lane + o < 64) s += v;
      }
      int abv = __shfl_down(s, 1, 64);
      if (lane == 63) abv = 0;
      int c3 = abv + h3, c2 = c3 + h2, c1 = c2 + h1, c0 = c1 + h0;
      int bin = -1, nab = 0;
      if (c3 >= rem && abv < rem) { bin = 4 * lane + 3; nab = abv; }
      else if (c2 >= rem && c3 < rem) { bin = 4 * lane + 2; nab = c3; }
      else if (c1 >= rem && c2 < rem) { bin = 4 * lane + 1; nab = c2; }
      else if (c0 >= rem && c1 < rem) { bin = 4 * lane + 0; nab = c1; }
      if (bin >= 0) { sh_bin = bin; sh_rem = rem - nab; }
    }
    __syncthreads();
    pref |= ((unsigned)sh_bin) << shift;
    mask |= 0xFFu << shift;
    rem = sh_rem;
  }

  const unsigned T = pref;
  const int above = KSEL - rem;

  if (t == 0) cnt = 0;
  int tc = 0;
#pragma unroll
  for (int i = 0; i < 4; ++i) tc += (key[i] == T);
  int inc = tc;
#pragma unroll
  for (int o = 1; o < 64; o <<= 1) {
    int v = __shfl_up(inc, o, 64);
    if (lane >= o) inc += v;
  }
  if (lane == 63) wsumT[wave] = inc;
  __syncthreads();
  int wbase = 0;
#pragma unroll
  for (int w = 0; w < 4; ++w)
    if (w < wave) wbase += wsumT[w];
  int excl = wbase + inc - tc;

  float* twr = tw + (size_t)row * KSEL;
  int* tir = ti + (size_t)row * KSEL;
#pragma unroll
  for (int i = 0; i < 4; ++i) {
    if (key[i] > T) {
      int slot = atomicAdd(&cnt, 1);
      twr[slot] = val[i];
      tir[slot] = 4 * t + i;
    } else if (key[i] == T) {
      int r = excl++;
      if (r < rem) {
        twr[above + r] = val[i];
        tir[above + r] = 4 * t + i;
      }
    }
  }
}

// -------- agg1: gated ka weights, bf16 e_h/e_t reads ---------------------
__global__ __launch_bounds__(256) void agg1(const short* __restrict__ eh_hi,
                                            const short* __restrict__ et_hi,
                                            const float* __restrict__ tw,
                                            const int* __restrict__ ti,
                                            float* __restrict__ kaw_raw) {
  const int bid = blockIdx.x;
  const int xcd = bid & 7, slot = bid >> 3;
  const int batch = xcd >> 1;
  const int u = ((xcd & 1) << 8) | slot;
  const int row = batch * 256 + (u >> 1);
  const int half = u & 1;
  const int t = threadIdx.x, lane = t & 63, wave = t >> 6;
  __shared__ float p[KSEL];
  __shared__ int idxs[KSEL];
  __shared__ float red[2];

  if (t < KSEL) {
    p[t] = tw[(size_t)row * KSEL + t];
    idxs[t] = ti[(size_t)row * KSEL + t];
  }
  __syncthreads();
  if (wave == 0) {
    float m = wmaxr(fmaxf(p[lane], p[lane + 64]));
    if (!lane) red[0] = m;
  }
  __syncthreads();
  if (t < KSEL) p[t] = __expf(p[t] - red[0]);
  __syncthreads();
  if (wave == 0) {
    float s = wsum(p[lane] + p[lane + 64]);
    if (!lane) red[1] = s;
  }
  __syncthreads();
  if (t < KSEL) p[t] *= (1.f / red[1]);
  __syncthreads();

  float ehr[12];
  {
    const short* ehrow = eh_hi + (size_t)row * DDIM;
#pragma unroll
    for (int c = 0; c < 3; ++c) {
      short4 v = *(const short4*)(ehrow + 4 * lane + 256 * c);
      ehr[4 * c + 0] = bf2f(v.x);
      ehr[4 * c + 1] = bf2f(v.y);
      ehr[4 * c + 2] = bf2f(v.z);
      ehr[4 * c + 3] = bf2f(v.w);
    }
  }
  const short* etb = et_hi + (size_t)batch * NTOK * DDIM;

  for (int i = 0; i < 16; ++i) {
    int j = half * 64 + wave * 16 + i;
    float pj = p[j];
    float a = 4.f - 2.f * pj, b2 = 2.f * pj;
    const short* nb = etb + (size_t)idxs[j] * DDIM;
    float partial = 0.f;
#pragma unroll
    for (int c = 0; c < 3; ++c) {
      short4 nv = *(const short4*)(nb + 4 * lane + 256 * c);
      float nq[4] = {bf2f(nv.x), bf2f(nv.y), bf2f(nv.z), bf2f(nv.w)};
#pragma unroll
      for (int q = 0; q < 4; ++q) {
        float y2 = fmaf(a, ehr[4 * c + q], b2 * nq[q]);
        float ex = __expf(y2);
        float g = fmaf(-2.f, __builtin_amdgcn_rcpf(1.f + ex), 1.f);
        partial = fmaf(nq[q], g, partial);
      }
    }
    partial = wsum(partial);
    if (!lane) kaw_raw[(size_t)row * KSEL + j] = partial;
  }
}

// -------- agg2: ka softmax + weighted sum (bf16 reads) -> bf16 lin inputs
__global__ __launch_bounds__(192) void agg2(
    const short* __restrict__ eh_hi, const short* __restrict__ et_hi,
    const float* __restrict__ cls, const float* __restrict__ kaw_raw,
    const int* __restrict__ ti, short* __restrict__ inbf) {
  const int bid = blockIdx.x;
  const int xcd = bid & 7, slot = bid >> 3;
  const int batch = xcd >> 1;
  const int row = batch * 256 + (xcd & 1) * 128 + slot;
  const int t = threadIdx.x, lane = t & 63, wave = t >> 6;
  __shared__ float kp[KSEL];
  __shared__ int idxs[KSEL];
  __shared__ float red[2];

  if (t < KSEL) {
    kp[t] = kaw_raw[(size_t)row * KSEL + t];
    idxs[t] = ti[(size_t)row * KSEL + t];
  }
  __syncthreads();
  if (wave == 0) {
    float m = wmaxr(fmaxf(kp[lane], kp[lane + 64]));
    if (!lane) red[0] = m;
  }
  __syncthreads();
  if (t < KSEL) kp[t] = __expf(kp[t] - red[0]);
  __syncthreads();
  if (wave == 0) {
    float s = wsum(kp[lane] + kp[lane + 64]);
    if (!lane) red[1] = s;
  }
  __syncthreads();
  if (t < KSEL) kp[t] *= (1.f / red[1]);
  __syncthreads();

  const size_t o = (size_t)row * DDIM + 4 * t;
  short4 ehs = *(const short4*)(eh_hi + o);
  float4 eh4 = {bf2f(ehs.x), bf2f(ehs.y), bf2f(ehs.z), bf2f(ehs.w)};
  float4 cl4 = *(const float4*)(cls + o);
  const short* etb = et_hi + (size_t)batch * NTOK * DDIM;

  float ax = 0.f, ay = 0.f, az = 0.f, aw = 0.f;
#pragma unroll 8
  for (int j = 0; j < KSEL; ++j) {
    float pr = kp[j];
    short4 nb = *(const short4*)(etb + (size_t)idxs[j] * DDIM + 4 * t);
    ax = fmaf(pr, bf2f(nb.x), ax);
    ay = fmaf(pr, bf2f(nb.y), ay);
    az = fmaf(pr, bf2f(nb.z), az);
    aw = fmaf(pr, bf2f(nb.w), aw);
  }

  short4 sv, bv;
  sv.x = f2bf((eh4.x + ax) * 0.1f + cl4.x);
  sv.y = f2bf((eh4.y + ay) * 0.1f + cl4.y);
  sv.z = f2bf((eh4.z + az) * 0.1f + cl4.z);
  sv.w = f2bf((eh4.w + aw) * 0.1f + cl4.w);
  bv.x = f2bf((eh4.x * ax) * 0.1f + cl4.x);
  bv.y = f2bf((eh4.y * ay) * 0.1f + cl4.y);
  bv.z = f2bf((eh4.z * az) * 0.1f + cl4.z);
  bv.w = f2bf((eh4.w * aw) * 0.1f + cl4.w);
  *(short4*)&inbf[o] = sv;
  *(short4*)&inbf[(size_t)(NBATCH * NCLS) * DDIM + o] = bv;
}

// -------- layernorm over D=768 on (embA[row] + embB[row]) --------
__global__ __launch_bounds__(256) void ln_kernel(const float* __restrict__ embA,
                                                 const float* __restrict__ embB,
                                                 const float* __restrict__ lw,
                                                 const float* __restrict__ lb,
                                                 float* __restrict__ out) {
  const int row = blockIdx.x;
  const int t = threadIdx.x;
  const int lane = t & 63, wave = t >> 6;
  __shared__ float red[4];
  __shared__ float bs[2];
  float e[3];
#pragma unroll
  for (int c = 0; c < 3; ++c) {
    size_t o = (size_t)row * DDIM + t + 256 * c;
    e[c] = embA[o] + embB[o];
  }
  float s = e[0] + e[1] + e[2];
  s = wsum(s);
  if (lane == 0) red[wave] = s;
  __syncthreads();
  if (t == 0) bs[0] = (red[0] + red[1] + red[2] + red[3]) * (1.f / DDIM);
  __syncthreads();
  float mu = bs[0];
  float q = 0.f;
#pragma unroll
  for (int c = 0; c < 3; ++c) {
    float d = e[c] - mu;
    q = fmaf(d, d, q);
  }
  q = wsum(q);
  if (lane == 0) red[wave] = q;
  __syncthreads();
  if (t == 0) bs[1] = (red[0] + red[1] + red[2] + red[3]) * (1.f / DDIM);
  __syncthreads();
  float rstd = rsqrtf(bs[1] + 1e-5f);
#pragma unroll
  for (int c = 0; c < 3; ++c) {
    int d = t + 256 * c;
    out[(size_t)row * DDIM + d] = (e[c] - mu) * rstd * lw[d] + lb[d];
  }
}

// ---------------- launch ----------------
extern "C" void kernel_launch(void* const* d_in, const int* in_sizes, int n_in,
                              void* d_out, int out_size, void* d_ws,
                              size_t ws_size, hipStream_t stream) {
  const float* cls = (const float*)d_in[0];
  const float* feats = (const float*)d_in[1];
  const float* Whw = (const float*)d_in[2];
  const float* Whb = (const float*)d_in[3];
  const float* Wtw = (const float*)d_in[4];
  const float* Wtb = (const float*)d_in[5];
  const float* l1w = (const float*)d_in[6];
  const float* l1b = (const float*)d_in[7];
  const float* l2w = (const float*)d_in[8];
  const float* l2b = (const float*)d_in[9];
  const float* lnw = (const float*)d_in[10];
  const float* lnb = (const float*)d_in[11];
  float* out = (float*)d_out;

  float* ws = (float*)d_ws;
  // layout (float units)
  float* linC = ws;                         // 1572864 (lin outputs, 2 halves)
  short* eh_hi = (short*)(ws + 3932160);    // 786432 shorts
  short* eh_lo = eh_hi + 786432;            // (ends 4718592f)
  short* et_hi = (short*)(ws + 4718592);    // 3145728 shorts
  short* et_lo = et_hi + 3145728;           // (ends 7864320f)
  short* WhT_h = (short*)(ws + 7864320);    // 589824 shorts each
  short* WhT_l = WhT_h + 589824;
  short* WtT_h = WhT_h + 2 * 589824;
  short* WtT_l = WhT_h + 3 * 589824;        // (ends 9043968f)
  short* L1T = (short*)(ws + 9043968);      // 589824 shorts
  short* L2T = L1T + 589824;                // (ends 9633792f)
  float* logits = ws + 7864320;             // overlays WhT/WtT (dead by then)
  short* Xh = (short*)(ws + 9633792);       // X bf16 hi/lo; dead after front
  short* Xl = Xh + 3145728;                 // (ends 12779520f)
  float* tw = ws + 9633792;                 // 131072 (overlays Xh - X dead)
  int* ti = (int*)(ws + 9764864);           // 131072
  float* kaw = ws + 9895936;                // 131072
  short* inbf = (short*)(ws + 10027008);    // 2048*768 shorts (786432 f)
  (void)ws_size;
  (void)in_sizes;
  (void)n_in;
  (void)out_size;

  const float scale = 0.036084391824351615f;  // 1/sqrt(768)
  dim3 blk(256);

  // X -> packed bf16 hi/lo (4096 rows x 768)
  xprep<<<dim3(1536), blk, 0, stream>>>(cls, feats, Xh, Xl);
  // weights -> transposed bf16 (hi/lo for Wh/Wt, plain for L1/L2)
  prep_weights<<<dim3(24, 24, 4), blk, 0, stream>>>(
      Whw, Wtw, l1w, l2w, WhT_h, WtT_h, L1T, L2T, WhT_l, WtT_l);
  // fused e_h | e_t (480 blocks, 128x64, XCD-chunked, swizzled LDS)
  gemm_front<<<dim3(480), blk, 0, stream>>>(
      Xh, Xl, WhT_h, WhT_l, Whb, WtT_h, WtT_l, Wtb, eh_hi, eh_lo, et_hi,
      et_lo);
  // logits[b] = scale * e_h[b] @ e_t[b]^T (512 blocks, batch->XCD)
  gemm_logits<<<dim3(512), blk, 0, stream>>>(eh_hi, eh_lo, et_hi, et_lo,
                                             logits, scale);
  // top-128 per row (radix select)
  topk_select<<<dim3(NBATCH * NCLS), blk, 0, stream>>>(logits, tw, ti);
  // agg1: gated ka weights (2048 blocks, bf16 reads)
  agg1<<<dim3(2048), blk, 0, stream>>>(eh_hi, et_hi, tw, ti, kaw);
  // agg2: softmax + weighted sum -> bf16 lin inputs
  agg2<<<dim3(1024), dim3(192), 0, stream>>>(eh_hi, et_hi, cls, kaw, ti, inbf);
  // fused lin1/lin2 (384 blocks, XCD-chunked, swizzled LDS)
  gemm_lin<<<dim3(384), blk, 0, stream>>>(inbf, L1T, L2T, l1b, l2b, linC);
  // layernorm(sum_emb + bi_emb) -> out
  ln_kernel<<<dim3(NBATCH * NCLS), blk, 0, stream>>>(
      linC, linC + (size_t)(NBATCH * NCLS) * DDIM, lnw, lnb, out);
}

// Round 11
// 124.236 us; speedup vs baseline: 1.1061x; 1.0117x over previous
//
#include <hip/hip_runtime.h>
#include <hip/hip_bf16.h>
#include <math.h>

#define DDIM 768
#define NCLS 256
#define NFEAT 768
#define NTOK 1024
#define NBATCH 4
#define KSEL 128

typedef float f32x4 __attribute__((ext_vector_type(4)));
typedef short s16x8 __attribute__((ext_vector_type(8)));

// ---------------- helpers ----------------
__device__ __forceinline__ float wsum(float v) {
#pragma unroll
  for (int o = 32; o; o >>= 1) v += __shfl_down(v, o, 64);
  return v;
}
__device__ __forceinline__ float wmaxr(float v) {
#pragma unroll
  for (int o = 32; o; o >>= 1) v = fmaxf(v, __shfl_down(v, o, 64));
  return v;
}
__device__ __forceinline__ short f2bf(float f) {
  union { __hip_bfloat16 h; short s; } u;
  u.h = __float2bfloat16(f);
  return u.s;
}
__device__ __forceinline__ float bf2f(short s) {
  union { unsigned u; float f; } c;
  c.u = ((unsigned)(unsigned short)s) << 16;
  return c.f;
}
__device__ __forceinline__ void cvt8(float4 x, float4 y, s16x8& h, s16x8& l) {
  float v[8] = {x.x, x.y, x.z, x.w, y.x, y.y, y.z, y.w};
#pragma unroll
  for (int i = 0; i < 8; ++i) {
    short hh = f2bf(v[i]);
    h[i] = hh;
    l[i] = f2bf(v[i] - bf2f(hh));
  }
}
// LDS address swizzle: 32-short (64B) rows, 8-short (16B) chunks.
__device__ __forceinline__ int swz(int row, int chunk) {
  return (row << 5) + (((chunk ^ (row >> 1)) & 3) << 3);
}

// -------- merged prep: blocks 0..2303 = weight transpose+cvt,
//          blocks 2304..3839 = X pack (concat(cls,feats) -> hi/lo) -------
__global__ __launch_bounds__(256) void prep_all(
    const float* __restrict__ cls, const float* __restrict__ feats,
    const float* __restrict__ w0, const float* __restrict__ w1,
    const float* __restrict__ w2, const float* __restrict__ w3,
    short* __restrict__ h0, short* __restrict__ h1, short* __restrict__ h2,
    short* __restrict__ h3, short* __restrict__ l0, short* __restrict__ l1,
    short* __restrict__ Xh, short* __restrict__ Xl) {
  __shared__ float tile[32][33];
  const int bid = blockIdx.x;
  const int t = threadIdx.x;
  if (bid < 2304) {
    const int z = bid / 576, rem = bid % 576;
    const int by = rem / 24, bx = rem % 24;
    const float* s = z == 0 ? w0 : z == 1 ? w1 : z == 2 ? w2 : w3;
    short* dh = z == 0 ? h0 : z == 1 ? h1 : z == 2 ? h2 : h3;
    short* dl = z == 0 ? l0 : z == 1 ? l1 : nullptr;
    const int tx = t & 31, ty0 = t >> 5;
    const int r0 = by * 32, c0 = bx * 32;
#pragma unroll
    for (int i = 0; i < 4; ++i) {
      int ty = ty0 + i * 8;
      tile[ty][tx] = s[(size_t)(r0 + ty) * DDIM + c0 + tx];
    }
    __syncthreads();
#pragma unroll
    for (int i = 0; i < 4; ++i) {
      int ty = ty0 + i * 8;
      float v = tile[tx][ty];
      short hh = f2bf(v);
      dh[(size_t)(c0 + ty) * DDIM + r0 + tx] = hh;
      if (dl) dl[(size_t)(c0 + ty) * DDIM + r0 + tx] = f2bf(v - bf2f(hh));
    }
  } else {
    const size_t base = ((size_t)(bid - 2304) * 256 + t) * 8;
    const int row = (int)(base / DDIM);
    const int col = (int)(base % DDIM);
    const int b = row >> 10, rr = row & 1023;
    const float* src =
        (rr < NCLS) ? cls + ((size_t)b * NCLS + rr) * DDIM + col
                    : feats + ((size_t)b * NFEAT + (rr - NCLS)) * DDIM + col;
    float4 a0 = *(const float4*)(src);
    float4 a1 = *(const float4*)(src + 4);
    s16x8 h, l;
    cvt8(a0, a1, h, l);
    *(s16x8*)(Xh + base) = h;
    *(s16x8*)(Xl + base) = l;
  }
}

// -------- front GEMM (fused e_h | e_t), 128x64 tiles, split-bf16,
//          bf16 hi/lo outputs only, swizzled LDS, XCD-chunked (480) -----
__global__ __launch_bounds__(256) void gemm_front(
    const short* __restrict__ Xh, const short* __restrict__ Xl,
    const short* __restrict__ WhT_h, const short* __restrict__ WhT_l,
    const float* __restrict__ Whb, const short* __restrict__ WtT_h,
    const short* __restrict__ WtT_l, const float* __restrict__ Wtb,
    short* __restrict__ eh_hi, short* __restrict__ eh_lo,
    short* __restrict__ et_hi, short* __restrict__ et_lo) {
  __shared__ short Ah[128 * 32], Al[128 * 32];
  __shared__ short Bh[64 * 32], Bl[64 * 32];
  const int bid = blockIdx.x;
  const int xcd = bid & 7, idx = bid >> 3;  // idx 0..59
  const int ytile = xcd * 5 + idx / 12;     // 0..39
  const int xtile = idx % 12;
  const int t = threadIdx.x;
  const int row0 = ytile * 128, col0 = xtile * 64;
  const bool head = row0 < 1024;

  const int ar = t >> 1, ac = (t & 1) * 2;
  const int aw0 = swz(ar, ac), aw1 = swz(ar, ac + 1);
  size_t xrow;
  {
    int gr = row0 + ar;
    xrow = head ? (size_t)(((gr >> 8) << 10) + (gr & 255)) : (size_t)(gr - 1024);
  }
  const short* aph = Xh + xrow * DDIM + ac * 8;
  const short* apl = Xl + xrow * DDIM + ac * 8;
  const int br = t >> 2, bc = t & 3;
  const int bw0 = swz(br, bc);
  const short* bph = (head ? WhT_h : WtT_h) + (size_t)(col0 + br) * DDIM + bc * 8;
  const short* bpl = (head ? WhT_l : WtT_l) + (size_t)(col0 + br) * DDIM + bc * 8;
  const float* biasu = head ? Whb : Wtb;

  const int lane = t & 63, wave = t >> 6;
  const int wr = wave >> 1, wc = wave & 1;
  const int fr = lane & 15, fq = lane >> 4;

  f32x4 acc[4][2] = {};
  s16x8 rah0 = *(const s16x8*)(aph);
  s16x8 rah1 = *(const s16x8*)(aph + 8);
  s16x8 ral0 = *(const s16x8*)(apl);
  s16x8 ral1 = *(const s16x8*)(apl + 8);
  s16x8 rbh = *(const s16x8*)(bph);
  s16x8 rbl = *(const s16x8*)(bpl);

  for (int kt = 0; kt < 24; ++kt) {
    __syncthreads();
    *(s16x8*)&Ah[aw0] = rah0;
    *(s16x8*)&Ah[aw1] = rah1;
    *(s16x8*)&Al[aw0] = ral0;
    *(s16x8*)&Al[aw1] = ral1;
    *(s16x8*)&Bh[bw0] = rbh;
    *(s16x8*)&Bl[bw0] = rbl;
    __syncthreads();
    const int kn = (kt < 23 ? kt + 1 : 23) * 32;
    rah0 = *(const s16x8*)(aph + kn);
    rah1 = *(const s16x8*)(aph + kn + 8);
    ral0 = *(const s16x8*)(apl + kn);
    ral1 = *(const s16x8*)(apl + kn + 8);
    rbh = *(const s16x8*)(bph + kn);
    rbl = *(const s16x8*)(bpl + kn);

    s16x8 afh[4], afl[4];
#pragma unroll
    for (int m = 0; m < 4; ++m) {
      int ao = swz(wr * 64 + m * 16 + fr, fq);
      afh[m] = *(const s16x8*)&Ah[ao];
      afl[m] = *(const s16x8*)&Al[ao];
    }
#pragma unroll
    for (int n = 0; n < 2; ++n) {
      int bo = swz(wc * 32 + n * 16 + fr, fq);
      s16x8 bfh = *(const s16x8*)&Bh[bo];
      s16x8 bfl = *(const s16x8*)&Bl[bo];
#pragma unroll
      for (int m = 0; m < 4; ++m) {
        acc[m][n] =
            __builtin_amdgcn_mfma_f32_16x16x32_bf16(afh[m], bfh, acc[m][n], 0, 0, 0);
        acc[m][n] =
            __builtin_amdgcn_mfma_f32_16x16x32_bf16(afh[m], bfl, acc[m][n], 0, 0, 0);
        acc[m][n] =
            __builtin_amdgcn_mfma_f32_16x16x32_bf16(afl[m], bfh, acc[m][n], 0, 0, 0);
      }
    }
  }

  short* Ch = head ? eh_hi : et_hi;
  short* Cl = head ? eh_lo : et_lo;
  const int rbase = head ? row0 : row0 - 1024;
#pragma unroll
  for (int m = 0; m < 4; ++m) {
#pragma unroll
    for (int n = 0; n < 2; ++n) {
#pragma unroll
      for (int r = 0; r < 4; ++r) {
        int rg = rbase + wr * 64 + m * 16 + fq * 4 + r;
        int cg = col0 + wc * 32 + n * 16 + fr;
        float v = acc[m][n][r] + biasu[cg];
        size_t o = (size_t)rg * DDIM + cg;
        short hh = f2bf(v);
        Ch[o] = hh;
        Cl[o] = f2bf(v - bf2f(hh));
      }
    }
  }
}

// -------- logits GEMM: 32x64 tiles, swizzled LDS, 512 blocks,
//          batch->XCD affinity, single-buffer + overlap --------
__global__ __launch_bounds__(256) void gemm_logits(
    const short* __restrict__ eh_hi, const short* __restrict__ eh_lo,
    const short* __restrict__ et_hi, const short* __restrict__ et_lo,
    float* __restrict__ logits, float scale) {
  __shared__ short Ah[32 * 32], Al[32 * 32];
  __shared__ short Bh[64 * 32], Bl[64 * 32];
  const int bid = blockIdx.x;
  const int xcd = bid & 7, idx = bid >> 3;
  const int batch = xcd >> 1;
  const int sub = ((xcd & 1) << 6) | idx;
  const int xtile = sub & 15, ytile = sub >> 4;
  const int row0 = ytile * 32, col0 = xtile * 64;
  const int t = threadIdx.x;

  const int ahalf = t >> 7, ac2 = t & 127;
  const int asr = ac2 >> 2, acc_ = ac2 & 3;
  const short* aptr = (ahalf ? eh_lo : eh_hi) +
                      ((size_t)batch * NCLS + row0 + asr) * DDIM + acc_ * 8;
  const int aso = swz(asr, acc_);
  const int bsr = t >> 2, bcc = t & 3;
  const short* bph = et_hi + ((size_t)batch * NTOK + col0 + bsr) * DDIM + bcc * 8;
  const short* bpl = et_lo + ((size_t)batch * NTOK + col0 + bsr) * DDIM + bcc * 8;
  const int bso = swz(bsr, bcc);

  const int lane = t & 63, wave = t >> 6;
  const int wr = wave >> 1, wc = wave & 1;
  const int fr = lane & 15, fq = lane >> 4;

  f32x4 acc[2] = {};
  s16x8 rA = *(const s16x8*)(aptr);
  s16x8 rbh = *(const s16x8*)(bph);
  s16x8 rbl = *(const s16x8*)(bpl);

  for (int kt = 0; kt < 24; ++kt) {
    __syncthreads();
    *(s16x8*)&(ahalf ? Al : Ah)[aso] = rA;
    *(s16x8*)&Bh[bso] = rbh;
    *(s16x8*)&Bl[bso] = rbl;
    __syncthreads();
    const int kn = (kt < 23 ? kt + 1 : 23) * 32;
    rA = *(const s16x8*)(aptr + kn);
    rbh = *(const s16x8*)(bph + kn);
    rbl = *(const s16x8*)(bpl + kn);
    int ao = swz(wr * 16 + fr, fq);
    s16x8 afh = *(const s16x8*)&Ah[ao];
    s16x8 afl = *(const s16x8*)&Al[ao];
#pragma unroll
    for (int n = 0; n < 2; ++n) {
      int bo = swz(wc * 32 + n * 16 + fr, fq);
      s16x8 bfh = *(const s16x8*)&Bh[bo];
      s16x8 bfl = *(const s16x8*)&Bl[bo];
      acc[n] = __builtin_amdgcn_mfma_f32_16x16x32_bf16(afh, bfh, acc[n], 0, 0, 0);
      acc[n] = __builtin_amdgcn_mfma_f32_16x16x32_bf16(afh, bfl, acc[n], 0, 0, 0);
      acc[n] = __builtin_amdgcn_mfma_f32_16x16x32_bf16(afl, bfh, acc[n], 0, 0, 0);
    }
  }

  float* Cb = logits + (size_t)batch * NCLS * NTOK;
#pragma unroll
  for (int n = 0; n < 2; ++n)
#pragma unroll
    for (int r = 0; r < 4; ++r) {
      int rg = row0 + wr * 16 + fq * 4 + r;
      int cg = col0 + wc * 32 + n * 16 + fr;
      Cb[(size_t)rg * NTOK + cg] = scale * acc[n][r];
    }
}

// -------- lin GEMM fused: both lin1 & lin2 per tile -> emb directly,
//          32x64 tiles, swizzled LDS, XCD-chunked (384 = 8 x 48) --------
__global__ __launch_bounds__(256) void gemm_lin(
    const short* __restrict__ inbf, const short* __restrict__ L1T,
    const short* __restrict__ L2T, const float* __restrict__ b1,
    const float* __restrict__ b2, float* __restrict__ emb) {
  __shared__ short A1[32 * 32], A2[32 * 32];
  __shared__ short B1[64 * 32], B2[64 * 32];
  const int bid = blockIdx.x;
  const int xcd = bid & 7, idx = bid >> 3;  // 0..47
  const int ytile = xcd * 4 + idx / 12, xtile = idx % 12;  // 32 x 12
  const int t = threadIdx.x;
  const int row0 = ytile * 32, col0 = xtile * 64;

  const int ahalf = t >> 7, at = t & 127;
  const int asr = at >> 2, asc = at & 3;
  const short* aptr = inbf + (ahalf ? (size_t)1024 * DDIM : 0) +
                      (size_t)(row0 + asr) * DDIM + asc * 8;
  const int aso = swz(asr, asc);
  const int bsr = t >> 2, bsc = t & 3;
  const short* b1p = L1T + (size_t)(col0 + bsr) * DDIM + bsc * 8;
  const short* b2p = L2T + (size_t)(col0 + bsr) * DDIM + bsc * 8;
  const int bso = swz(bsr, bsc);

  const int lane = t & 63, wave = t >> 6;
  const int wr = wave >> 1, wc = wave & 1;
  const int fr = lane & 15, fq = lane >> 4;

  f32x4 acc1[2] = {}, acc2[2] = {};
  s16x8 rA = *(const s16x8*)(aptr);
  s16x8 rB1 = *(const s16x8*)(b1p);
  s16x8 rB2 = *(const s16x8*)(b2p);
  for (int kt = 0; kt < 24; ++kt) {
    __syncthreads();
    *(s16x8*)&(ahalf ? A2 : A1)[aso] = rA;
    *(s16x8*)&B1[bso] = rB1;
    *(s16x8*)&B2[bso] = rB2;
    __syncthreads();
    const int kn = (kt < 23 ? kt + 1 : 23) * 32;
    rA = *(const s16x8*)(aptr + kn);
    rB1 = *(const s16x8*)(b1p + kn);
    rB2 = *(const s16x8*)(b2p + kn);
    int ao = swz(wr * 16 + fr, fq);
    s16x8 a1f = *(const s16x8*)&A1[ao];
    s16x8 a2f = *(const s16x8*)&A2[ao];
#pragma unroll
    for (int n = 0; n < 2; ++n) {
      int bo = swz(wc * 32 + n * 16 + fr, fq);
      s16x8 b1f = *(const s16x8*)&B1[bo];
      s16x8 b2f = *(const s16x8*)&B2[bo];
      acc1[n] = __builtin_amdgcn_mfma_f32_16x16x32_bf16(a1f, b1f, acc1[n], 0, 0, 0);
      acc2[n] = __builtin_amdgcn_mfma_f32_16x16x32_bf16(a2f, b2f, acc2[n], 0, 0, 0);
    }
  }
#pragma unroll
  for (int n = 0; n < 2; ++n)
#pragma unroll
    for (int r = 0; r < 4; ++r) {
      int rg = row0 + wr * 16 + fq * 4 + r;
      int cg = col0 + wc * 32 + n * 16 + fr;
      float v1 = acc1[n][r] + b1[cg];
      v1 = v1 > 0.f ? v1 : 0.01f * v1;
      float v2 = acc2[n][r] + b2[cg];
      v2 = v2 > 0.f ? v2 : 0.01f * v2;
      emb[(size_t)rg * DDIM + cg] = v1 + v2;
    }
}

// -------- top-k via 4-round byte radix select (set semantics) ------------
__global__ __launch_bounds__(256) void topk_select(
    const float* __restrict__ logits, float* __restrict__ tw,
    int* __restrict__ ti) {
  const int row = blockIdx.x;
  const int t = threadIdx.x;
  const int lane = t & 63, wave = t >> 6;
  __shared__ int hist[256];
  __shared__ int sh_bin, sh_rem;
  __shared__ int cnt;
  __shared__ int wsumT[4];

  float4 v4 = *(const float4*)(logits + (size_t)row * NTOK + 4 * t);
  float val[4] = {v4.x, v4.y, v4.z, v4.w};
  unsigned key[4];
#pragma unroll
  for (int i = 0; i < 4; ++i) {
    unsigned u = __float_as_uint(val[i]);
    key[i] = (u & 0x80000000u) ? ~u : (u | 0x80000000u);
  }

  unsigned pref = 0, mask = 0;
  int rem = KSEL;
#pragma unroll
  for (int shift = 24; shift >= 0; shift -= 8) {
    hist[t] = 0;
    __syncthreads();
#pragma unroll
    for (int i = 0; i < 4; ++i)
      if ((key[i] & mask) == pref)
        atomicAdd(&hist[(key[i] >> shift) & 255], 1);
    __syncthreads();
    if (wave == 0) {
      int h0 = hist[4 * lane], h1 = hist[4 * lane + 1];
      int h2 = hist[4 * lane + 2], h3 = hist[4 * lane + 3];
      int s = h0 + h1 + h2 + h3;
#pragma unroll
      for (int o = 1; o < 64; o <<= 1) {
        int v = __shfl_down(s, o, 64);
        if (lane + o < 64) s += v;
      }
      int abv = __shfl_down(s, 1, 64);
      if (lane == 63) abv = 0;
      int c3 = abv + h3, c2 = c3 + h2, c1 = c2 + h1, c0 = c1 + h0;
      int bin = -1, nab = 0;
      if (c3 >= rem && abv < rem) { bin = 4 * lane + 3; nab = abv; }
      else if (c2 >= rem && c3 < rem) { bin = 4 * lane + 2; nab = c3; }
      else if (c1 >= rem && c2 < rem) { bin = 4 * lane + 1; nab = c2; }
      else if (c0 >= rem && c1 < rem) { bin = 4 * lane + 0; nab = c1; }
      if (bin >= 0) { sh_bin = bin; sh_rem = rem - nab; }
    }
    __syncthreads();
    pref |= ((unsigned)sh_bin) << shift;
    mask |= 0xFFu << shift;
    rem = sh_rem;
  }

  const unsigned T = pref;
  const int above = KSEL - rem;

  if (t == 0) cnt = 0;
  int tc = 0;
#pragma unroll
  for (int i = 0; i < 4; ++i) tc += (key[i] == T);
  int inc = tc;
#pragma unroll
  for (int o = 1; o < 64; o <<= 1) {
    int v = __shfl_up(inc, o, 64);
    if (lane >= o) inc += v;
  }
  if (lane == 63) wsumT[wave] = inc;
  __syncthreads();
  int wbase = 0;
#pragma unroll
  for (int w = 0; w < 4; ++w)
    if (w < wave) wbase += wsumT[w];
  int excl = wbase + inc - tc;

  float* twr = tw + (size_t)row * KSEL;
  int* tir = ti + (size_t)row * KSEL;
#pragma unroll
  for (int i = 0; i < 4; ++i) {
    if (key[i] > T) {
      int slot = atomicAdd(&cnt, 1);
      twr[slot] = val[i];
      tir[slot] = 4 * t + i;
    } else if (key[i] == T) {
      int r = excl++;
      if (r < rem) {
        twr[above + r] = val[i];
        tir[above + r] = 4 * t + i;
      }
    }
  }
}

// -------- agg1: gated ka weights, bf16 reads, 12 elems/lane -------------
__global__ __launch_bounds__(256) void agg1(const short* __restrict__ eh_hi,
                                            const short* __restrict__ et_hi,
                                            const float* __restrict__ tw,
                                            const int* __restrict__ ti,
                                            float* __restrict__ kaw_raw) {
  const int bid = blockIdx.x;
  const int xcd = bid & 7, slot = bid >> 3;
  const int batch = xcd >> 1;
  const int u = ((xcd & 1) << 8) | slot;
  const int row = batch * 256 + (u >> 1);
  const int half = u & 1;
  const int t = threadIdx.x, lane = t & 63, wave = t >> 6;
  __shared__ float p[KSEL];
  __shared__ int idxs[KSEL];
  __shared__ float red[2];

  if (t < KSEL) {
    p[t] = tw[(size_t)row * KSEL + t];
    idxs[t] = ti[(size_t)row * KSEL + t];
  }
  __syncthreads();
  if (wave == 0) {
    float m = wmaxr(fmaxf(p[lane], p[lane + 64]));
    if (!lane) red[0] = m;
  }
  __syncthreads();
  if (t < KSEL) p[t] = __expf(p[t] - red[0]);
  __syncthreads();
  if (wave == 0) {
    float s = wsum(p[lane] + p[lane + 64]);
    if (!lane) red[1] = s;
  }
  __syncthreads();
  if (t < KSEL) p[t] *= (1.f / red[1]);
  __syncthreads();

  // lane owns 12 elems: [8*lane .. 8*lane+7] and [512+4*lane .. +3]
  float ehr[12];
  {
    const short* ehrow = eh_hi + (size_t)row * DDIM;
    s16x8 e8 = *(const s16x8*)(ehrow + 8 * lane);
    short4 e4 = *(const short4*)(ehrow + 512 + 4 * lane);
#pragma unroll
    for (int i = 0; i < 8; ++i) ehr[i] = bf2f(e8[i]);
    ehr[8] = bf2f(e4.x);
    ehr[9] = bf2f(e4.y);
    ehr[10] = bf2f(e4.z);
    ehr[11] = bf2f(e4.w);
  }
  const short* etb = et_hi + (size_t)batch * NTOK * DDIM;

  for (int i = 0; i < 16; ++i) {
    int j = half * 64 + wave * 16 + i;
    float pj = p[j];
    float a = 4.f - 2.f * pj, b2 = 2.f * pj;
    const short* nb = etb + (size_t)idxs[j] * DDIM;
    s16x8 n8 = *(const s16x8*)(nb + 8 * lane);
    short4 n4 = *(const short4*)(nb + 512 + 4 * lane);
    float nq[12];
#pragma unroll
    for (int q = 0; q < 8; ++q) nq[q] = bf2f(n8[q]);
    nq[8] = bf2f(n4.x);
    nq[9] = bf2f(n4.y);
    nq[10] = bf2f(n4.z);
    nq[11] = bf2f(n4.w);
    float partial = 0.f;
#pragma unroll
    for (int q = 0; q < 12; ++q) {
      float y2 = fmaf(a, ehr[q], b2 * nq[q]);
      float ex = __expf(y2);
      float g = fmaf(-2.f, __builtin_amdgcn_rcpf(1.f + ex), 1.f);
      partial = fmaf(nq[q], g, partial);
    }
    partial = wsum(partial);
    if (!lane) kaw_raw[(size_t)row * KSEL + j] = partial;
  }
}

// -------- agg2: ka softmax + weighted sum (bf16 reads) -> bf16 lin inputs
__global__ __launch_bounds__(192) void agg2(
    const short* __restrict__ eh_hi, const short* __restrict__ et_hi,
    const float* __restrict__ cls, const float* __restrict__ kaw_raw,
    const int* __restrict__ ti, short* __restrict__ inbf) {
  const int bid = blockIdx.x;
  const int xcd = bid & 7, slot = bid >> 3;
  const int batch = xcd >> 1;
  const int row = batch * 256 + (xcd & 1) * 128 + slot;
  const int t = threadIdx.x, lane = t & 63, wave = t >> 6;
  __shared__ float kp[KSEL];
  __shared__ int idxs[KSEL];
  __shared__ float red[2];

  if (t < KSEL) {
    kp[t] = kaw_raw[(size_t)row * KSEL + t];
    idxs[t] = ti[(size_t)row * KSEL + t];
  }
  __syncthreads();
  if (wave == 0) {
    float m = wmaxr(fmaxf(kp[lane], kp[lane + 64]));
    if (!lane) red[0] = m;
  }
  __syncthreads();
  if (t < KSEL) kp[t] = __expf(kp[t] - red[0]);
  __syncthreads();
  if (wave == 0) {
    float s = wsum(kp[lane] + kp[lane + 64]);
    if (!lane) red[1] = s;
  }
  __syncthreads();
  if (t < KSEL) kp[t] *= (1.f / red[1]);
  __syncthreads();

  const size_t o = (size_t)row * DDIM + 4 * t;
  short4 ehs = *(const short4*)(eh_hi + o);
  float4 eh4 = {bf2f(ehs.x), bf2f(ehs.y), bf2f(ehs.z), bf2f(ehs.w)};
  float4 cl4 = *(const float4*)(cls + o);
  const short* etb = et_hi + (size_t)batch * NTOK * DDIM;

  float ax = 0.f, ay = 0.f, az = 0.f, aw = 0.f;
#pragma unroll 8
  for (int j = 0; j < KSEL; ++j) {
    float pr = kp[j];
    short4 nb = *(const short4*)(etb + (size_t)idxs[j] * DDIM + 4 * t);
    ax = fmaf(pr, bf2f(nb.x), ax);
    ay = fmaf(pr, bf2f(nb.y), ay);
    az = fmaf(pr, bf2f(nb.z), az);
    aw = fmaf(pr, bf2f(nb.w), aw);
  }

  short4 sv, bv;
  sv.x = f2bf((eh4.x + ax) * 0.1f + cl4.x);
  sv.y = f2bf((eh4.y + ay) * 0.1f + cl4.y);
  sv.z = f2bf((eh4.z + az) * 0.1f + cl4.z);
  sv.w = f2bf((eh4.w + aw) * 0.1f + cl4.w);
  bv.x = f2bf((eh4.x * ax) * 0.1f + cl4.x);
  bv.y = f2bf((eh4.y * ay) * 0.1f + cl4.y);
  bv.z = f2bf((eh4.z * az) * 0.1f + cl4.z);
  bv.w = f2bf((eh4.w * aw) * 0.1f + cl4.w);
  *(short4*)&inbf[o] = sv;
  *(short4*)&inbf[(size_t)(NBATCH * NCLS) * DDIM + o] = bv;
}

// -------- layernorm over D=768 --------
__global__ __launch_bounds__(256) void ln_kernel(const float* __restrict__ emb,
                                                 const float* __restrict__ lw,
                                                 const float* __restrict__ lb,
                                                 float* __restrict__ out) {
  const int row = blockIdx.x;
  const int t = threadIdx.x;
  const int lane = t & 63, wave = t >> 6;
  __shared__ float red[4];
  __shared__ float bs[2];
  float e[3];
#pragma unroll
  for (int c = 0; c < 3; ++c) e[c] = emb[(size_t)row * DDIM + t + 256 * c];
  float s = e[0] + e[1] + e[2];
  s = wsum(s);
  if (lane == 0) red[wave] = s;
  __syncthreads();
  if (t == 0) bs[0] = (red[0] + red[1] + red[2] + red[3]) * (1.f / DDIM);
  __syncthreads();
  float mu = bs[0];
  float q = 0.f;
#pragma unroll
  for (int c = 0; c < 3; ++c) {
    float d = e[c] - mu;
    q = fmaf(d, d, q);
  }
  q = wsum(q);
  if (lane == 0) red[wave] = q;
  __syncthreads();
  if (t == 0) bs[1] = (red[0] + red[1] + red[2] + red[3]) * (1.f / DDIM);
  __syncthreads();
  float rstd = rsqrtf(bs[1] + 1e-5f);
#pragma unroll
  for (int c = 0; c < 3; ++c) {
    int d = t + 256 * c;
    out[(size_t)row * DDIM + d] = (e[c] - mu) * rstd * lw[d] + lb[d];
  }
}

// ---------------- launch ----------------
extern "C" void kernel_launch(void* const* d_in, const int* in_sizes, int n_in,
                              void* d_out, int out_size, void* d_ws,
                              size_t ws_size, hipStream_t stream) {
  const float* cls = (const float*)d_in[0];
  const float* feats = (const float*)d_in[1];
  const float* Whw = (const float*)d_in[2];
  const float* Whb = (const float*)d_in[3];
  const float* Wtw = (const float*)d_in[4];
  const float* Wtb = (const float*)d_in[5];
  const float* l1w = (const float*)d_in[6];
  const float* l1b = (const float*)d_in[7];
  const float* l2w = (const float*)d_in[8];
  const float* l2b = (const float*)d_in[9];
  const float* lnw = (const float*)d_in[10];
  const float* lnb = (const float*)d_in[11];
  float* out = (float*)d_out;

  float* ws = (float*)d_ws;
  // layout (float units)
  float* emb = ws;                          // 786432 (lin fused output)
  short* eh_hi = (short*)(ws + 3932160);    // 786432 shorts
  short* eh_lo = eh_hi + 786432;            // (ends 4718592f)
  short* et_hi = (short*)(ws + 4718592);    // 3145728 shorts
  short* et_lo = et_hi + 3145728;           // (ends 7864320f)
  short* WhT_h = (short*)(ws + 7864320);    // 589824 shorts each
  short* WhT_l = WhT_h + 589824;
  short* WtT_h = WhT_h + 2 * 589824;
  short* WtT_l = WhT_h + 3 * 589824;        // (ends 9043968f)
  short* L1T = (short*)(ws + 9043968);      // 589824 shorts
  short* L2T = L1T + 589824;                // (ends 9633792f)
  float* logits = ws + 7864320;             // overlays WhT/WtT (dead by then)
  short* Xh = (short*)(ws + 9633792);       // X bf16 hi/lo; dead after front
  short* Xl = Xh + 3145728;                 // (ends 12779520f)
  float* tw = ws + 9633792;                 // 131072 (overlays Xh - X dead)
  int* ti = (int*)(ws + 9764864);           // 131072
  float* kaw = ws + 9895936;                // 131072
  short* inbf = (short*)(ws + 10027008);    // 2048*768 shorts (786432 f)
  (void)ws_size;
  (void)in_sizes;
  (void)n_in;
  (void)out_size;

  const float scale = 0.036084391824351615f;  // 1/sqrt(768)
  dim3 blk(256);

  // merged prep: weights (2304 blocks) + X pack (1536 blocks)
  prep_all<<<dim3(3840), blk, 0, stream>>>(cls, feats, Whw, Wtw, l1w, l2w,
                                           WhT_h, WtT_h, L1T, L2T, WhT_l,
                                           WtT_l, Xh, Xl);
  // fused e_h | e_t (480 blocks, 128x64, XCD-chunked, swizzled LDS)
  gemm_front<<<dim3(480), blk, 0, stream>>>(
      Xh, Xl, WhT_h, WhT_l, Whb, WtT_h, WtT_l, Wtb, eh_hi, eh_lo, et_hi,
      et_lo);
  // logits[b] = scale * e_h[b] @ e_t[b]^T (512 blocks, batch->XCD)
  gemm_logits<<<dim3(512), blk, 0, stream>>>(eh_hi, eh_lo, et_hi, et_lo,
                                             logits, scale);
  // top-128 per row (radix select)
  topk_select<<<dim3(NBATCH * NCLS), blk, 0, stream>>>(logits, tw, ti);
  // agg1: gated ka weights (2048 blocks, bf16 reads)
  agg1<<<dim3(2048), blk, 0, stream>>>(eh_hi, et_hi, tw, ti, kaw);
  // agg2: softmax + weighted sum -> bf16 lin inputs
  agg2<<<dim3(1024), dim3(192), 0, stream>>>(eh_hi, et_hi, cls, kaw, ti, inbf);
  // fused lin1+lin2 -> emb (384 blocks, 32x64, XCD-chunked)
  gemm_lin<<<dim3(384), blk, 0, stream>>>(inbf, L1T, L2T, l1b, l2b, emb);
  // layernorm(emb) -> out
  ln_kernel<<<dim3(NBATCH * NCLS), blk, 0, stream>>>(emb, lnw, lnb, out);
}

// Round 12
// 117.981 us; speedup vs baseline: 1.1647x; 1.0530x over previous
//
#include <hip/hip_runtime.h>
#include <hip/hip_bf16.h>
#include <math.h>

#define DDIM 768
#define NCLS 256
#define NFEAT 768
#define NTOK 1024
#define NBATCH 4
#define KSEL 128

typedef float f32x4 __attribute__((ext_vector_type(4)));
typedef short s16x8 __attribute__((ext_vector_type(8)));

// ---------------- helpers ----------------
__device__ __forceinline__ float wsum(float v) {
#pragma unroll
  for (int o = 32; o; o >>= 1) v += __shfl_down(v, o, 64);
  return v;
}
__device__ __forceinline__ float wmaxr(float v) {
#pragma unroll
  for (int o = 32; o; o >>= 1) v = fmaxf(v, __shfl_down(v, o, 64));
  return v;
}
__device__ __forceinline__ short f2bf(float f) {
  union { __hip_bfloat16 h; short s; } u;
  u.h = __float2bfloat16(f);
  return u.s;
}
__device__ __forceinline__ float bf2f(short s) {
  union { unsigned u; float f; } c;
  c.u = ((unsigned)(unsigned short)s) << 16;
  return c.f;
}
__device__ __forceinline__ void cvt8(float4 x, float4 y, s16x8& h, s16x8& l) {
  float v[8] = {x.x, x.y, x.z, x.w, y.x, y.y, y.z, y.w};
#pragma unroll
  for (int i = 0; i < 8; ++i) {
    short hh = f2bf(v[i]);
    h[i] = hh;
    l[i] = f2bf(v[i] - bf2f(hh));
  }
}
// LDS address swizzle: 32-short (64B) rows, 8-short (16B) chunks.
__device__ __forceinline__ int swz(int row, int chunk) {
  return (row << 5) + (((chunk ^ (row >> 1)) & 3) << 3);
}

// -------- merged prep: blocks 0..2303 = weight transpose+cvt,
//          blocks 2304..3839 = X pack (concat(cls,feats) -> hi/lo) -------
__global__ __launch_bounds__(256) void prep_all(
    const float* __restrict__ cls, const float* __restrict__ feats,
    const float* __restrict__ w0, const float* __restrict__ w1,
    const float* __restrict__ w2, const float* __restrict__ w3,
    short* __restrict__ h0, short* __restrict__ h1, short* __restrict__ h2,
    short* __restrict__ h3, short* __restrict__ l0, short* __restrict__ l1,
    short* __restrict__ Xh, short* __restrict__ Xl) {
  __shared__ float tile[32][33];
  const int bid = blockIdx.x;
  const int t = threadIdx.x;
  if (bid < 2304) {
    const int z = bid / 576, rem = bid % 576;
    const int by = rem / 24, bx = rem % 24;
    const float* s = z == 0 ? w0 : z == 1 ? w1 : z == 2 ? w2 : w3;
    short* dh = z == 0 ? h0 : z == 1 ? h1 : z == 2 ? h2 : h3;
    short* dl = z == 0 ? l0 : z == 1 ? l1 : nullptr;
    const int tx = t & 31, ty0 = t >> 5;
    const int r0 = by * 32, c0 = bx * 32;
#pragma unroll
    for (int i = 0; i < 4; ++i) {
      int ty = ty0 + i * 8;
      tile[ty][tx] = s[(size_t)(r0 + ty) * DDIM + c0 + tx];
    }
    __syncthreads();
#pragma unroll
    for (int i = 0; i < 4; ++i) {
      int ty = ty0 + i * 8;
      float v = tile[tx][ty];
      short hh = f2bf(v);
      dh[(size_t)(c0 + ty) * DDIM + r0 + tx] = hh;
      if (dl) dl[(size_t)(c0 + ty) * DDIM + r0 + tx] = f2bf(v - bf2f(hh));
    }
  } else {
    const size_t base = ((size_t)(bid - 2304) * 256 + t) * 8;
    const int row = (int)(base / DDIM);
    const int col = (int)(base % DDIM);
    const int b = row >> 10, rr = row & 1023;
    const float* src =
        (rr < NCLS) ? cls + ((size_t)b * NCLS + rr) * DDIM + col
                    : feats + ((size_t)b * NFEAT + (rr - NCLS)) * DDIM + col;
    float4 a0 = *(const float4*)(src);
    float4 a1 = *(const float4*)(src + 4);
    s16x8 h, l;
    cvt8(a0, a1, h, l);
    *(s16x8*)(Xh + base) = h;
    *(s16x8*)(Xl + base) = l;
  }
}

// -------- front GEMM (fused e_h | e_t), 128x64 tiles, split-bf16,
//          bf16 hi/lo outputs only, swizzled LDS, XCD-chunked (480) -----
__global__ __launch_bounds__(256) void gemm_front(
    const short* __restrict__ Xh, const short* __restrict__ Xl,
    const short* __restrict__ WhT_h, const short* __restrict__ WhT_l,
    const float* __restrict__ Whb, const short* __restrict__ WtT_h,
    const short* __restrict__ WtT_l, const float* __restrict__ Wtb,
    short* __restrict__ eh_hi, short* __restrict__ eh_lo,
    short* __restrict__ et_hi, short* __restrict__ et_lo) {
  __shared__ short Ah[128 * 32], Al[128 * 32];
  __shared__ short Bh[64 * 32], Bl[64 * 32];
  const int bid = blockIdx.x;
  const int xcd = bid & 7, idx = bid >> 3;  // idx 0..59
  const int ytile = xcd * 5 + idx / 12;     // 0..39
  const int xtile = idx % 12;
  const int t = threadIdx.x;
  const int row0 = ytile * 128, col0 = xtile * 64;
  const bool head = row0 < 1024;

  const int ar = t >> 1, ac = (t & 1) * 2;
  const int aw0 = swz(ar, ac), aw1 = swz(ar, ac + 1);
  size_t xrow;
  {
    int gr = row0 + ar;
    xrow = head ? (size_t)(((gr >> 8) << 10) + (gr & 255)) : (size_t)(gr - 1024);
  }
  const short* aph = Xh + xrow * DDIM + ac * 8;
  const short* apl = Xl + xrow * DDIM + ac * 8;
  const int br = t >> 2, bc = t & 3;
  const int bw0 = swz(br, bc);
  const short* bph = (head ? WhT_h : WtT_h) + (size_t)(col0 + br) * DDIM + bc * 8;
  const short* bpl = (head ? WhT_l : WtT_l) + (size_t)(col0 + br) * DDIM + bc * 8;
  const float* biasu = head ? Whb : Wtb;

  const int lane = t & 63, wave = t >> 6;
  const int wr = wave >> 1, wc = wave & 1;
  const int fr = lane & 15, fq = lane >> 4;

  f32x4 acc[4][2] = {};
  s16x8 rah0 = *(const s16x8*)(aph);
  s16x8 rah1 = *(const s16x8*)(aph + 8);
  s16x8 ral0 = *(const s16x8*)(apl);
  s16x8 ral1 = *(const s16x8*)(apl + 8);
  s16x8 rbh = *(const s16x8*)(bph);
  s16x8 rbl = *(const s16x8*)(bpl);

  for (int kt = 0; kt < 24; ++kt) {
    __syncthreads();
    *(s16x8*)&Ah[aw0] = rah0;
    *(s16x8*)&Ah[aw1] = rah1;
    *(s16x8*)&Al[aw0] = ral0;
    *(s16x8*)&Al[aw1] = ral1;
    *(s16x8*)&Bh[bw0] = rbh;
    *(s16x8*)&Bl[bw0] = rbl;
    __syncthreads();
    const int kn = (kt < 23 ? kt + 1 : 23) * 32;
    rah0 = *(const s16x8*)(aph + kn);
    rah1 = *(const s16x8*)(aph + kn + 8);
    ral0 = *(const s16x8*)(apl + kn);
    ral1 = *(const s16x8*)(apl + kn + 8);
    rbh = *(const s16x8*)(bph + kn);
    rbl = *(const s16x8*)(bpl + kn);

    s16x8 afh[4], afl[4];
#pragma unroll
    for (int m = 0; m < 4; ++m) {
      int ao = swz(wr * 64 + m * 16 + fr, fq);
      afh[m] = *(const s16x8*)&Ah[ao];
      afl[m] = *(const s16x8*)&Al[ao];
    }
#pragma unroll
    for (int n = 0; n < 2; ++n) {
      int bo = swz(wc * 32 + n * 16 + fr, fq);
      s16x8 bfh = *(const s16x8*)&Bh[bo];
      s16x8 bfl = *(const s16x8*)&Bl[bo];
#pragma unroll
      for (int m = 0; m < 4; ++m) {
        acc[m][n] =
            __builtin_amdgcn_mfma_f32_16x16x32_bf16(afh[m], bfh, acc[m][n], 0, 0, 0);
        acc[m][n] =
            __builtin_amdgcn_mfma_f32_16x16x32_bf16(afh[m], bfl, acc[m][n], 0, 0, 0);
        acc[m][n] =
            __builtin_amdgcn_mfma_f32_16x16x32_bf16(afl[m], bfh, acc[m][n], 0, 0, 0);
      }
    }
  }

  short* Ch = head ? eh_hi : et_hi;
  short* Cl = head ? eh_lo : et_lo;
  const int rbase = head ? row0 : row0 - 1024;
#pragma unroll
  for (int m = 0; m < 4; ++m) {
#pragma unroll
    for (int n = 0; n < 2; ++n) {
#pragma unroll
      for (int r = 0; r < 4; ++r) {
        int rg = rbase + wr * 64 + m * 16 + fq * 4 + r;
        int cg = col0 + wc * 32 + n * 16 + fr;
        float v = acc[m][n][r] + biasu[cg];
        size_t o = (size_t)rg * DDIM + cg;
        short hh = f2bf(v);
        Ch[o] = hh;
        Cl[o] = f2bf(v - bf2f(hh));
      }
    }
  }
}

// -------- logits GEMM: 32x64 tiles, swizzled LDS, 512 blocks,
//          batch->XCD affinity, single-buffer + overlap --------
__global__ __launch_bounds__(256) void gemm_logits(
    const short* __restrict__ eh_hi, const short* __restrict__ eh_lo,
    const short* __restrict__ et_hi, const short* __restrict__ et_lo,
    float* __restrict__ logits, float scale) {
  __shared__ short Ah[32 * 32], Al[32 * 32];
  __shared__ short Bh[64 * 32], Bl[64 * 32];
  const int bid = blockIdx.x;
  const int xcd = bid & 7, idx = bid >> 3;
  const int batch = xcd >> 1;
  const int sub = ((xcd & 1) << 6) | idx;
  const int xtile = sub & 15, ytile = sub >> 4;
  const int row0 = ytile * 32, col0 = xtile * 64;
  const int t = threadIdx.x;

  const int ahalf = t >> 7, ac2 = t & 127;
  const int asr = ac2 >> 2, acc_ = ac2 & 3;
  const short* aptr = (ahalf ? eh_lo : eh_hi) +
                      ((size_t)batch * NCLS + row0 + asr) * DDIM + acc_ * 8;
  const int aso = swz(asr, acc_);
  const int bsr = t >> 2, bcc = t & 3;
  const short* bph = et_hi + ((size_t)batch * NTOK + col0 + bsr) * DDIM + bcc * 8;
  const short* bpl = et_lo + ((size_t)batch * NTOK + col0 + bsr) * DDIM + bcc * 8;
  const int bso = swz(bsr, bcc);

  const int lane = t & 63, wave = t >> 6;
  const int wr = wave >> 1, wc = wave & 1;
  const int fr = lane & 15, fq = lane >> 4;

  f32x4 acc[2] = {};
  s16x8 rA = *(const s16x8*)(aptr);
  s16x8 rbh = *(const s16x8*)(bph);
  s16x8 rbl = *(const s16x8*)(bpl);

  for (int kt = 0; kt < 24; ++kt) {
    __syncthreads();
    *(s16x8*)&(ahalf ? Al : Ah)[aso] = rA;
    *(s16x8*)&Bh[bso] = rbh;
    *(s16x8*)&Bl[bso] = rbl;
    __syncthreads();
    const int kn = (kt < 23 ? kt + 1 : 23) * 32;
    rA = *(const s16x8*)(aptr + kn);
    rbh = *(const s16x8*)(bph + kn);
    rbl = *(const s16x8*)(bpl + kn);
    int ao = swz(wr * 16 + fr, fq);
    s16x8 afh = *(const s16x8*)&Ah[ao];
    s16x8 afl = *(const s16x8*)&Al[ao];
#pragma unroll
    for (int n = 0; n < 2; ++n) {
      int bo = swz(wc * 32 + n * 16 + fr, fq);
      s16x8 bfh = *(const s16x8*)&Bh[bo];
      s16x8 bfl = *(const s16x8*)&Bl[bo];
      acc[n] = __builtin_amdgcn_mfma_f32_16x16x32_bf16(afh, bfh, acc[n], 0, 0, 0);
      acc[n] = __builtin_amdgcn_mfma_f32_16x16x32_bf16(afh, bfl, acc[n], 0, 0, 0);
      acc[n] = __builtin_amdgcn_mfma_f32_16x16x32_bf16(afl, bfh, acc[n], 0, 0, 0);
    }
  }

  float* Cb = logits + (size_t)batch * NCLS * NTOK;
#pragma unroll
  for (int n = 0; n < 2; ++n)
#pragma unroll
    for (int r = 0; r < 4; ++r) {
      int rg = row0 + wr * 16 + fq * 4 + r;
      int cg = col0 + wc * 32 + n * 16 + fr;
      Cb[(size_t)rg * NTOK + cg] = scale * acc[n][r];
    }
}

// -------- fused select+agg: radix top-128, p-softmax, gated ka dots,
//          ka-softmax, weighted sum -> bf16 lin inputs. 1 block/row ------
__global__ __launch_bounds__(256) void select_agg(
    const float* __restrict__ logits, const short* __restrict__ eh_hi,
    const short* __restrict__ et_hi, const float* __restrict__ cls,
    short* __restrict__ inbf) {
  const int bid = blockIdx.x;
  const int xcd = bid & 7, slot = bid >> 3;
  const int batch = xcd >> 1;
  const int row = batch * 256 + (xcd & 1) * 128 + slot;
  const int t = threadIdx.x, lane = t & 63, wave = t >> 6;

  __shared__ int hist[256];
  __shared__ int sh_bin, sh_rem;
  __shared__ int cnt;
  __shared__ int wsumT[4];
  __shared__ float p_sh[KSEL];
  __shared__ int idx_sh[KSEL];
  __shared__ float kaw_sh[KSEL];
  __shared__ float red[2];

  // ---- phase A: radix select top-128 of this row's 1024 logits ----
  float4 v4 = *(const float4*)(logits + (size_t)row * NTOK + 4 * t);
  float val[4] = {v4.x, v4.y, v4.z, v4.w};
  unsigned key[4];
#pragma unroll
  for (int i = 0; i < 4; ++i) {
    unsigned u = __float_as_uint(val[i]);
    key[i] = (u & 0x80000000u) ? ~u : (u | 0x80000000u);
  }
  unsigned pref = 0, mask = 0;
  int rem = KSEL;
#pragma unroll
  for (int shift = 24; shift >= 0; shift -= 8) {
    hist[t] = 0;
    __syncthreads();
#pragma unroll
    for (int i = 0; i < 4; ++i)
      if ((key[i] & mask) == pref)
        atomicAdd(&hist[(key[i] >> shift) & 255], 1);
    __syncthreads();
    if (wave == 0) {
      int h0 = hist[4 * lane], h1 = hist[4 * lane + 1];
      int h2 = hist[4 * lane + 2], h3 = hist[4 * lane + 3];
      int s = h0 + h1 + h2 + h3;
#pragma unroll
      for (int o = 1; o < 64; o <<= 1) {
        int v = __shfl_down(s, o, 64);
        if (lane + o < 64) s += v;
      }
      int abv = __shfl_down(s, 1, 64);
      if (lane == 63) abv = 0;
      int c3 = abv + h3, c2 = c3 + h2, c1 = c2 + h1, c0 = c1 + h0;
      int bin = -1, nab = 0;
      if (c3 >= rem && abv < rem) { bin = 4 * lane + 3; nab = abv; }
      else if (c2 >= rem && c3 < rem) { bin = 4 * lane + 2; nab = c3; }
      else if (c1 >= rem && c2 < rem) { bin = 4 * lane + 1; nab = c2; }
      else if (c0 >= rem && c1 < rem) { bin = 4 * lane + 0; nab = c1; }
      if (bin >= 0) { sh_bin = bin; sh_rem = rem - nab; }
    }
    __syncthreads();
    pref |= ((unsigned)sh_bin) << shift;
    mask |= 0xFFu << shift;
    rem = sh_rem;
  }
  const unsigned T = pref;
  const int above = KSEL - rem;

  if (t == 0) cnt = 0;
  int tc = 0;
#pragma unroll
  for (int i = 0; i < 4; ++i) tc += (key[i] == T);
  int inc = tc;
#pragma unroll
  for (int o = 1; o < 64; o <<= 1) {
    int v = __shfl_up(inc, o, 64);
    if (lane >= o) inc += v;
  }
  if (lane == 63) wsumT[wave] = inc;
  __syncthreads();
  int wbase = 0;
#pragma unroll
  for (int w = 0; w < 4; ++w)
    if (w < wave) wbase += wsumT[w];
  int excl = wbase + inc - tc;
#pragma unroll
  for (int i = 0; i < 4; ++i) {
    if (key[i] > T) {
      int s2 = atomicAdd(&cnt, 1);
      p_sh[s2] = val[i];
      idx_sh[s2] = 4 * t + i;
    } else if (key[i] == T) {
      int r = excl++;
      if (r < rem) {
        p_sh[above + r] = val[i];
        idx_sh[above + r] = 4 * t + i;
      }
    }
  }
  __syncthreads();

  // ---- phase B: softmax over p_sh ----
  if (wave == 0) {
    float m = wmaxr(fmaxf(p_sh[lane], p_sh[lane + 64]));
    if (!lane) red[0] = m;
  }
  __syncthreads();
  if (t < KSEL) p_sh[t] = __expf(p_sh[t] - red[0]);
  __syncthreads();
  if (wave == 0) {
    float s = wsum(p_sh[lane] + p_sh[lane + 64]);
    if (!lane) red[1] = s;
  }
  __syncthreads();
  if (t < KSEL) p_sh[t] *= (1.f / red[1]);
  __syncthreads();

  // ---- phase C: gated ka dots (32 j per wave) ----
  float ehr[12];
  {
    const short* ehrow = eh_hi + (size_t)row * DDIM;
    s16x8 e8 = *(const s16x8*)(ehrow + 8 * lane);
    short4 e4 = *(const short4*)(ehrow + 512 + 4 * lane);
#pragma unroll
    for (int i = 0; i < 8; ++i) ehr[i] = bf2f(e8[i]);
    ehr[8] = bf2f(e4.x);
    ehr[9] = bf2f(e4.y);
    ehr[10] = bf2f(e4.z);
    ehr[11] = bf2f(e4.w);
  }
  const short* etb = et_hi + (size_t)batch * NTOK * DDIM;

  for (int i = 0; i < 32; ++i) {
    int j = wave * 32 + i;
    float pj = p_sh[j];
    float a = 4.f - 2.f * pj, b2 = 2.f * pj;
    const short* nb = etb + (size_t)idx_sh[j] * DDIM;
    s16x8 n8 = *(const s16x8*)(nb + 8 * lane);
    short4 n4 = *(const short4*)(nb + 512 + 4 * lane);
    float nq[12];
#pragma unroll
    for (int q = 0; q < 8; ++q) nq[q] = bf2f(n8[q]);
    nq[8] = bf2f(n4.x);
    nq[9] = bf2f(n4.y);
    nq[10] = bf2f(n4.z);
    nq[11] = bf2f(n4.w);
    float partial = 0.f;
#pragma unroll
    for (int q = 0; q < 12; ++q) {
      float y2 = fmaf(a, ehr[q], b2 * nq[q]);
      float ex = __expf(y2);
      float g = fmaf(-2.f, __builtin_amdgcn_rcpf(1.f + ex), 1.f);
      partial = fmaf(nq[q], g, partial);
    }
    partial = wsum(partial);
    if (!lane) kaw_sh[j] = partial;
  }
  __syncthreads();

  // ---- phase D: softmax over kaw_sh ----
  if (wave == 0) {
    float m = wmaxr(fmaxf(kaw_sh[lane], kaw_sh[lane + 64]));
    if (!lane) red[0] = m;
  }
  __syncthreads();
  if (t < KSEL) kaw_sh[t] = __expf(kaw_sh[t] - red[0]);
  __syncthreads();
  if (wave == 0) {
    float s = wsum(kaw_sh[lane] + kaw_sh[lane + 64]);
    if (!lane) red[1] = s;
  }
  __syncthreads();
  if (t < KSEL) kaw_sh[t] *= (1.f / red[1]);
  __syncthreads();

  // ---- phase E: weighted sum + emit bf16 lin inputs (t < 192) ----
  if (t < 192) {
    const size_t o = (size_t)row * DDIM + 4 * t;
    short4 ehs = *(const short4*)(eh_hi + o);
    float4 eh4 = {bf2f(ehs.x), bf2f(ehs.y), bf2f(ehs.z), bf2f(ehs.w)};
    float4 cl4 = *(const float4*)(cls + o);
    float ax = 0.f, ay = 0.f, az = 0.f, aw = 0.f;
#pragma unroll 8
    for (int j = 0; j < KSEL; ++j) {
      float pr = kaw_sh[j];
      short4 nb = *(const short4*)(etb + (size_t)idx_sh[j] * DDIM + 4 * t);
      ax = fmaf(pr, bf2f(nb.x), ax);
      ay = fmaf(pr, bf2f(nb.y), ay);
      az = fmaf(pr, bf2f(nb.z), az);
      aw = fmaf(pr, bf2f(nb.w), aw);
    }
    short4 sv, bv;
    sv.x = f2bf((eh4.x + ax) * 0.1f + cl4.x);
    sv.y = f2bf((eh4.y + ay) * 0.1f + cl4.y);
    sv.z = f2bf((eh4.z + az) * 0.1f + cl4.z);
    sv.w = f2bf((eh4.w + aw) * 0.1f + cl4.w);
    bv.x = f2bf((eh4.x * ax) * 0.1f + cl4.x);
    bv.y = f2bf((eh4.y * ay) * 0.1f + cl4.y);
    bv.z = f2bf((eh4.z * az) * 0.1f + cl4.z);
    bv.w = f2bf((eh4.w * aw) * 0.1f + cl4.w);
    *(short4*)&inbf[o] = sv;
    *(short4*)&inbf[(size_t)(NBATCH * NCLS) * DDIM + o] = bv;
  }
}

// -------- lin GEMM fused: both lin1 & lin2 per tile -> emb directly,
//          32x64 tiles, swizzled LDS, XCD-chunked (384 = 8 x 48) --------
__global__ __launch_bounds__(256) void gemm_lin(
    const short* __restrict__ inbf, const short* __restrict__ L1T,
    const short* __restrict__ L2T, const float* __restrict__ b1,
    const float* __restrict__ b2, float* __restrict__ emb) {
  __shared__ short A1[32 * 32], A2[32 * 32];
  __shared__ short B1[64 * 32], B2[64 * 32];
  const int bid = blockIdx.x;
  const int xcd = bid & 7, idx = bid >> 3;  // 0..47
  const int ytile = xcd * 4 + idx / 12, xtile = idx % 12;  // 32 x 12
  const int t = threadIdx.x;
  const int row0 = ytile * 32, col0 = xtile * 64;

  const int ahalf = t >> 7, at = t & 127;
  const int asr = at >> 2, asc = at & 3;
  const short* aptr = inbf + (ahalf ? (size_t)1024 * DDIM : 0) +
                      (size_t)(row0 + asr) * DDIM + asc * 8;
  const int aso = swz(asr, asc);
  const int bsr = t >> 2, bsc = t & 3;
  const short* b1p = L1T + (size_t)(col0 + bsr) * DDIM + bsc * 8;
  const short* b2p = L2T + (size_t)(col0 + bsr) * DDIM + bsc * 8;
  const int bso = swz(bsr, bsc);

  const int lane = t & 63, wave = t >> 6;
  const int wr = wave >> 1, wc = wave & 1;
  const int fr = lane & 15, fq = lane >> 4;

  f32x4 acc1[2] = {}, acc2[2] = {};
  s16x8 rA = *(const s16x8*)(aptr);
  s16x8 rB1 = *(const s16x8*)(b1p);
  s16x8 rB2 = *(const s16x8*)(b2p);
  for (int kt = 0; kt < 24; ++kt) {
    __syncthreads();
    *(s16x8*)&(ahalf ? A2 : A1)[aso] = rA;
    *(s16x8*)&B1[bso] = rB1;
    *(s16x8*)&B2[bso] = rB2;
    __syncthreads();
    const int kn = (kt < 23 ? kt + 1 : 23) * 32;
    rA = *(const s16x8*)(aptr + kn);
    rB1 = *(const s16x8*)(b1p + kn);
    rB2 = *(const s16x8*)(b2p + kn);
    int ao = swz(wr * 16 + fr, fq);
    s16x8 a1f = *(const s16x8*)&A1[ao];
    s16x8 a2f = *(const s16x8*)&A2[ao];
#pragma unroll
    for (int n = 0; n < 2; ++n) {
      int bo = swz(wc * 32 + n * 16 + fr, fq);
      s16x8 b1f = *(const s16x8*)&B1[bo];
      s16x8 b2f = *(const s16x8*)&B2[bo];
      acc1[n] = __builtin_amdgcn_mfma_f32_16x16x32_bf16(a1f, b1f, acc1[n], 0, 0, 0);
      acc2[n] = __builtin_amdgcn_mfma_f32_16x16x32_bf16(a2f, b2f, acc2[n], 0, 0, 0);
    }
  }
#pragma unroll
  for (int n = 0; n < 2; ++n)
#pragma unroll
    for (int r = 0; r < 4; ++r) {
      int rg = row0 + wr * 16 + fq * 4 + r;
      int cg = col0 + wc * 32 + n * 16 + fr;
      float v1 = acc1[n][r] + b1[cg];
      v1 = v1 > 0.f ? v1 : 0.01f * v1;
      float v2 = acc2[n][r] + b2[cg];
      v2 = v2 > 0.f ? v2 : 0.01f * v2;
      emb[(size_t)rg * DDIM + cg] = v1 + v2;
    }
}

// -------- layernorm over D=768 --------
__global__ __launch_bounds__(256) void ln_kernel(const float* __restrict__ emb,
                                                 const float* __restrict__ lw,
                                                 const float* __restrict__ lb,
                                                 float* __restrict__ out) {
  const int row = blockIdx.x;
  const int t = threadIdx.x;
  const int lane = t & 63, wave = t >> 6;
  __shared__ float red[4];
  __shared__ float bs[2];
  float e[3];
#pragma unroll
  for (int c = 0; c < 3; ++c) e[c] = emb[(size_t)row * DDIM + t + 256 * c];
  float s = e[0] + e[1] + e[2];
  s = wsum(s);
  if (lane == 0) red[wave] = s;
  __syncthreads();
  if (t == 0) bs[0] = (red[0] + red[1] + red[2] + red[3]) * (1.f / DDIM);
  __syncthreads();
  float mu = bs[0];
  float q = 0.f;
#pragma unroll
  for (int c = 0; c < 3; ++c) {
    float d = e[c] - mu;
    q = fmaf(d, d, q);
  }
  q = wsum(q);
  if (lane == 0) red[wave] = q;
  __syncthreads();
  if (t == 0) bs[1] = (red[0] + red[1] + red[2] + red[3]) * (1.f / DDIM);
  __syncthreads();
  float rstd = rsqrtf(bs[1] + 1e-5f);
#pragma unroll
  for (int c = 0; c < 3; ++c) {
    int d = t + 256 * c;
    out[(size_t)row * DDIM + d] = (e[c] - mu) * rstd * lw[d] + lb[d];
  }
}

// ---------------- launch ----------------
extern "C" void kernel_launch(void* const* d_in, const int* in_sizes, int n_in,
                              void* d_out, int out_size, void* d_ws,
                              size_t ws_size, hipStream_t stream) {
  const float* cls = (const float*)d_in[0];
  const float* feats = (const float*)d_in[1];
  const float* Whw = (const float*)d_in[2];
  const float* Whb = (const float*)d_in[3];
  const float* Wtw = (const float*)d_in[4];
  const float* Wtb = (const float*)d_in[5];
  const float* l1w = (const float*)d_in[6];
  const float* l1b = (const float*)d_in[7];
  const float* l2w = (const float*)d_in[8];
  const float* l2b = (const float*)d_in[9];
  const float* lnw = (const float*)d_in[10];
  const float* lnb = (const float*)d_in[11];
  float* out = (float*)d_out;

  float* ws = (float*)d_ws;
  // layout (float units)
  float* emb = ws;                          // 786432 (lin fused output)
  short* eh_hi = (short*)(ws + 3932160);    // 786432 shorts
  short* eh_lo = eh_hi + 786432;            // (ends 4718592f)
  short* et_hi = (short*)(ws + 4718592);    // 3145728 shorts
  short* et_lo = et_hi + 3145728;           // (ends 7864320f)
  short* WhT_h = (short*)(ws + 7864320);    // 589824 shorts each
  short* WhT_l = WhT_h + 589824;
  short* WtT_h = WhT_h + 2 * 589824;
  short* WtT_l = WhT_h + 3 * 589824;        // (ends 9043968f)
  short* L1T = (short*)(ws + 9043968);      // 589824 shorts
  short* L2T = L1T + 589824;                // (ends 9633792f)
  float* logits = ws + 7864320;             // overlays WhT/WtT (dead by then)
  short* Xh = (short*)(ws + 9633792);       // X bf16 hi/lo; dead after front
  short* Xl = Xh + 3145728;                 // (ends 12779520f)
  short* inbf = (short*)(ws + 10027008);    // 2048*768 shorts (786432 f)
  (void)ws_size;
  (void)in_sizes;
  (void)n_in;
  (void)out_size;

  const float scale = 0.036084391824351615f;  // 1/sqrt(768)
  dim3 blk(256);

  // merged prep: weights (2304 blocks) + X pack (1536 blocks)
  prep_all<<<dim3(3840), blk, 0, stream>>>(cls, feats, Whw, Wtw, l1w, l2w,
                                           WhT_h, WtT_h, L1T, L2T, WhT_l,
                                           WtT_l, Xh, Xl);
  // fused e_h | e_t (480 blocks, 128x64, XCD-chunked, swizzled LDS)
  gemm_front<<<dim3(480), blk, 0, stream>>>(
      Xh, Xl, WhT_h, WhT_l, Whb, WtT_h, WtT_l, Wtb, eh_hi, eh_lo, et_hi,
      et_lo);
  // logits[b] = scale * e_h[b] @ e_t[b]^T (512 blocks, batch->XCD)
  gemm_logits<<<dim3(512), blk, 0, stream>>>(eh_hi, eh_lo, et_hi, et_lo,
                                             logits, scale);
  // fused top-128 select + both softmaxes + gated agg (1024 blocks)
  select_agg<<<dim3(1024), blk, 0, stream>>>(logits, eh_hi, et_hi, cls, inbf);
  // fused lin1+lin2 -> emb (384 blocks, 32x64, XCD-chunked)
  gemm_lin<<<dim3(384), blk, 0, stream>>>(inbf, L1T, L2T, l1b, l2b, emb);
  // layernorm(emb) -> out
  ln_kernel<<<dim3(NBATCH * NCLS), blk, 0, stream>>>(emb, lnw, lnb, out);
}

// Round 13
// 117.321 us; speedup vs baseline: 1.1713x; 1.0056x over previous
//
#include <hip/hip_runtime.h>
#include <hip/hip_bf16.h>
#include <math.h>

#define DDIM 768
#define NCLS 256
#define NFEAT 768
#define NTOK 1024
#define NBATCH 4
#define KSEL 128

typedef float f32x4 __attribute__((ext_vector_type(4)));
typedef short s16x8 __attribute__((ext_vector_type(8)));

// ---------------- helpers ----------------
__device__ __forceinline__ float wsum(float v) {
#pragma unroll
  for (int o = 32; o; o >>= 1) v += __shfl_down(v, o, 64);
  return v;
}
__device__ __forceinline__ float wmaxr(float v) {
#pragma unroll
  for (int o = 32; o; o >>= 1) v = fmaxf(v, __shfl_down(v, o, 64));
  return v;
}
__device__ __forceinline__ short f2bf(float f) {
  union { __hip_bfloat16 h; short s; } u;
  u.h = __float2bfloat16(f);
  return u.s;
}
__device__ __forceinline__ float bf2f(short s) {
  union { unsigned u; float f; } c;
  c.u = ((unsigned)(unsigned short)s) << 16;
  return c.f;
}
__device__ __forceinline__ void cvt8(float4 x, float4 y, s16x8& h, s16x8& l) {
  float v[8] = {x.x, x.y, x.z, x.w, y.x, y.y, y.z, y.w};
#pragma unroll
  for (int i = 0; i < 8; ++i) {
    short hh = f2bf(v[i]);
    h[i] = hh;
    l[i] = f2bf(v[i] - bf2f(hh));
  }
}
// LDS address swizzle: 32-short (64B) rows, 8-short (16B) chunks.
__device__ __forceinline__ int swz(int row, int chunk) {
  return (row << 5) + (((chunk ^ (row >> 1)) & 3) << 3);
}

// -------- merged prep: blocks 0..2303 = weight transpose+cvt,
//          blocks 2304..3839 = X pack (concat(cls,feats) -> hi/lo) -------
__global__ __launch_bounds__(256) void prep_all(
    const float* __restrict__ cls, const float* __restrict__ feats,
    const float* __restrict__ w0, const float* __restrict__ w1,
    const float* __restrict__ w2, const float* __restrict__ w3,
    short* __restrict__ h0, short* __restrict__ h1, short* __restrict__ h2,
    short* __restrict__ h3, short* __restrict__ l0, short* __restrict__ l1,
    short* __restrict__ Xh, short* __restrict__ Xl) {
  __shared__ float tile[32][33];
  const int bid = blockIdx.x;
  const int t = threadIdx.x;
  if (bid < 2304) {
    const int z = bid / 576, rem = bid % 576;
    const int by = rem / 24, bx = rem % 24;
    const float* s = z == 0 ? w0 : z == 1 ? w1 : z == 2 ? w2 : w3;
    short* dh = z == 0 ? h0 : z == 1 ? h1 : z == 2 ? h2 : h3;
    short* dl = z == 0 ? l0 : z == 1 ? l1 : nullptr;
    const int tx = t & 31, ty0 = t >> 5;
    const int r0 = by * 32, c0 = bx * 32;
#pragma unroll
    for (int i = 0; i < 4; ++i) {
      int ty = ty0 + i * 8;
      tile[ty][tx] = s[(size_t)(r0 + ty) * DDIM + c0 + tx];
    }
    __syncthreads();
#pragma unroll
    for (int i = 0; i < 4; ++i) {
      int ty = ty0 + i * 8;
      float v = tile[tx][ty];
      short hh = f2bf(v);
      dh[(size_t)(c0 + ty) * DDIM + r0 + tx] = hh;
      if (dl) dl[(size_t)(c0 + ty) * DDIM + r0 + tx] = f2bf(v - bf2f(hh));
    }
  } else {
    const size_t base = ((size_t)(bid - 2304) * 256 + t) * 8;
    const int row = (int)(base / DDIM);
    const int col = (int)(base % DDIM);
    const int b = row >> 10, rr = row & 1023;
    const float* src =
        (rr < NCLS) ? cls + ((size_t)b * NCLS + rr) * DDIM + col
                    : feats + ((size_t)b * NFEAT + (rr - NCLS)) * DDIM + col;
    float4 a0 = *(const float4*)(src);
    float4 a1 = *(const float4*)(src + 4);
    s16x8 h, l;
    cvt8(a0, a1, h, l);
    *(s16x8*)(Xh + base) = h;
    *(s16x8*)(Xl + base) = l;
  }
}

// -------- front GEMM (fused e_h | e_t), 128x64 tiles, split-bf16,
//          bf16 hi/lo outputs only, swizzled LDS, XCD-chunked (480) -----
__global__ __launch_bounds__(256) void gemm_front(
    const short* __restrict__ Xh, const short* __restrict__ Xl,
    const short* __restrict__ WhT_h, const short* __restrict__ WhT_l,
    const float* __restrict__ Whb, const short* __restrict__ WtT_h,
    const short* __restrict__ WtT_l, const float* __restrict__ Wtb,
    short* __restrict__ eh_hi, short* __restrict__ eh_lo,
    short* __restrict__ et_hi, short* __restrict__ et_lo) {
  __shared__ short Ah[128 * 32], Al[128 * 32];
  __shared__ short Bh[64 * 32], Bl[64 * 32];
  const int bid = blockIdx.x;
  const int xcd = bid & 7, idx = bid >> 3;  // idx 0..59
  const int ytile = xcd * 5 + idx / 12;     // 0..39
  const int xtile = idx % 12;
  const int t = threadIdx.x;
  const int row0 = ytile * 128, col0 = xtile * 64;
  const bool head = row0 < 1024;

  const int ar = t >> 1, ac = (t & 1) * 2;
  const int aw0 = swz(ar, ac), aw1 = swz(ar, ac + 1);
  size_t xrow;
  {
    int gr = row0 + ar;
    xrow = head ? (size_t)(((gr >> 8) << 10) + (gr & 255)) : (size_t)(gr - 1024);
  }
  const short* aph = Xh + xrow * DDIM + ac * 8;
  const short* apl = Xl + xrow * DDIM + ac * 8;
  const int br = t >> 2, bc = t & 3;
  const int bw0 = swz(br, bc);
  const short* bph = (head ? WhT_h : WtT_h) + (size_t)(col0 + br) * DDIM + bc * 8;
  const short* bpl = (head ? WhT_l : WtT_l) + (size_t)(col0 + br) * DDIM + bc * 8;
  const float* biasu = head ? Whb : Wtb;

  const int lane = t & 63, wave = t >> 6;
  const int wr = wave >> 1, wc = wave & 1;
  const int fr = lane & 15, fq = lane >> 4;

  f32x4 acc[4][2] = {};
  s16x8 rah0 = *(const s16x8*)(aph);
  s16x8 rah1 = *(const s16x8*)(aph + 8);
  s16x8 ral0 = *(const s16x8*)(apl);
  s16x8 ral1 = *(const s16x8*)(apl + 8);
  s16x8 rbh = *(const s16x8*)(bph);
  s16x8 rbl = *(const s16x8*)(bpl);

  for (int kt = 0; kt < 24; ++kt) {
    __syncthreads();
    *(s16x8*)&Ah[aw0] = rah0;
    *(s16x8*)&Ah[aw1] = rah1;
    *(s16x8*)&Al[aw0] = ral0;
    *(s16x8*)&Al[aw1] = ral1;
    *(s16x8*)&Bh[bw0] = rbh;
    *(s16x8*)&Bl[bw0] = rbl;
    __syncthreads();
    const int kn = (kt < 23 ? kt + 1 : 23) * 32;
    rah0 = *(const s16x8*)(aph + kn);
    rah1 = *(const s16x8*)(aph + kn + 8);
    ral0 = *(const s16x8*)(apl + kn);
    ral1 = *(const s16x8*)(apl + kn + 8);
    rbh = *(const s16x8*)(bph + kn);
    rbl = *(const s16x8*)(bpl + kn);

    s16x8 afh[4], afl[4];
#pragma unroll
    for (int m = 0; m < 4; ++m) {
      int ao = swz(wr * 64 + m * 16 + fr, fq);
      afh[m] = *(const s16x8*)&Ah[ao];
      afl[m] = *(const s16x8*)&Al[ao];
    }
#pragma unroll
    for (int n = 0; n < 2; ++n) {
      int bo = swz(wc * 32 + n * 16 + fr, fq);
      s16x8 bfh = *(const s16x8*)&Bh[bo];
      s16x8 bfl = *(const s16x8*)&Bl[bo];
#pragma unroll
      for (int m = 0; m < 4; ++m) {
        acc[m][n] =
            __builtin_amdgcn_mfma_f32_16x16x32_bf16(afh[m], bfh, acc[m][n], 0, 0, 0);
        acc[m][n] =
            __builtin_amdgcn_mfma_f32_16x16x32_bf16(afh[m], bfl, acc[m][n], 0, 0, 0);
        acc[m][n] =
            __builtin_amdgcn_mfma_f32_16x16x32_bf16(afl[m], bfh, acc[m][n], 0, 0, 0);
      }
    }
  }

  short* Ch = head ? eh_hi : et_hi;
  short* Cl = head ? eh_lo : et_lo;
  const int rbase = head ? row0 : row0 - 1024;
#pragma unroll
  for (int m = 0; m < 4; ++m) {
#pragma unroll
    for (int n = 0; n < 2; ++n) {
#pragma unroll
      for (int r = 0; r < 4; ++r) {
        int rg = rbase + wr * 64 + m * 16 + fq * 4 + r;
        int cg = col0 + wc * 32 + n * 16 + fr;
        float v = acc[m][n][r] + biasu[cg];
        size_t o = (size_t)rg * DDIM + cg;
        short hh = f2bf(v);
        Ch[o] = hh;
        Cl[o] = f2bf(v - bf2f(hh));
      }
    }
  }
}

// -------- logits GEMM: 32x64 tiles, swizzled LDS, 512 blocks,
//          batch->XCD affinity, single-buffer + overlap --------
__global__ __launch_bounds__(256) void gemm_logits(
    const short* __restrict__ eh_hi, const short* __restrict__ eh_lo,
    const short* __restrict__ et_hi, const short* __restrict__ et_lo,
    float* __restrict__ logits, float scale) {
  __shared__ short Ah[32 * 32], Al[32 * 32];
  __shared__ short Bh[64 * 32], Bl[64 * 32];
  const int bid = blockIdx.x;
  const int xcd = bid & 7, idx = bid >> 3;
  const int batch = xcd >> 1;
  const int sub = ((xcd & 1) << 6) | idx;
  const int xtile = sub & 15, ytile = sub >> 4;
  const int row0 = ytile * 32, col0 = xtile * 64;
  const int t = threadIdx.x;

  const int ahalf = t >> 7, ac2 = t & 127;
  const int asr = ac2 >> 2, acc_ = ac2 & 3;
  const short* aptr = (ahalf ? eh_lo : eh_hi) +
                      ((size_t)batch * NCLS + row0 + asr) * DDIM + acc_ * 8;
  const int aso = swz(asr, acc_);
  const int bsr = t >> 2, bcc = t & 3;
  const short* bph = et_hi + ((size_t)batch * NTOK + col0 + bsr) * DDIM + bcc * 8;
  const short* bpl = et_lo + ((size_t)batch * NTOK + col0 + bsr) * DDIM + bcc * 8;
  const int bso = swz(bsr, bcc);

  const int lane = t & 63, wave = t >> 6;
  const int wr = wave >> 1, wc = wave & 1;
  const int fr = lane & 15, fq = lane >> 4;

  f32x4 acc[2] = {};
  s16x8 rA = *(const s16x8*)(aptr);
  s16x8 rbh = *(const s16x8*)(bph);
  s16x8 rbl = *(const s16x8*)(bpl);

  for (int kt = 0; kt < 24; ++kt) {
    __syncthreads();
    *(s16x8*)&(ahalf ? Al : Ah)[aso] = rA;
    *(s16x8*)&Bh[bso] = rbh;
    *(s16x8*)&Bl[bso] = rbl;
    __syncthreads();
    const int kn = (kt < 23 ? kt + 1 : 23) * 32;
    rA = *(const s16x8*)(aptr + kn);
    rbh = *(const s16x8*)(bph + kn);
    rbl = *(const s16x8*)(bpl + kn);
    int ao = swz(wr * 16 + fr, fq);
    s16x8 afh = *(const s16x8*)&Ah[ao];
    s16x8 afl = *(const s16x8*)&Al[ao];
#pragma unroll
    for (int n = 0; n < 2; ++n) {
      int bo = swz(wc * 32 + n * 16 + fr, fq);
      s16x8 bfh = *(const s16x8*)&Bh[bo];
      s16x8 bfl = *(const s16x8*)&Bl[bo];
      acc[n] = __builtin_amdgcn_mfma_f32_16x16x32_bf16(afh, bfh, acc[n], 0, 0, 0);
      acc[n] = __builtin_amdgcn_mfma_f32_16x16x32_bf16(afh, bfl, acc[n], 0, 0, 0);
      acc[n] = __builtin_amdgcn_mfma_f32_16x16x32_bf16(afl, bfh, acc[n], 0, 0, 0);
    }
  }

  float* Cb = logits + (size_t)batch * NCLS * NTOK;
#pragma unroll
  for (int n = 0; n < 2; ++n)
#pragma unroll
    for (int r = 0; r < 4; ++r) {
      int rg = row0 + wr * 16 + fq * 4 + r;
      int cg = col0 + wc * 32 + n * 16 + fr;
      Cb[(size_t)rg * NTOK + cg] = scale * acc[n][r];
    }
}

// -------- fused select+agg, 512 threads/row: radix top-128, p-softmax,
//          gated ka dots (8 waves x 16 j, 2-deep prefetch), ka-softmax,
//          weighted sum -> bf16 lin inputs. 1 block/row ------------------
__global__ __launch_bounds__(512) void select_agg(
    const float* __restrict__ logits, const short* __restrict__ eh_hi,
    const short* __restrict__ et_hi, const float* __restrict__ cls,
    short* __restrict__ inbf) {
  const int bid = blockIdx.x;
  const int xcd = bid & 7, slot = bid >> 3;
  const int batch = xcd >> 1;
  const int row = batch * 256 + (xcd & 1) * 128 + slot;
  const int t = threadIdx.x, lane = t & 63, wave = t >> 6;  // wave 0..7

  __shared__ int hist[256];
  __shared__ int sh_bin, sh_rem;
  __shared__ int cnt;
  __shared__ int wsumT[8];
  __shared__ float p_sh[KSEL];
  __shared__ int idx_sh[KSEL];
  __shared__ float kaw_sh[KSEL];
  __shared__ float red[2];

  // ---- phase A: radix select top-128 (2 keys per thread) ----
  float2 v2 = *(const float2*)(logits + (size_t)row * NTOK + 2 * t);
  float val[2] = {v2.x, v2.y};
  unsigned key[2];
#pragma unroll
  for (int i = 0; i < 2; ++i) {
    unsigned u = __float_as_uint(val[i]);
    key[i] = (u & 0x80000000u) ? ~u : (u | 0x80000000u);
  }
  unsigned pref = 0, mask = 0;
  int rem = KSEL;
#pragma unroll
  for (int shift = 24; shift >= 0; shift -= 8) {
    if (t < 256) hist[t] = 0;
    __syncthreads();
#pragma unroll
    for (int i = 0; i < 2; ++i)
      if ((key[i] & mask) == pref)
        atomicAdd(&hist[(key[i] >> shift) & 255], 1);
    __syncthreads();
    if (wave == 0) {
      int h0 = hist[4 * lane], h1 = hist[4 * lane + 1];
      int h2 = hist[4 * lane + 2], h3 = hist[4 * lane + 3];
      int s = h0 + h1 + h2 + h3;
#pragma unroll
      for (int o = 1; o < 64; o <<= 1) {
        int v = __shfl_down(s, o, 64);
        if (lane + o < 64) s += v;
      }
      int abv = __shfl_down(s, 1, 64);
      if (lane == 63) abv = 0;
      int c3 = abv + h3, c2 = c3 + h2, c1 = c2 + h1, c0 = c1 + h0;
      int bin = -1, nab = 0;
      if (c3 >= rem && abv < rem) { bin = 4 * lane + 3; nab = abv; }
      else if (c2 >= rem && c3 < rem) { bin = 4 * lane + 2; nab = c3; }
      else if (c1 >= rem && c2 < rem) { bin = 4 * lane + 1; nab = c2; }
      else if (c0 >= rem && c1 < rem) { bin = 4 * lane + 0; nab = c1; }
      if (bin >= 0) { sh_bin = bin; sh_rem = rem - nab; }
    }
    __syncthreads();
    pref |= ((unsigned)sh_bin) << shift;
    mask |= 0xFFu << shift;
    rem = sh_rem;
  }
  const unsigned T = pref;
  const int above = KSEL - rem;

  if (t == 0) cnt = 0;
  int tc = (key[0] == T) + (key[1] == T);
  int inc = tc;
#pragma unroll
  for (int o = 1; o < 64; o <<= 1) {
    int v = __shfl_up(inc, o, 64);
    if (lane >= o) inc += v;
  }
  if (lane == 63) wsumT[wave] = inc;
  __syncthreads();
  int wbase = 0;
#pragma unroll
  for (int w = 0; w < 8; ++w)
    if (w < wave) wbase += wsumT[w];
  int excl = wbase + inc - tc;
#pragma unroll
  for (int i = 0; i < 2; ++i) {
    if (key[i] > T) {
      int s2 = atomicAdd(&cnt, 1);
      p_sh[s2] = val[i];
      idx_sh[s2] = 2 * t + i;
    } else if (key[i] == T) {
      int r = excl++;
      if (r < rem) {
        p_sh[above + r] = val[i];
        idx_sh[above + r] = 2 * t + i;
      }
    }
  }
  __syncthreads();

  // ---- phase B: softmax over p_sh ----
  if (wave == 0) {
    float m = wmaxr(fmaxf(p_sh[lane], p_sh[lane + 64]));
    if (!lane) red[0] = m;
  }
  __syncthreads();
  if (t < KSEL) p_sh[t] = __expf(p_sh[t] - red[0]);
  __syncthreads();
  if (wave == 0) {
    float s = wsum(p_sh[lane] + p_sh[lane + 64]);
    if (!lane) red[1] = s;
  }
  __syncthreads();
  if (t < KSEL) p_sh[t] *= (1.f / red[1]);
  __syncthreads();

  // ---- phase C: gated ka dots, 16 j per wave, 2-deep prefetch ----
  float ehr[12];
  {
    const short* ehrow = eh_hi + (size_t)row * DDIM;
    s16x8 e8 = *(const s16x8*)(ehrow + 8 * lane);
    short4 e4 = *(const short4*)(ehrow + 512 + 4 * lane);
#pragma unroll
    for (int i = 0; i < 8; ++i) ehr[i] = bf2f(e8[i]);
    ehr[8] = bf2f(e4.x);
    ehr[9] = bf2f(e4.y);
    ehr[10] = bf2f(e4.z);
    ehr[11] = bf2f(e4.w);
  }
  const short* etb = et_hi + (size_t)batch * NTOK * DDIM;

  {
    const int jb = wave * 16;
    const short* nb0 = etb + (size_t)idx_sh[jb] * DDIM;
    s16x8 n8 = *(const s16x8*)(nb0 + 8 * lane);
    short4 n4 = *(const short4*)(nb0 + 512 + 4 * lane);
    for (int i = 0; i < 16; ++i) {
      const int j = jb + i;
      s16x8 n8n;
      short4 n4n;
      if (i < 15) {
        const short* nbn = etb + (size_t)idx_sh[j + 1] * DDIM;
        n8n = *(const s16x8*)(nbn + 8 * lane);
        n4n = *(const short4*)(nbn + 512 + 4 * lane);
      }
      float pj = p_sh[j];
      float a = 4.f - 2.f * pj, b2 = 2.f * pj;
      float nq[12];
#pragma unroll
      for (int q = 0; q < 8; ++q) nq[q] = bf2f(n8[q]);
      nq[8] = bf2f(n4.x);
      nq[9] = bf2f(n4.y);
      nq[10] = bf2f(n4.z);
      nq[11] = bf2f(n4.w);
      float partial = 0.f;
#pragma unroll
      for (int q = 0; q < 12; ++q) {
        float y2 = fmaf(a, ehr[q], b2 * nq[q]);
        float ex = __expf(y2);
        float g = fmaf(-2.f, __builtin_amdgcn_rcpf(1.f + ex), 1.f);
        partial = fmaf(nq[q], g, partial);
      }
      partial = wsum(partial);
      if (!lane) kaw_sh[j] = partial;
      n8 = n8n;
      n4 = n4n;
    }
  }
  __syncthreads();

  // ---- phase D: softmax over kaw_sh ----
  if (wave == 0) {
    float m = wmaxr(fmaxf(kaw_sh[lane], kaw_sh[lane + 64]));
    if (!lane) red[0] = m;
  }
  __syncthreads();
  if (t < KSEL) kaw_sh[t] = __expf(kaw_sh[t] - red[0]);
  __syncthreads();
  if (wave == 0) {
    float s = wsum(kaw_sh[lane] + kaw_sh[lane + 64]);
    if (!lane) red[1] = s;
  }
  __syncthreads();
  if (t < KSEL) kaw_sh[t] *= (1.f / red[1]);
  __syncthreads();

  // ---- phase E: weighted sum + emit bf16 lin inputs (t < 192) ----
  if (t < 192) {
    const size_t o = (size_t)row * DDIM + 4 * t;
    short4 ehs = *(const short4*)(eh_hi + o);
    float4 eh4 = {bf2f(ehs.x), bf2f(ehs.y), bf2f(ehs.z), bf2f(ehs.w)};
    float4 cl4 = *(const float4*)(cls + o);
    float ax = 0.f, ay = 0.f, az = 0.f, aw = 0.f;
#pragma unroll 8
    for (int j = 0; j < KSEL; ++j) {
      float pr = kaw_sh[j];
      short4 nb = *(const short4*)(etb + (size_t)idx_sh[j] * DDIM + 4 * t);
      ax = fmaf(pr, bf2f(nb.x), ax);
      ay = fmaf(pr, bf2f(nb.y), ay);
      az = fmaf(pr, bf2f(nb.z), az);
      aw = fmaf(pr, bf2f(nb.w), aw);
    }
    short4 sv, bv;
    sv.x = f2bf((eh4.x + ax) * 0.1f + cl4.x);
    sv.y = f2bf((eh4.y + ay) * 0.1f + cl4.y);
    sv.z = f2bf((eh4.z + az) * 0.1f + cl4.z);
    sv.w = f2bf((eh4.w + aw) * 0.1f + cl4.w);
    bv.x = f2bf((eh4.x * ax) * 0.1f + cl4.x);
    bv.y = f2bf((eh4.y * ay) * 0.1f + cl4.y);
    bv.z = f2bf((eh4.z * az) * 0.1f + cl4.z);
    bv.w = f2bf((eh4.w * aw) * 0.1f + cl4.w);
    *(short4*)&inbf[o] = sv;
    *(short4*)&inbf[(size_t)(NBATCH * NCLS) * DDIM + o] = bv;
  }
}

// -------- lin GEMM fused: both lin1 & lin2 per tile -> emb directly,
//          32x64 tiles, swizzled LDS, XCD-chunked (384 = 8 x 48) --------
__global__ __launch_bounds__(256) void gemm_lin(
    const short* __restrict__ inbf, const short* __restrict__ L1T,
    const short* __restrict__ L2T, const float* __restrict__ b1,
    const float* __restrict__ b2, float* __restrict__ emb) {
  __shared__ short A1[32 * 32], A2[32 * 32];
  __shared__ short B1[64 * 32], B2[64 * 32];
  const int bid = blockIdx.x;
  const int xcd = bid & 7, idx = bid >> 3;  // 0..47
  const int ytile = xcd * 4 + idx / 12, xtile = idx % 12;  // 32 x 12
  const int t = threadIdx.x;
  const int row0 = ytile * 32, col0 = xtile * 64;

  const int ahalf = t >> 7, at = t & 127;
  const int asr = at >> 2, asc = at & 3;
  const short* aptr = inbf + (ahalf ? (size_t)1024 * DDIM : 0) +
                      (size_t)(row0 + asr) * DDIM + asc * 8;
  const int aso = swz(asr, asc);
  const int bsr = t >> 2, bsc = t & 3;
  const short* b1p = L1T + (size_t)(col0 + bsr) * DDIM + bsc * 8;
  const short* b2p = L2T + (size_t)(col0 + bsr) * DDIM + bsc * 8;
  const int bso = swz(bsr, bsc);

  const int lane = t & 63, wave = t >> 6;
  const int wr = wave >> 1, wc = wave & 1;
  const int fr = lane & 15, fq = lane >> 4;

  f32x4 acc1[2] = {}, acc2[2] = {};
  s16x8 rA = *(const s16x8*)(aptr);
  s16x8 rB1 = *(const s16x8*)(b1p);
  s16x8 rB2 = *(const s16x8*)(b2p);
  for (int kt = 0; kt < 24; ++kt) {
    __syncthreads();
    *(s16x8*)&(ahalf ? A2 : A1)[aso] = rA;
    *(s16x8*)&B1[bso] = rB1;
    *(s16x8*)&B2[bso] = rB2;
    __syncthreads();
    const int kn = (kt < 23 ? kt + 1 : 23) * 32;
    rA = *(const s16x8*)(aptr + kn);
    rB1 = *(const s16x8*)(b1p + kn);
    rB2 = *(const s16x8*)(b2p + kn);
    int ao = swz(wr * 16 + fr, fq);
    s16x8 a1f = *(const s16x8*)&A1[ao];
    s16x8 a2f = *(const s16x8*)&A2[ao];
#pragma unroll
    for (int n = 0; n < 2; ++n) {
      int bo = swz(wc * 32 + n * 16 + fr, fq);
      s16x8 b1f = *(const s16x8*)&B1[bo];
      s16x8 b2f = *(const s16x8*)&B2[bo];
      acc1[n] = __builtin_amdgcn_mfma_f32_16x16x32_bf16(a1f, b1f, acc1[n], 0, 0, 0);
      acc2[n] = __builtin_amdgcn_mfma_f32_16x16x32_bf16(a2f, b2f, acc2[n], 0, 0, 0);
    }
  }
#pragma unroll
  for (int n = 0; n < 2; ++n)
#pragma unroll
    for (int r = 0; r < 4; ++r) {
      int rg = row0 + wr * 16 + fq * 4 + r;
      int cg = col0 + wc * 32 + n * 16 + fr;
      float v1 = acc1[n][r] + b1[cg];
      v1 = v1 > 0.f ? v1 : 0.01f * v1;
      float v2 = acc2[n][r] + b2[cg];
      v2 = v2 > 0.f ? v2 : 0.01f * v2;
      emb[(size_t)rg * DDIM + cg] = v1 + v2;
    }
}

// -------- layernorm over D=768 --------
__global__ __launch_bounds__(256) void ln_kernel(const float* __restrict__ emb,
                                                 const float* __restrict__ lw,
                                                 const float* __restrict__ lb,
                                                 float* __restrict__ out) {
  const int row = blockIdx.x;
  const int t = threadIdx.x;
  const int lane = t & 63, wave = t >> 6;
  __shared__ float red[4];
  __shared__ float bs[2];
  float e[3];
#pragma unroll
  for (int c = 0; c < 3; ++c) e[c] = emb[(size_t)row * DDIM + t + 256 * c];
  float s = e[0] + e[1] + e[2];
  s = wsum(s);
  if (lane == 0) red[wave] = s;
  __syncthreads();
  if (t == 0) bs[0] = (red[0] + red[1] + red[2] + red[3]) * (1.f / DDIM);
  __syncthreads();
  float mu = bs[0];
  float q = 0.f;
#pragma unroll
  for (int c = 0; c < 3; ++c) {
    float d = e[c] - mu;
    q = fmaf(d, d, q);
  }
  q = wsum(q);
  if (lane == 0) red[wave] = q;
  __syncthreads();
  if (t == 0) bs[1] = (red[0] + red[1] + red[2] + red[3]) * (1.f / DDIM);
  __syncthreads();
  float rstd = rsqrtf(bs[1] + 1e-5f);
#pragma unroll
  for (int c = 0; c < 3; ++c) {
    int d = t + 256 * c;
    out[(size_t)row * DDIM + d] = (e[c] - mu) * rstd * lw[d] + lb[d];
  }
}

// ---------------- launch ----------------
extern "C" void kernel_launch(void* const* d_in, const int* in_sizes, int n_in,
                              void* d_out, int out_size, void* d_ws,
                              size_t ws_size, hipStream_t stream) {
  const float* cls = (const float*)d_in[0];
  const float* feats = (const float*)d_in[1];
  const float* Whw = (const float*)d_in[2];
  const float* Whb = (const float*)d_in[3];
  const float* Wtw = (const float*)d_in[4];
  const float* Wtb = (const float*)d_in[5];
  const float* l1w = (const float*)d_in[6];
  const float* l1b = (const float*)d_in[7];
  const float* l2w = (const float*)d_in[8];
  const float* l2b = (const float*)d_in[9];
  const float* lnw = (const float*)d_in[10];
  const float* lnb = (const float*)d_in[11];
  float* out = (float*)d_out;

  float* ws = (float*)d_ws;
  // layout (float units)
  float* emb = ws;                          // 786432 (lin fused output)
  short* eh_hi = (short*)(ws + 3932160);    // 786432 shorts
  short* eh_lo = eh_hi + 786432;            // (ends 4718592f)
  short* et_hi = (short*)(ws + 4718592);    // 3145728 shorts
  short* et_lo = et_hi + 3145728;           // (ends 7864320f)
  short* WhT_h = (short*)(ws + 7864320);    // 589824 shorts each
  short* WhT_l = WhT_h + 589824;
  short* WtT_h = WhT_h + 2 * 589824;
  short* WtT_l = WhT_h + 3 * 589824;        // (ends 9043968f)
  short* L1T = (short*)(ws + 9043968);      // 589824 shorts
  short* L2T = L1T + 589824;                // (ends 9633792f)
  float* logits = ws + 7864320;             // overlays WhT/WtT (dead by then)
  short* Xh = (short*)(ws + 9633792);       // X bf16 hi/lo; dead after front
  short* Xl = Xh + 3145728;                 // (ends 12779520f)
  short* inbf = (short*)(ws + 10027008);    // 2048*768 shorts (786432 f)
  (void)ws_size;
  (void)in_sizes;
  (void)n_in;
  (void)out_size;

  const float scale = 0.036084391824351615f;  // 1/sqrt(768)
  dim3 blk(256);

  // merged prep: weights (2304 blocks) + X pack (1536 blocks)
  prep_all<<<dim3(3840), blk, 0, stream>>>(cls, feats, Whw, Wtw, l1w, l2w,
                                           WhT_h, WtT_h, L1T, L2T, WhT_l,
                                           WtT_l, Xh, Xl);
  // fused e_h | e_t (480 blocks, 128x64, XCD-chunked, swizzled LDS)
  gemm_front<<<dim3(480), blk, 0, stream>>>(
      Xh, Xl, WhT_h, WhT_l, Whb, WtT_h, WtT_l, Wtb, eh_hi, eh_lo, et_hi,
      et_lo);
  // logits[b] = scale * e_h[b] @ e_t[b]^T (512 blocks, batch->XCD)
  gemm_logits<<<dim3(512), blk, 0, stream>>>(eh_hi, eh_lo, et_hi, et_lo,
                                             logits, scale);
  // fused top-128 select + both softmaxes + gated agg (1024 x 512 threads)
  select_agg<<<dim3(1024), dim3(512), 0, stream>>>(logits, eh_hi, et_hi, cls,
                                                   inbf);
  // fused lin1+lin2 -> emb (384 blocks, 32x64, XCD-chunked)
  gemm_lin<<<dim3(384), blk, 0, stream>>>(inbf, L1T, L2T, l1b, l2b, emb);
  // layernorm(emb) -> out
  ln_kernel<<<dim3(NBATCH * NCLS), blk, 0, stream>>>(emb, lnw, lnb, out);
}

// Round 14
// 110.922 us; speedup vs baseline: 1.2389x; 1.0577x over previous
//
#include <hip/hip_runtime.h>
#include <hip/hip_bf16.h>
#include <math.h>

#define DDIM 768
#define NCLS 256
#define NFEAT 768
#define NTOK 1024
#define NBATCH 4
#define KSEL 128

typedef float f32x4 __attribute__((ext_vector_type(4)));
typedef float f32x2 __attribute__((ext_vector_type(2)));
typedef short s16x8 __attribute__((ext_vector_type(8)));

#if __has_builtin(__builtin_amdgcn_exp2f)
#define EXP2F __builtin_amdgcn_exp2f
#else
#define EXP2F(x) __expf(0.6931471805599453f * (x))
#endif

// ---------------- helpers ----------------
__device__ __forceinline__ float wsum(float v) {
#pragma unroll
  for (int o = 32; o; o >>= 1) v += __shfl_down(v, o, 64);
  return v;
}
__device__ __forceinline__ float wmaxr(float v) {
#pragma unroll
  for (int o = 32; o; o >>= 1) v = fmaxf(v, __shfl_down(v, o, 64));
  return v;
}
__device__ __forceinline__ short f2bf(float f) {
  union { __hip_bfloat16 h; short s; } u;
  u.h = __float2bfloat16(f);
  return u.s;
}
__device__ __forceinline__ float bf2f(short s) {
  union { unsigned u; float f; } c;
  c.u = ((unsigned)(unsigned short)s) << 16;
  return c.f;
}
// two packed bf16 (one u32) -> two fp32
__device__ __forceinline__ f32x2 bfpair(unsigned w) {
  f32x2 r;
  r.x = __uint_as_float(w << 16);
  r.y = __uint_as_float(w & 0xffff0000u);
  return r;
}
__device__ __forceinline__ void cvt8(float4 x, float4 y, s16x8& h, s16x8& l) {
  float v[8] = {x.x, x.y, x.z, x.w, y.x, y.y, y.z, y.w};
#pragma unroll
  for (int i = 0; i < 8; ++i) {
    short hh = f2bf(v[i]);
    h[i] = hh;
    l[i] = f2bf(v[i] - bf2f(hh));
  }
}
// LDS address swizzle: 32-short (64B) rows, 8-short (16B) chunks.
__device__ __forceinline__ int swz(int row, int chunk) {
  return (row << 5) + (((chunk ^ (row >> 1)) & 3) << 3);
}

// -------- merged prep: blocks 0..2303 = weight transpose+cvt,
//          blocks 2304..3839 = X pack (concat(cls,feats) -> hi/lo) -------
__global__ __launch_bounds__(256) void prep_all(
    const float* __restrict__ cls, const float* __restrict__ feats,
    const float* __restrict__ w0, const float* __restrict__ w1,
    const float* __restrict__ w2, const float* __restrict__ w3,
    short* __restrict__ h0, short* __restrict__ h1, short* __restrict__ h2,
    short* __restrict__ h3, short* __restrict__ l0, short* __restrict__ l1,
    short* __restrict__ Xh, short* __restrict__ Xl) {
  __shared__ float tile[32][33];
  const int bid = blockIdx.x;
  const int t = threadIdx.x;
  if (bid < 2304) {
    const int z = bid / 576, rem = bid % 576;
    const int by = rem / 24, bx = rem % 24;
    const float* s = z == 0 ? w0 : z == 1 ? w1 : z == 2 ? w2 : w3;
    short* dh = z == 0 ? h0 : z == 1 ? h1 : z == 2 ? h2 : h3;
    short* dl = z == 0 ? l0 : z == 1 ? l1 : nullptr;
    const int tx = t & 31, ty0 = t >> 5;
    const int r0 = by * 32, c0 = bx * 32;
#pragma unroll
    for (int i = 0; i < 4; ++i) {
      int ty = ty0 + i * 8;
      tile[ty][tx] = s[(size_t)(r0 + ty) * DDIM + c0 + tx];
    }
    __syncthreads();
#pragma unroll
    for (int i = 0; i < 4; ++i) {
      int ty = ty0 + i * 8;
      float v = tile[tx][ty];
      short hh = f2bf(v);
      dh[(size_t)(c0 + ty) * DDIM + r0 + tx] = hh;
      if (dl) dl[(size_t)(c0 + ty) * DDIM + r0 + tx] = f2bf(v - bf2f(hh));
    }
  } else {
    const size_t base = ((size_t)(bid - 2304) * 256 + t) * 8;
    const int row = (int)(base / DDIM);
    const int col = (int)(base % DDIM);
    const int b = row >> 10, rr = row & 1023;
    const float* src =
        (rr < NCLS) ? cls + ((size_t)b * NCLS + rr) * DDIM + col
                    : feats + ((size_t)b * NFEAT + (rr - NCLS)) * DDIM + col;
    float4 a0 = *(const float4*)(src);
    float4 a1 = *(const float4*)(src + 4);
    s16x8 h, l;
    cvt8(a0, a1, h, l);
    *(s16x8*)(Xh + base) = h;
    *(s16x8*)(Xl + base) = l;
  }
}

// -------- front GEMM (fused e_h | e_t), 128x64 tiles, split-bf16,
//          bf16 hi/lo outputs only, swizzled LDS, XCD-chunked (480) -----
__global__ __launch_bounds__(256) void gemm_front(
    const short* __restrict__ Xh, const short* __restrict__ Xl,
    const short* __restrict__ WhT_h, const short* __restrict__ WhT_l,
    const float* __restrict__ Whb, const short* __restrict__ WtT_h,
    const short* __restrict__ WtT_l, const float* __restrict__ Wtb,
    short* __restrict__ eh_hi, short* __restrict__ eh_lo,
    short* __restrict__ et_hi, short* __restrict__ et_lo) {
  __shared__ short Ah[128 * 32], Al[128 * 32];
  __shared__ short Bh[64 * 32], Bl[64 * 32];
  const int bid = blockIdx.x;
  const int xcd = bid & 7, idx = bid >> 3;  // idx 0..59
  const int ytile = xcd * 5 + idx / 12;     // 0..39
  const int xtile = idx % 12;
  const int t = threadIdx.x;
  const int row0 = ytile * 128, col0 = xtile * 64;
  const bool head = row0 < 1024;

  const int ar = t >> 1, ac = (t & 1) * 2;
  const int aw0 = swz(ar, ac), aw1 = swz(ar, ac + 1);
  size_t xrow;
  {
    int gr = row0 + ar;
    xrow = head ? (size_t)(((gr >> 8) << 10) + (gr & 255)) : (size_t)(gr - 1024);
  }
  const short* aph = Xh + xrow * DDIM + ac * 8;
  const short* apl = Xl + xrow * DDIM + ac * 8;
  const int br = t >> 2, bc = t & 3;
  const int bw0 = swz(br, bc);
  const short* bph = (head ? WhT_h : WtT_h) + (size_t)(col0 + br) * DDIM + bc * 8;
  const short* bpl = (head ? WhT_l : WtT_l) + (size_t)(col0 + br) * DDIM + bc * 8;
  const float* biasu = head ? Whb : Wtb;

  const int lane = t & 63, wave = t >> 6;
  const int wr = wave >> 1, wc = wave & 1;
  const int fr = lane & 15, fq = lane >> 4;

  f32x4 acc[4][2] = {};
  s16x8 rah0 = *(const s16x8*)(aph);
  s16x8 rah1 = *(const s16x8*)(aph + 8);
  s16x8 ral0 = *(const s16x8*)(apl);
  s16x8 ral1 = *(const s16x8*)(apl + 8);
  s16x8 rbh = *(const s16x8*)(bph);
  s16x8 rbl = *(const s16x8*)(bpl);

  for (int kt = 0; kt < 24; ++kt) {
    __syncthreads();
    *(s16x8*)&Ah[aw0] = rah0;
    *(s16x8*)&Ah[aw1] = rah1;
    *(s16x8*)&Al[aw0] = ral0;
    *(s16x8*)&Al[aw1] = ral1;
    *(s16x8*)&Bh[bw0] = rbh;
    *(s16x8*)&Bl[bw0] = rbl;
    __syncthreads();
    const int kn = (kt < 23 ? kt + 1 : 23) * 32;
    rah0 = *(const s16x8*)(aph + kn);
    rah1 = *(const s16x8*)(aph + kn + 8);
    ral0 = *(const s16x8*)(apl + kn);
    ral1 = *(const s16x8*)(apl + kn + 8);
    rbh = *(const s16x8*)(bph + kn);
    rbl = *(const s16x8*)(bpl + kn);

    s16x8 afh[4], afl[4];
#pragma unroll
    for (int m = 0; m < 4; ++m) {
      int ao = swz(wr * 64 + m * 16 + fr, fq);
      afh[m] = *(const s16x8*)&Ah[ao];
      afl[m] = *(const s16x8*)&Al[ao];
    }
#pragma unroll
    for (int n = 0; n < 2; ++n) {
      int bo = swz(wc * 32 + n * 16 + fr, fq);
      s16x8 bfh = *(const s16x8*)&Bh[bo];
      s16x8 bfl = *(const s16x8*)&Bl[bo];
#pragma unroll
      for (int m = 0; m < 4; ++m) {
        acc[m][n] =
            __builtin_amdgcn_mfma_f32_16x16x32_bf16(afh[m], bfh, acc[m][n], 0, 0, 0);
        acc[m][n] =
            __builtin_amdgcn_mfma_f32_16x16x32_bf16(afh[m], bfl, acc[m][n], 0, 0, 0);
        acc[m][n] =
            __builtin_amdgcn_mfma_f32_16x16x32_bf16(afl[m], bfh, acc[m][n], 0, 0, 0);
      }
    }
  }

  short* Ch = head ? eh_hi : et_hi;
  short* Cl = head ? eh_lo : et_lo;
  const int rbase = head ? row0 : row0 - 1024;
#pragma unroll
  for (int m = 0; m < 4; ++m) {
#pragma unroll
    for (int n = 0; n < 2; ++n) {
#pragma unroll
      for (int r = 0; r < 4; ++r) {
        int rg = rbase + wr * 64 + m * 16 + fq * 4 + r;
        int cg = col0 + wc * 32 + n * 16 + fr;
        float v = acc[m][n][r] + biasu[cg];
        size_t o = (size_t)rg * DDIM + cg;
        short hh = f2bf(v);
        Ch[o] = hh;
        Cl[o] = f2bf(v - bf2f(hh));
      }
    }
  }
}

// -------- logits GEMM: 32x64 tiles, swizzled LDS, 512 blocks,
//          batch->XCD affinity, single-buffer + overlap --------
__global__ __launch_bounds__(256) void gemm_logits(
    const short* __restrict__ eh_hi, const short* __restrict__ eh_lo,
    const short* __restrict__ et_hi, const short* __restrict__ et_lo,
    float* __restrict__ logits, float scale) {
  __shared__ short Ah[32 * 32], Al[32 * 32];
  __shared__ short Bh[64 * 32], Bl[64 * 32];
  const int bid = blockIdx.x;
  const int xcd = bid & 7, idx = bid >> 3;
  const int batch = xcd >> 1;
  const int sub = ((xcd & 1) << 6) | idx;
  const int xtile = sub & 15, ytile = sub >> 4;
  const int row0 = ytile * 32, col0 = xtile * 64;
  const int t = threadIdx.x;

  const int ahalf = t >> 7, ac2 = t & 127;
  const int asr = ac2 >> 2, acc_ = ac2 & 3;
  const short* aptr = (ahalf ? eh_lo : eh_hi) +
                      ((size_t)batch * NCLS + row0 + asr) * DDIM + acc_ * 8;
  const int aso = swz(asr, acc_);
  const int bsr = t >> 2, bcc = t & 3;
  const short* bph = et_hi + ((size_t)batch * NTOK + col0 + bsr) * DDIM + bcc * 8;
  const short* bpl = et_lo + ((size_t)batch * NTOK + col0 + bsr) * DDIM + bcc * 8;
  const int bso = swz(bsr, bcc);

  const int lane = t & 63, wave = t >> 6;
  const int wr = wave >> 1, wc = wave & 1;
  const int fr = lane & 15, fq = lane >> 4;

  f32x4 acc[2] = {};
  s16x8 rA = *(const s16x8*)(aptr);
  s16x8 rbh = *(const s16x8*)(bph);
  s16x8 rbl = *(const s16x8*)(bpl);

  for (int kt = 0; kt < 24; ++kt) {
    __syncthreads();
    *(s16x8*)&(ahalf ? Al : Ah)[aso] = rA;
    *(s16x8*)&Bh[bso] = rbh;
    *(s16x8*)&Bl[bso] = rbl;
    __syncthreads();
    const int kn = (kt < 23 ? kt + 1 : 23) * 32;
    rA = *(const s16x8*)(aptr + kn);
    rbh = *(const s16x8*)(bph + kn);
    rbl = *(const s16x8*)(bpl + kn);
    int ao = swz(wr * 16 + fr, fq);
    s16x8 afh = *(const s16x8*)&Ah[ao];
    s16x8 afl = *(const s16x8*)&Al[ao];
#pragma unroll
    for (int n = 0; n < 2; ++n) {
      int bo = swz(wc * 32 + n * 16 + fr, fq);
      s16x8 bfh = *(const s16x8*)&Bh[bo];
      s16x8 bfl = *(const s16x8*)&Bl[bo];
      acc[n] = __builtin_amdgcn_mfma_f32_16x16x32_bf16(afh, bfh, acc[n], 0, 0, 0);
      acc[n] = __builtin_amdgcn_mfma_f32_16x16x32_bf16(afh, bfl, acc[n], 0, 0, 0);
      acc[n] = __builtin_amdgcn_mfma_f32_16x16x32_bf16(afl, bfh, acc[n], 0, 0, 0);
    }
  }

  float* Cb = logits + (size_t)batch * NCLS * NTOK;
#pragma unroll
  for (int n = 0; n < 2; ++n)
#pragma unroll
    for (int r = 0; r < 4; ++r) {
      int rg = row0 + wr * 16 + fq * 4 + r;
      int cg = col0 + wc * 32 + n * 16 + fr;
      Cb[(size_t)rg * NTOK + cg] = scale * acc[n][r];
    }
}

// -------- fused select+agg, 512 threads/row, packed-f32 gate math -------
__global__ __launch_bounds__(512) void select_agg(
    const float* __restrict__ logits, const short* __restrict__ eh_hi,
    const short* __restrict__ et_hi, const float* __restrict__ cls,
    short* __restrict__ inbf) {
  const int bid = blockIdx.x;
  const int xcd = bid & 7, slot = bid >> 3;
  const int batch = xcd >> 1;
  const int row = batch * 256 + (xcd & 1) * 128 + slot;
  const int t = threadIdx.x, lane = t & 63, wave = t >> 6;  // wave 0..7

  __shared__ int hist[256];
  __shared__ int sh_bin, sh_rem;
  __shared__ int cnt;
  __shared__ int wsumT[8];
  __shared__ float p_sh[KSEL];
  __shared__ int idx_sh[KSEL];
  __shared__ float kaw_sh[KSEL];
  __shared__ float red[2];

  // ---- phase A: radix select top-128 (2 keys per thread) ----
  float2 v2 = *(const float2*)(logits + (size_t)row * NTOK + 2 * t);
  float val[2] = {v2.x, v2.y};
  unsigned key[2];
#pragma unroll
  for (int i = 0; i < 2; ++i) {
    unsigned u = __float_as_uint(val[i]);
    key[i] = (u & 0x80000000u) ? ~u : (u | 0x80000000u);
  }
  unsigned pref = 0, mask = 0;
  int rem = KSEL;
#pragma unroll
  for (int shift = 24; shift >= 0; shift -= 8) {
    if (t < 256) hist[t] = 0;
    __syncthreads();
#pragma unroll
    for (int i = 0; i < 2; ++i)
      if ((key[i] & mask) == pref)
        atomicAdd(&hist[(key[i] >> shift) & 255], 1);
    __syncthreads();
    if (wave == 0) {
      int h0 = hist[4 * lane], h1 = hist[4 * lane + 1];
      int h2 = hist[4 * lane + 2], h3 = hist[4 * lane + 3];
      int s = h0 + h1 + h2 + h3;
#pragma unroll
      for (int o = 1; o < 64; o <<= 1) {
        int v = __shfl_down(s, o, 64);
        if (lane + o < 64) s += v;
      }
      int abv = __shfl_down(s, 1, 64);
      if (lane == 63) abv = 0;
      int c3 = abv + h3, c2 = c3 + h2, c1 = c2 + h1, c0 = c1 + h0;
      int bin = -1, nab = 0;
      if (c3 >= rem && abv < rem) { bin = 4 * lane + 3; nab = abv; }
      else if (c2 >= rem && c3 < rem) { bin = 4 * lane + 2; nab = c3; }
      else if (c1 >= rem && c2 < rem) { bin = 4 * lane + 1; nab = c2; }
      else if (c0 >= rem && c1 < rem) { bin = 4 * lane + 0; nab = c1; }
      if (bin >= 0) { sh_bin = bin; sh_rem = rem - nab; }
    }
    __syncthreads();
    pref |= ((unsigned)sh_bin) << shift;
    mask |= 0xFFu << shift;
    rem = sh_rem;
  }
  const unsigned T = pref;
  const int above = KSEL - rem;

  if (t == 0) cnt = 0;
  int tc = (key[0] == T) + (key[1] == T);
  int inc = tc;
#pragma unroll
  for (int o = 1; o < 64; o <<= 1) {
    int v = __shfl_up(inc, o, 64);
    if (lane >= o) inc += v;
  }
  if (lane == 63) wsumT[wave] = inc;
  __syncthreads();
  int wbase = 0;
#pragma unroll
  for (int w = 0; w < 8; ++w)
    if (w < wave) wbase += wsumT[w];
  int excl = wbase + inc - tc;
#pragma unroll
  for (int i = 0; i < 2; ++i) {
    if (key[i] > T) {
      int s2 = atomicAdd(&cnt, 1);
      p_sh[s2] = val[i];
      idx_sh[s2] = 2 * t + i;
    } else if (key[i] == T) {
      int r = excl++;
      if (r < rem) {
        p_sh[above + r] = val[i];
        idx_sh[above + r] = 2 * t + i;
      }
    }
  }
  __syncthreads();

  // ---- phase B: softmax over p_sh ----
  if (wave == 0) {
    float m = wmaxr(fmaxf(p_sh[lane], p_sh[lane + 64]));
    if (!lane) red[0] = m;
  }
  __syncthreads();
  if (t < KSEL) p_sh[t] = __expf(p_sh[t] - red[0]);
  __syncthreads();
  if (wave == 0) {
    float s = wsum(p_sh[lane] + p_sh[lane + 64]);
    if (!lane) red[1] = s;
  }
  __syncthreads();
  if (t < KSEL) p_sh[t] *= (1.f / red[1]);
  __syncthreads();

  // ---- phase C: gated ka dots, 16 j per wave, packed f32, prefetch ----
  // ehr as 6 packed pairs (elems [8*lane..8*lane+7] + [512+4*lane..+3])
  f32x2 eh2[6];
  {
    const short* ehrow = eh_hi + (size_t)row * DDIM;
    s16x8 e8 = *(const s16x8*)(ehrow + 8 * lane);
    short4 e4 = *(const short4*)(ehrow + 512 + 4 * lane);
    const unsigned* w8 = (const unsigned*)&e8;
    const unsigned* w4 = (const unsigned*)&e4;
#pragma unroll
    for (int i = 0; i < 4; ++i) eh2[i] = bfpair(w8[i]);
    eh2[4] = bfpair(w4[0]);
    eh2[5] = bfpair(w4[1]);
  }
  const short* etb = et_hi + (size_t)batch * NTOK * DDIM;
  const float LOG2E = 1.4426950408889634f;

  {
    const int jb = wave * 16;
    const short* nb0 = etb + (size_t)idx_sh[jb] * DDIM;
    s16x8 n8 = *(const s16x8*)(nb0 + 8 * lane);
    short4 n4 = *(const short4*)(nb0 + 512 + 4 * lane);
    for (int i = 0; i < 16; ++i) {
      const int j = jb + i;
      s16x8 n8n;
      short4 n4n;
      if (i < 15) {
        const short* nbn = etb + (size_t)idx_sh[j + 1] * DDIM;
        n8n = *(const s16x8*)(nbn + 8 * lane);
        n4n = *(const short4*)(nbn + 512 + 4 * lane);
      }
      float pj = p_sh[j];
      float a2 = (4.f - 2.f * pj) * LOG2E;
      float b22 = (2.f * pj) * LOG2E;
      f32x2 av = {a2, a2}, bv = {b22, b22};
      f32x2 acc2 = {0.f, 0.f};
      const unsigned* w8 = (const unsigned*)&n8;
      const unsigned* w4 = (const unsigned*)&n4;
      f32x2 nq2[6];
#pragma unroll
      for (int q = 0; q < 4; ++q) nq2[q] = bfpair(w8[q]);
      nq2[4] = bfpair(w4[0]);
      nq2[5] = bfpair(w4[1]);
#pragma unroll
      for (int q = 0; q < 6; ++q) {
        f32x2 arg = av * eh2[q] + bv * nq2[q];      // pk_mul + pk_fma
        f32x2 ex;
        ex.x = EXP2F(arg.x);
        ex.y = EXP2F(arg.y);
        f32x2 den = ex + (f32x2){1.f, 1.f};         // pk_add
        f32x2 r;
        r.x = __builtin_amdgcn_rcpf(den.x);
        r.y = __builtin_amdgcn_rcpf(den.y);
        f32x2 g = r * (f32x2){-2.f, -2.f} + (f32x2){1.f, 1.f};  // pk_fma
        acc2 = nq2[q] * g + acc2;                    // pk_fma
      }
      float partial = acc2.x + acc2.y;
      partial = wsum(partial);
      if (!lane) kaw_sh[j] = partial;
      n8 = n8n;
      n4 = n4n;
    }
  }
  __syncthreads();

  // ---- phase D: softmax over kaw_sh ----
  if (wave == 0) {
    float m = wmaxr(fmaxf(kaw_sh[lane], kaw_sh[lane + 64]));
    if (!lane) red[0] = m;
  }
  __syncthreads();
  if (t < KSEL) kaw_sh[t] = __expf(kaw_sh[t] - red[0]);
  __syncthreads();
  if (wave == 0) {
    float s = wsum(kaw_sh[lane] + kaw_sh[lane + 64]);
    if (!lane) red[1] = s;
  }
  __syncthreads();
  if (t < KSEL) kaw_sh[t] *= (1.f / red[1]);
  __syncthreads();

  // ---- phase E: weighted sum, 384 threads x 2 elems, packed fma ----
  if (t < 384) {
    const size_t o = (size_t)row * DDIM + 2 * t;
    unsigned ehw = *(const unsigned*)(eh_hi + o);
    f32x2 eh = bfpair(ehw);
    float2 cl2 = *(const float2*)(cls + o);
    f32x2 cl = {cl2.x, cl2.y};
    f32x2 acc = {0.f, 0.f};
#pragma unroll 8
    for (int j = 0; j < KSEL; ++j) {
      float pr = kaw_sh[j];
      unsigned w = *(const unsigned*)(etb + (size_t)idx_sh[j] * DDIM + 2 * t);
      f32x2 nb = bfpair(w);
      acc = nb * (f32x2){pr, pr} + acc;  // pk_fma
    }
    f32x2 sv = (eh + acc) * (f32x2){0.1f, 0.1f} + cl;
    f32x2 bvv = (eh * acc) * (f32x2){0.1f, 0.1f} + cl;
    short2 s2, b2;
    s2.x = f2bf(sv.x);
    s2.y = f2bf(sv.y);
    b2.x = f2bf(bvv.x);
    b2.y = f2bf(bvv.y);
    *(short2*)&inbf[o] = s2;
    *(short2*)&inbf[(size_t)(NBATCH * NCLS) * DDIM + o] = b2;
  }
}

// -------- lin GEMM fused: both lin1 & lin2 per tile -> emb directly,
//          32x64 tiles, swizzled LDS, XCD-chunked (384 = 8 x 48) --------
__global__ __launch_bounds__(256) void gemm_lin(
    const short* __restrict__ inbf, const short* __restrict__ L1T,
    const short* __restrict__ L2T, const float* __restrict__ b1,
    const float* __restrict__ b2, float* __restrict__ emb) {
  __shared__ short A1[32 * 32], A2[32 * 32];
  __shared__ short B1[64 * 32], B2[64 * 32];
  const int bid = blockIdx.x;
  const int xcd = bid & 7, idx = bid >> 3;  // 0..47
  const int ytile = xcd * 4 + idx / 12, xtile = idx % 12;  // 32 x 12
  const int t = threadIdx.x;
  const int row0 = ytile * 32, col0 = xtile * 64;

  const int ahalf = t >> 7, at = t & 127;
  const int asr = at >> 2, asc = at & 3;
  const short* aptr = inbf + (ahalf ? (size_t)1024 * DDIM : 0) +
                      (size_t)(row0 + asr) * DDIM + asc * 8;
  const int aso = swz(asr, asc);
  const int bsr = t >> 2, bsc = t & 3;
  const short* b1p = L1T + (size_t)(col0 + bsr) * DDIM + bsc * 8;
  const short* b2p = L2T + (size_t)(col0 + bsr) * DDIM + bsc * 8;
  const int bso = swz(bsr, bsc);

  const int lane = t & 63, wave = t >> 6;
  const int wr = wave >> 1, wc = wave & 1;
  const int fr = lane & 15, fq = lane >> 4;

  f32x4 acc1[2] = {}, acc2[2] = {};
  s16x8 rA = *(const s16x8*)(aptr);
  s16x8 rB1 = *(const s16x8*)(b1p);
  s16x8 rB2 = *(const s16x8*)(b2p);
  for (int kt = 0; kt < 24; ++kt) {
    __syncthreads();
    *(s16x8*)&(ahalf ? A2 : A1)[aso] = rA;
    *(s16x8*)&B1[bso] = rB1;
    *(s16x8*)&B2[bso] = rB2;
    __syncthreads();
    const int kn = (kt < 23 ? kt + 1 : 23) * 32;
    rA = *(const s16x8*)(aptr + kn);
    rB1 = *(const s16x8*)(b1p + kn);
    rB2 = *(const s16x8*)(b2p + kn);
    int ao = swz(wr * 16 + fr, fq);
    s16x8 a1f = *(const s16x8*)&A1[ao];
    s16x8 a2f = *(const s16x8*)&A2[ao];
#pragma unroll
    for (int n = 0; n < 2; ++n) {
      int bo = swz(wc * 32 + n * 16 + fr, fq);
      s16x8 b1f = *(const s16x8*)&B1[bo];
      s16x8 b2f = *(const s16x8*)&B2[bo];
      acc1[n] = __builtin_amdgcn_mfma_f32_16x16x32_bf16(a1f, b1f, acc1[n], 0, 0, 0);
      acc2[n] = __builtin_amdgcn_mfma_f32_16x16x32_bf16(a2f, b2f, acc2[n], 0, 0, 0);
    }
  }
#pragma unroll
  for (int n = 0; n < 2; ++n)
#pragma unroll
    for (int r = 0; r < 4; ++r) {
      int rg = row0 + wr * 16 + fq * 4 + r;
      int cg = col0 + wc * 32 + n * 16 + fr;
      float v1 = acc1[n][r] + b1[cg];
      v1 = v1 > 0.f ? v1 : 0.01f * v1;
      float v2 = acc2[n][r] + b2[cg];
      v2 = v2 > 0.f ? v2 : 0.01f * v2;
      emb[(size_t)rg * DDIM + cg] = v1 + v2;
    }
}

// -------- layernorm over D=768 --------
__global__ __launch_bounds__(256) void ln_kernel(const float* __restrict__ emb,
                                                 const float* __restrict__ lw,
                                                 const float* __restrict__ lb,
                                                 float* __restrict__ out) {
  const int row = blockIdx.x;
  const int t = threadIdx.x;
  const int lane = t & 63, wave = t >> 6;
  __shared__ float red[4];
  __shared__ float bs[2];
  float e[3];
#pragma unroll
  for (int c = 0; c < 3; ++c) e[c] = emb[(size_t)row * DDIM + t + 256 * c];
  float s = e[0] + e[1] + e[2];
  s = wsum(s);
  if (lane == 0) red[wave] = s;
  __syncthreads();
  if (t == 0) bs[0] = (red[0] + red[1] + red[2] + red[3]) * (1.f / DDIM);
  __syncthreads();
  float mu = bs[0];
  float q = 0.f;
#pragma unroll
  for (int c = 0; c < 3; ++c) {
    float d = e[c] - mu;
    q = fmaf(d, d, q);
  }
  q = wsum(q);
  if (lane == 0) red[wave] = q;
  __syncthreads();
  if (t == 0) bs[1] = (red[0] + red[1] + red[2] + red[3]) * (1.f / DDIM);
  __syncthreads();
  float rstd = rsqrtf(bs[1] + 1e-5f);
#pragma unroll
  for (int c = 0; c < 3; ++c) {
    int d = t + 256 * c;
    out[(size_t)row * DDIM + d] = (e[c] - mu) * rstd * lw[d] + lb[d];
  }
}

// ---------------- launch ----------------
extern "C" void kernel_launch(void* const* d_in, const int* in_sizes, int n_in,
                              void* d_out, int out_size, void* d_ws,
                              size_t ws_size, hipStream_t stream) {
  const float* cls = (const float*)d_in[0];
  const float* feats = (const float*)d_in[1];
  const float* Whw = (const float*)d_in[2];
  const float* Whb = (const float*)d_in[3];
  const float* Wtw = (const float*)d_in[4];
  const float* Wtb = (const float*)d_in[5];
  const float* l1w = (const float*)d_in[6];
  const float* l1b = (const float*)d_in[7];
  const float* l2w = (const float*)d_in[8];
  const float* l2b = (const float*)d_in[9];
  const float* lnw = (const float*)d_in[10];
  const float* lnb = (const float*)d_in[11];
  float* out = (float*)d_out;

  float* ws = (float*)d_ws;
  // layout (float units)
  float* emb = ws;                          // 786432 (lin fused output)
  short* eh_hi = (short*)(ws + 3932160);    // 786432 shorts
  short* eh_lo = eh_hi + 786432;            // (ends 4718592f)
  short* et_hi = (short*)(ws + 4718592);    // 3145728 shorts
  short* et_lo = et_hi + 3145728;           // (ends 7864320f)
  short* WhT_h = (short*)(ws + 7864320);    // 589824 shorts each
  short* WhT_l = WhT_h + 589824;
  short* WtT_h = WhT_h + 2 * 589824;
  short* WtT_l = WhT_h + 3 * 589824;        // (ends 9043968f)
  short* L1T = (short*)(ws + 9043968);      // 589824 shorts
  short* L2T = L1T + 589824;                // (ends 9633792f)
  float* logits = ws + 7864320;             // overlays WhT/WtT (dead by then)
  short* Xh = (short*)(ws + 9633792);       // X bf16 hi/lo; dead after front
  short* Xl = Xh + 3145728;                 // (ends 12779520f)
  short* inbf = (short*)(ws + 10027008);    // 2048*768 shorts (786432 f)
  (void)ws_size;
  (void)in_sizes;
  (void)n_in;
  (void)out_size;

  const float scale = 0.036084391824351615f;  // 1/sqrt(768)
  dim3 blk(256);

  // merged prep: weights (2304 blocks) + X pack (1536 blocks)
  prep_all<<<dim3(3840), blk, 0, stream>>>(cls, feats, Whw, Wtw, l1w, l2w,
                                           WhT_h, WtT_h, L1T, L2T, WhT_l,
                                           WtT_l, Xh, Xl);
  // fused e_h | e_t (480 blocks, 128x64, XCD-chunked, swizzled LDS)
  gemm_front<<<dim3(480), blk, 0, stream>>>(
      Xh, Xl, WhT_h, WhT_l, Whb, WtT_h, WtT_l, Wtb, eh_hi, eh_lo, et_hi,
      et_lo);
  // logits[b] = scale * e_h[b] @ e_t[b]^T (512 blocks, batch->XCD)
  gemm_logits<<<dim3(512), blk, 0, stream>>>(eh_hi, eh_lo, et_hi, et_lo,
                                             logits, scale);
  // fused top-128 select + both softmaxes + gated agg (1024 x 512 threads)
  select_agg<<<dim3(1024), dim3(512), 0, stream>>>(logits, eh_hi, et_hi, cls,
                                                   inbf);
  // fused lin1+lin2 -> emb (384 blocks, 32x64, XCD-chunked)
  gemm_lin<<<dim3(384), blk, 0, stream>>>(inbf, L1T, L2T, l1b, l2b, emb);
  // layernorm(emb) -> out
  ln_kernel<<<dim3(NBATCH * NCLS), blk, 0, stream>>>(emb, lnw, lnb, out);
}